// Round 1
// baseline (7840.726 us; speedup 1.0000x reference)
//
#include <hip/hip_runtime.h>
#include <hip/hip_bf16.h>
#include <cstdint>
#include <cstddef>

#define PD 11
#define PP 121
#define NB 8

// ---------------------------------------------------------------------------
// zero corr buffer + init max slot (encoded -inf)
__global__ void zero_kernel(float* __restrict__ p, int n, unsigned* __restrict__ slot) {
    int i = blockIdx.x * 256 + threadIdx.x;
    if (i < n) p[i] = 0.f;
    if (i == 0) *slot = 0x007FFFFFu;  // enc(-inf)
}

// ---------------------------------------------------------------------------
// corr: thread = 1 output pixel, 121 accumulators in VGPRs.
// xp tile (rows y0-5..y0+TH+4, cols -5..W+4) staged in LDS per 8-ch chunk.
// C split across blockIdx.z (CS chunks) -> atomicAdd partial sums into corr ws.
template<int C, int H, int TH, int CS, int THREADS>
__global__ __launch_bounds__(THREADS) void corr_kernel(
    const float* __restrict__ x, const float* __restrict__ xp,
    float* __restrict__ corr)
{
    constexpr int W  = H;
    constexpr int RW = W + 10;
    constexpr int RR = TH + 10;
    constexpr int CC = 8;
    constexpr int CPER = C / CS;
    __shared__ float sXp[CC * RR * RW];

    const int tid = threadIdx.x;
    const int b  = blockIdx.y;
    const int y0 = blockIdx.x * TH;
    const int c_begin = blockIdx.z * CPER;
    const int row = tid / W;
    const int col = tid % W;
    const int y = y0 + row;
    const bool active = tid < TH * W;

    float acc[PP];
#pragma unroll
    for (int q = 0; q < PP; ++q) acc[q] = 0.f;

    for (int c0 = 0; c0 < CPER; c0 += CC) {
        __syncthreads();
        for (int fl = tid; fl < CC * RR * RW; fl += THREADS) {
            int c  = fl / (RR * RW);
            int r  = (fl / RW) % RR;
            int cx = fl % RW;
            int gy = y0 + r - 5;
            int gx = cx - 5;
            float v = 0.f;
            if (gy >= 0 && gy < H && gx >= 0 && gx < W)
                v = xp[(((size_t)b * C + (c_begin + c0 + c)) * H + gy) * W + gx];
            sXp[fl] = v;
        }
        __syncthreads();
        if (active) {
            for (int c = 0; c < CC; ++c) {
                float xv = x[(((size_t)b * C + (c_begin + c0 + c)) * H + y) * W + col];
                const float* lp = &sXp[(c * RR + row) * RW + col];
#pragma unroll
                for (int dy = 0; dy < PD; ++dy)
#pragma unroll
                    for (int dx = 0; dx < PD; ++dx)
                        acc[dy * PD + dx] = fmaf(xv, lp[dy * RW + dx], acc[dy * PD + dx]);
            }
        }
    }
    if (active) {
#pragma unroll
        for (int q = 0; q < PP; ++q)
            atomicAdd(&corr[(((size_t)b * PP + q) * H + y) * W + col], acc[q]);
    }
}

// ---------------------------------------------------------------------------
// leaky relu in-place + global max (encoded-uint atomicMax), grid-stride
__global__ void leaky_max_kernel(float* __restrict__ corr, int S, unsigned* __restrict__ slot) {
    __shared__ float sred[16];
    float v = -3.4e38f;
    for (int i = blockIdx.x * blockDim.x + threadIdx.x; i < S; i += gridDim.x * blockDim.x) {
        float c = corr[i];
        c = c > 0.f ? c : 0.01f * c;
        corr[i] = c;
        v = fmaxf(v, c);
    }
    for (int off = 32; off; off >>= 1) v = fmaxf(v, __shfl_down(v, off));
    int wid = threadIdx.x >> 6;
    if ((threadIdx.x & 63) == 0) sred[wid] = v;
    __syncthreads();
    if (threadIdx.x == 0) {
        int nw = blockDim.x >> 6;
        float m = sred[0];
        for (int w = 1; w < nw; ++w) m = fmaxf(m, sred[w]);
        unsigned eb = __float_as_uint(m);
        eb = (eb & 0x80000000u) ? ~eb : (eb | 0x80000000u);
        atomicMax(slot, eb);
    }
}

// ---------------------------------------------------------------------------
// weight transpose: W[g*121+q][ic][ky][kx] -> Wt[((q*242+ic)*9+k)*4 + g]
// so one aligned float4 load = 4 gate weights for one (q,ic,k).
__global__ void wtrans_kernel(const float* __restrict__ Wsrc, float* __restrict__ Wt) {
    int t = blockIdx.x * 256 + threadIdx.x;
    if (t >= PP * 242 * 9 * 4) return;
    int g  = t & 3;
    int kk = t >> 2;
    int k  = kk % 9;
    int icq = kk / 9;
    int ic = icq % 242;
    int q  = icq / 242;
    Wt[t] = Wsrc[(((g * PP + q) * 242 + ic) * 9) + k];
}

// ---------------------------------------------------------------------------
// fused conv3x3 (242 -> 4*121) + LSTM gates.
// Block: tile TH x TW pixels, THREADS/ (TH*TW) q-slots; input tile staged in LDS.
template<int H, int TH, int TW, int THREADS, int QG, int J>
__global__ __launch_bounds__(THREADS) void conv_lstm_kernel(
    const float* __restrict__ corr, const float* __restrict__ hpre,
    const float* __restrict__ cpre, const float* __restrict__ Wt,
    const float* __restrict__ bias, const unsigned* __restrict__ maxslot,
    float* __restrict__ outh, float* __restrict__ outc)
{
    constexpr int W    = H;
    constexpr int PX   = TH * TW;
    constexpr int QS   = THREADS / PX;
    constexpr int SR   = TW + 2;
    constexpr int SROW = (TH + 2) * SR;
    constexpr int TILES_X = W / TW;
    __shared__ float sIn[242 * SROW];

    const int tid  = threadIdx.x;
    const int b    = blockIdx.y;
    const int tile = blockIdx.x;
    const int qg   = blockIdx.z;
    const int ty0  = (tile / TILES_X) * TH;
    const int tx0  = (tile % TILES_X) * TW;

    unsigned mu = *maxslot;
    float maxv = (mu & 0x80000000u) ? __uint_as_float(mu ^ 0x80000000u) : __uint_as_float(~mu);

    for (int fl = tid; fl < 242 * SROW; fl += THREADS) {
        int ic  = fl / SROW;
        int rem = fl % SROW;
        int iy  = rem / SR;
        int ix  = rem % SR;
        int gy = ty0 + iy - 1, gx = tx0 + ix - 1;
        float v = 0.f;
        if (gy >= 0 && gy < H && gx >= 0 && gx < W) {
            if (ic < PP) v = corr[(((size_t)b * PP + ic) * H + gy) * W + gx] / maxv;
            else         v = hpre[(((size_t)b * PP + (ic - PP)) * H + gy) * W + gx];
        }
        sIn[fl] = v;
    }
    __syncthreads();

    const int slot = tid / PX;
    const int px   = tid % PX;
    const int py = px / TW, pxx = px % TW;
    const int y = ty0 + py, x = tx0 + pxx;
    const float* lp0 = &sIn[py * SR + pxx];

    for (int j = 0; j < J; ++j) {
        int q = (qg * J + j) * QS + slot;
        if (q > 120) continue;
        float a0 = bias[q], a1 = bias[PP + q], a2 = bias[2 * PP + q], a3 = bias[3 * PP + q];
        const float4* wp = (const float4*)(Wt + (size_t)q * 242 * 9 * 4);
        for (int ic = 0; ic < 242; ++ic) {
            const float* lp = lp0 + ic * SROW;
#pragma unroll
            for (int ky = 0; ky < 3; ++ky)
#pragma unroll
                for (int kx = 0; kx < 3; ++kx) {
                    float v = lp[ky * SR + kx];
                    float4 wv = wp[ic * 9 + ky * 3 + kx];
                    a0 = fmaf(v, wv.x, a0);
                    a1 = fmaf(v, wv.y, a1);
                    a2 = fmaf(v, wv.z, a2);
                    a3 = fmaf(v, wv.w, a3);
                }
        }
        float ig = 1.f / (1.f + expf(-a0));
        float fg = 1.f / (1.f + expf(-a1));
        float og = 1.f / (1.f + expf(-a2));
        float gg = tanhf(a3);
        size_t oidx = (((size_t)b * PP + q) * H + y) * W + x;
        float cp = cpre[oidx];
        float cn = fg * cp + ig * gg;
        float hn = og * tanhf(cn);
        outh[oidx] = hn;
        outc[oidx] = cn;
    }
}

// ---------------------------------------------------------------------------
extern "C" void kernel_launch(void* const* d_in, const int* in_sizes, int n_in,
                              void* d_out, int out_size, void* d_ws, size_t ws_size,
                              hipStream_t stream) {
    (void)in_sizes; (void)n_in; (void)out_size; (void)ws_size;
    static const int HH[6] = {64, 32, 16, 8, 4, 2};

    unsigned* maxslots = (unsigned*)d_ws;
    float* Wt      = (float*)((char*)d_ws + 256);
    float* corrbuf = (float*)((char*)d_ws + 256 + 4216832);  // Wt = 1,054,152 floats padded
    float* out = (float*)d_out;
    size_t obase = 0;

    for (int L = 0; L < 6; ++L) {
        const float* x    = (const float*)d_in[6 * L + 0];
        const float* xp   = (const float*)d_in[6 * L + 1];
        const float* h    = (const float*)d_in[6 * L + 2];
        const float* c    = (const float*)d_in[6 * L + 3];
        const float* Wsrc = (const float*)d_in[6 * L + 4];
        const float* bias = (const float*)d_in[6 * L + 5];
        int Hh = HH[L];
        int S = NB * PP * Hh * Hh;
        float* oh = out + obase;
        float* oc = out + obase + S;
        obase += 2 * (size_t)S;

        zero_kernel<<<(S + 255) / 256, 256, 0, stream>>>(corrbuf, S, maxslots + L);

        switch (L) {
            case 0: corr_kernel<512, 64, 4, 2, 256><<<dim3(16, 8, 2), 256, 0, stream>>>(x, xp, corrbuf); break;
            case 1: corr_kernel<1024, 32, 4, 4, 128><<<dim3(8, 8, 4), 128, 0, stream>>>(x, xp, corrbuf); break;
            case 2: corr_kernel<512, 16, 8, 8, 128><<<dim3(2, 8, 8), 128, 0, stream>>>(x, xp, corrbuf); break;
            case 3: corr_kernel<256, 8, 8, 4, 64><<<dim3(1, 8, 4), 64, 0, stream>>>(x, xp, corrbuf); break;
            case 4: corr_kernel<256, 4, 4, 4, 64><<<dim3(1, 8, 4), 64, 0, stream>>>(x, xp, corrbuf); break;
            case 5: corr_kernel<256, 2, 2, 4, 64><<<dim3(1, 8, 4), 64, 0, stream>>>(x, xp, corrbuf); break;
        }

        int gz = (S + 255) / 256; if (gz > 1024) gz = 1024;
        leaky_max_kernel<<<gz, 256, 0, stream>>>(corrbuf, S, maxslots + L);

        wtrans_kernel<<<(PP * 242 * 9 * 4 + 255) / 256, 256, 0, stream>>>(Wsrc, Wt);

        switch (L) {
            case 0: conv_lstm_kernel<64, 4, 8, 512, 1, 8><<<dim3(128, 8, 1), 512, 0, stream>>>(corrbuf, h, c, Wt, bias, maxslots + L, oh, oc); break;
            case 1: conv_lstm_kernel<32, 4, 8, 512, 1, 8><<<dim3(32, 8, 1), 512, 0, stream>>>(corrbuf, h, c, Wt, bias, maxslots + L, oh, oc); break;
            case 2: conv_lstm_kernel<16, 4, 8, 512, 4, 2><<<dim3(8, 8, 4), 512, 0, stream>>>(corrbuf, h, c, Wt, bias, maxslots + L, oh, oc); break;
            case 3: conv_lstm_kernel<8, 4, 8, 512, 8, 1><<<dim3(2, 8, 8), 512, 0, stream>>>(corrbuf, h, c, Wt, bias, maxslots + L, oh, oc); break;
            case 4: conv_lstm_kernel<4, 4, 4, 256, 8, 1><<<dim3(1, 8, 8), 256, 0, stream>>>(corrbuf, h, c, Wt, bias, maxslots + L, oh, oc); break;
            case 5: conv_lstm_kernel<2, 2, 2, 256, 2, 1><<<dim3(1, 8, 2), 256, 0, stream>>>(corrbuf, h, c, Wt, bias, maxslots + L, oh, oc); break;
        }
    }
}

// Round 2
// 3219.337 us; speedup vs baseline: 2.4355x; 2.4355x over previous
//
#include <hip/hip_runtime.h>
#include <hip/hip_bf16.h>
#include <cstdint>
#include <cstddef>

#define PD 11
#define PP 121
#define NB 8

typedef _Float16 f16x8 __attribute__((ext_vector_type(8)));
typedef float    f32x4 __attribute__((ext_vector_type(4)));

// ---------------------------------------------------------------------------
// zero corr buffer + init max slot (encoded -inf)
__global__ void zero_kernel(float* __restrict__ p, int n, unsigned* __restrict__ slot) {
    int i = blockIdx.x * 256 + threadIdx.x;
    if (i < n) p[i] = 0.f;
    if (i == 0) *slot = 0x007FFFFFu;  // enc(-inf)
}

// ---------------------------------------------------------------------------
// corr: thread = 1 output pixel, 121 accumulators in VGPRs.
template<int C, int H, int TH, int CS, int THREADS>
__global__ __launch_bounds__(THREADS) void corr_kernel(
    const float* __restrict__ x, const float* __restrict__ xp,
    float* __restrict__ corr)
{
    constexpr int W  = H;
    constexpr int RW = W + 10;
    constexpr int RR = TH + 10;
    constexpr int CC = 8;
    constexpr int CPER = C / CS;
    __shared__ float sXp[CC * RR * RW];

    const int tid = threadIdx.x;
    const int b  = blockIdx.y;
    const int y0 = blockIdx.x * TH;
    const int c_begin = blockIdx.z * CPER;
    const int row = tid / W;
    const int col = tid % W;
    const int y = y0 + row;
    const bool active = tid < TH * W;

    float acc[PP];
#pragma unroll
    for (int q = 0; q < PP; ++q) acc[q] = 0.f;

    for (int c0 = 0; c0 < CPER; c0 += CC) {
        __syncthreads();
        for (int fl = tid; fl < CC * RR * RW; fl += THREADS) {
            int c  = fl / (RR * RW);
            int r  = (fl / RW) % RR;
            int cx = fl % RW;
            int gy = y0 + r - 5;
            int gx = cx - 5;
            float v = 0.f;
            if (gy >= 0 && gy < H && gx >= 0 && gx < W)
                v = xp[(((size_t)b * C + (c_begin + c0 + c)) * H + gy) * W + gx];
            sXp[fl] = v;
        }
        __syncthreads();
        if (active) {
            for (int c = 0; c < CC; ++c) {
                float xv = x[(((size_t)b * C + (c_begin + c0 + c)) * H + y) * W + col];
                const float* lp = &sXp[(c * RR + row) * RW + col];
#pragma unroll
                for (int dy = 0; dy < PD; ++dy)
#pragma unroll
                    for (int dx = 0; dx < PD; ++dx)
                        acc[dy * PD + dx] = fmaf(xv, lp[dy * RW + dx], acc[dy * PD + dx]);
            }
        }
    }
    if (active) {
#pragma unroll
        for (int q = 0; q < PP; ++q)
            atomicAdd(&corr[(((size_t)b * PP + q) * H + y) * W + col], acc[q]);
    }
}

// ---------------------------------------------------------------------------
// leaky relu in-place + global max (encoded-uint atomicMax), grid-stride
__global__ void leaky_max_kernel(float* __restrict__ corr, int S, unsigned* __restrict__ slot) {
    __shared__ float sred[16];
    float v = -3.4e38f;
    for (int i = blockIdx.x * blockDim.x + threadIdx.x; i < S; i += gridDim.x * blockDim.x) {
        float c = corr[i];
        c = c > 0.f ? c : 0.01f * c;
        corr[i] = c;
        v = fmaxf(v, c);
    }
    for (int off = 32; off; off >>= 1) v = fmaxf(v, __shfl_down(v, off));
    int wid = threadIdx.x >> 6;
    if ((threadIdx.x & 63) == 0) sred[wid] = v;
    __syncthreads();
    if (threadIdx.x == 0) {
        int nw = blockDim.x >> 6;
        float m = sred[0];
        for (int w = 1; w < nw; ++w) m = fmaxf(m, sred[w]);
        unsigned eb = __float_as_uint(m);
        eb = (eb & 0x80000000u) ? ~eb : (eb | 0x80000000u);
        atomicMax(slot, eb);
    }
}

// ---------------------------------------------------------------------------
// weight transpose for the OLD fp32 path (levels 3..5):
// W[g*121+q][ic][ky][kx] -> Wt[((q*242+ic)*9+k)*4 + g]
__global__ void wtrans_kernel(const float* __restrict__ Wsrc, float* __restrict__ Wt) {
    int t = blockIdx.x * 256 + threadIdx.x;
    if (t >= PP * 242 * 9 * 4) return;
    int g  = t & 3;
    int kk = t >> 2;
    int k  = kk % 9;
    int icq = kk / 9;
    int ic = icq % 242;
    int q  = icq / 242;
    Wt[t] = Wsrc[(((g * PP + q) * 242 + ic) * 9) + k];
}

// ---------------------------------------------------------------------------
// weight pack for the MFMA path (levels 0..2): fragment-linear fp16.
// Apack[(((k9*8+ks)*32+mt)*64+l)*8+e] = W[m=mt*16+(l&15)][ic=ks*32+(l>>4)*8+e] for shift k9
// with m = q*4+gate  (so one lane's 4 C-regs are the 4 gates of one q).
__global__ void pack_kernel(const float* __restrict__ Wsrc, _Float16* __restrict__ Apack) {
    int t = blockIdx.x * 256 + threadIdx.x;
    if (t >= 9 * 8 * 32 * 64 * 8) return;
    int e  = t & 7;
    int l  = (t >> 3) & 63;
    int mt = (t >> 9) & 31;
    int ks = (t >> 14) & 7;
    int k9 = t >> 17;
    int m    = mt * 16 + (l & 15);
    int kloc = (l >> 4) * 8 + e;
    int ic   = ks * 32 + kloc;
    float v = 0.f;
    if (m < 484 && ic < 242) {
        int q = m >> 2, g = m & 3;
        v = Wsrc[((g * PP + q) * 242 + ic) * 9 + k9];
    }
    Apack[t] = (_Float16)v;
}

// ---------------------------------------------------------------------------
// MFMA conv3x3 (242->484) + fused LSTM. Levels with W>=16.
// Block: 512 thr = 8 waves. Pixel tile 4 rows x 16 cols. M padded to 512.
// Wave w owns m-tiles [4w,4w+4) x all 4 n-tiles (rows).
// Input tile channel-last fp16 in LDS [iy6][ix18][ic256], XOR-swizzled.
template<int H>
__global__ __launch_bounds__(512, 4) void conv_mfma_kernel(
    const float* __restrict__ corr, const float* __restrict__ hpre,
    const float* __restrict__ cpre, const _Float16* __restrict__ Apack,
    const float* __restrict__ bias, const unsigned* __restrict__ maxslot,
    float* __restrict__ outh, float* __restrict__ outc)
{
    constexpr int W = H;
    constexpr int TILES_X = W / 16;
    __shared__ _Float16 sIn[6 * 18 * 256];   // 55.3 KB

    const int tid  = threadIdx.x;
    const int b    = blockIdx.y;
    const int tile = blockIdx.x;
    const int ty0  = (tile / TILES_X) * 4;
    const int tx0  = (tile % TILES_X) * 16;

    unsigned mu = *maxslot;
    float maxv = (mu & 0x80000000u) ? __uint_as_float(mu ^ 0x80000000u) : __uint_as_float(~mu);
    float inv = 1.0f / maxv;

    // ---- stage input tile (fp32 -> fp16, channel-last, swizzled) ----
    char* sB = (char*)sIn;
    for (int it = 0; it < 27; ++it) {
        int flat = it * 512 + tid;          // 13824 u32 words total
        int ix  = flat % 18;
        int iy  = (flat / 18) % 6;
        int icp = flat / 108;               // 0..127 (pair of channels)
        int gy = ty0 + iy - 1, gx = tx0 + ix - 1;
        float v0 = 0.f, v1 = 0.f;
        if (gy >= 0 && gy < H && gx >= 0 && gx < W) {
            int ic0 = icp * 2, ic1 = icp * 2 + 1;
            if (ic0 < PP)       v0 = corr[(((size_t)b * PP + ic0) * H + gy) * W + gx] * inv;
            else if (ic0 < 242) v0 = hpre[(((size_t)b * PP + (ic0 - PP)) * H + gy) * W + gx];
            if (ic1 < PP)       v1 = corr[(((size_t)b * PP + ic1) * H + gy) * W + gx] * inv;
            else if (ic1 < 242) v1 = hpre[(((size_t)b * PP + (ic1 - PP)) * H + gy) * W + gx];
        }
        union { _Float16 h[2]; unsigned u; } pk;
        pk.h[0] = (_Float16)v0; pk.h[1] = (_Float16)v1;
        int byteoff = ((iy * 18 + ix) * 256 + icp * 2) * 2;
        byteoff ^= ((ix & 7) << 4);
        *(unsigned*)(sB + byteoff) = pk.u;
    }
    __syncthreads();

    const int w    = tid >> 6;
    const int lane = tid & 63;
    const int pxx  = lane & 15;
    const int kg   = lane >> 4;

    // ---- accumulators init = bias (D = conv + bias) ----
    f32x4 acc[4][4];
#pragma unroll
    for (int i = 0; i < 4; ++i) {
        int q = (w * 4 + i) * 4 + kg;
        f32x4 bv;
#pragma unroll
        for (int r = 0; r < 4; ++r) bv[r] = (q < PP) ? bias[r * PP + q] : 0.f;
#pragma unroll
        for (int nt = 0; nt < 4; ++nt) acc[i][nt] = bv;
    }

    // ---- K loop: 9 shifts x 8 k-steps of 32 ----
#pragma unroll 1
    for (int k9 = 0; k9 < 9; ++k9) {
        const int ky = k9 / 3, kx = k9 % 3;
        const int ix = pxx + kx;
        const int xsw = ((ix & 7) << 4);
        const f16x8* apb = (const f16x8*)Apack + ((size_t)(k9 * 8) * 32 + w * 4) * 64 + lane;
#pragma unroll 1
        for (int ks = 0; ks < 8; ++ks) {
            f16x8 bf[4];
#pragma unroll
            for (int nt = 0; nt < 4; ++nt) {
                int byteoff = (((nt + ky) * 18 + ix) * 512) + ks * 64 + kg * 16;
                bf[nt] = *(const f16x8*)(sB + (byteoff ^ xsw));
            }
            const f16x8* ap = apb + (size_t)ks * 32 * 64;
            f16x8 af4[4];
#pragma unroll
            for (int i = 0; i < 4; ++i) af4[i] = ap[i * 64];
#pragma unroll
            for (int i = 0; i < 4; ++i)
#pragma unroll
                for (int nt = 0; nt < 4; ++nt)
                    acc[i][nt] = __builtin_amdgcn_mfma_f32_16x16x32_f16(af4[i], bf[nt], acc[i][nt], 0, 0, 0);
        }
    }

    // ---- fused LSTM epilogue (lane-local: 4 regs = 4 gates of one q) ----
    const int x = tx0 + pxx;
#pragma unroll
    for (int i = 0; i < 4; ++i) {
        int q = (w * 4 + i) * 4 + kg;
        if (q >= PP) continue;
#pragma unroll
        for (int nt = 0; nt < 4; ++nt) {
            int y = ty0 + nt;
            float ai = acc[i][nt][0];
            float af_ = acc[i][nt][1];
            float ao = acc[i][nt][2];
            float ag = acc[i][nt][3];
            float ig = 1.f / (1.f + expf(-ai));
            float fg = 1.f / (1.f + expf(-af_));
            float og = 1.f / (1.f + expf(-ao));
            float gg = tanhf(ag);
            size_t oidx = (((size_t)b * PP + q) * H + y) * W + x;
            float cp = cpre[oidx];
            float cn = fg * cp + ig * gg;
            outh[oidx] = og * tanhf(cn);
            outc[oidx] = cn;
        }
    }
}

// ---------------------------------------------------------------------------
// OLD fp32 conv+LSTM, kept for tiny levels (H=8,4,2)
template<int H, int TH, int TW, int THREADS, int QG, int J>
__global__ __launch_bounds__(THREADS) void conv_lstm_kernel(
    const float* __restrict__ corr, const float* __restrict__ hpre,
    const float* __restrict__ cpre, const float* __restrict__ Wt,
    const float* __restrict__ bias, const unsigned* __restrict__ maxslot,
    float* __restrict__ outh, float* __restrict__ outc)
{
    constexpr int W    = H;
    constexpr int PX   = TH * TW;
    constexpr int QS   = THREADS / PX;
    constexpr int SR   = TW + 2;
    constexpr int SROW = (TH + 2) * SR;
    constexpr int TILES_X = W / TW;
    __shared__ float sIn[242 * SROW];

    const int tid  = threadIdx.x;
    const int b    = blockIdx.y;
    const int tile = blockIdx.x;
    const int qg   = blockIdx.z;
    const int ty0  = (tile / TILES_X) * TH;
    const int tx0  = (tile % TILES_X) * TW;

    unsigned mu = *maxslot;
    float maxv = (mu & 0x80000000u) ? __uint_as_float(mu ^ 0x80000000u) : __uint_as_float(~mu);

    for (int fl = tid; fl < 242 * SROW; fl += THREADS) {
        int ic  = fl / SROW;
        int rem = fl % SROW;
        int iy  = rem / SR;
        int ix  = rem % SR;
        int gy = ty0 + iy - 1, gx = tx0 + ix - 1;
        float v = 0.f;
        if (gy >= 0 && gy < H && gx >= 0 && gx < W) {
            if (ic < PP) v = corr[(((size_t)b * PP + ic) * H + gy) * W + gx] / maxv;
            else         v = hpre[(((size_t)b * PP + (ic - PP)) * H + gy) * W + gx];
        }
        sIn[fl] = v;
    }
    __syncthreads();

    const int slot = tid / PX;
    const int px   = tid % PX;
    const int py = px / TW, pxx = px % TW;
    const int y = ty0 + py, x = tx0 + pxx;
    const float* lp0 = &sIn[py * SR + pxx];

    for (int j = 0; j < J; ++j) {
        int q = (qg * J + j) * QS + slot;
        if (q > 120) continue;
        float a0 = bias[q], a1 = bias[PP + q], a2 = bias[2 * PP + q], a3 = bias[3 * PP + q];
        const float4* wp = (const float4*)(Wt + (size_t)q * 242 * 9 * 4);
        for (int ic = 0; ic < 242; ++ic) {
            const float* lp = lp0 + ic * SROW;
#pragma unroll
            for (int ky = 0; ky < 3; ++ky)
#pragma unroll
                for (int kx = 0; kx < 3; ++kx) {
                    float v = lp[ky * SR + kx];
                    float4 wv = wp[ic * 9 + ky * 3 + kx];
                    a0 = fmaf(v, wv.x, a0);
                    a1 = fmaf(v, wv.y, a1);
                    a2 = fmaf(v, wv.z, a2);
                    a3 = fmaf(v, wv.w, a3);
                }
        }
        float ig = 1.f / (1.f + expf(-a0));
        float fg = 1.f / (1.f + expf(-a1));
        float og = 1.f / (1.f + expf(-a2));
        float gg = tanhf(a3);
        size_t oidx = (((size_t)b * PP + q) * H + y) * W + x;
        float cp = cpre[oidx];
        float cn = fg * cp + ig * gg;
        float hn = og * tanhf(cn);
        outh[oidx] = hn;
        outc[oidx] = cn;
    }
}

// ---------------------------------------------------------------------------
extern "C" void kernel_launch(void* const* d_in, const int* in_sizes, int n_in,
                              void* d_out, int out_size, void* d_ws, size_t ws_size,
                              hipStream_t stream) {
    (void)in_sizes; (void)n_in; (void)out_size; (void)ws_size;
    static const int HH[6] = {64, 32, 16, 8, 4, 2};

    unsigned* maxslots = (unsigned*)d_ws;
    // Wt (old path, fp32, 4,216,832 B) and Apack (MFMA path, 2,359,296 B)
    // are never live at the same time -> union the region.
    float*     Wt    = (float*)((char*)d_ws + 256);
    _Float16*  Apack = (_Float16*)((char*)d_ws + 256);
    float* corrbuf   = (float*)((char*)d_ws + 256 + 4216832);
    float* out = (float*)d_out;
    size_t obase = 0;

    for (int L = 0; L < 6; ++L) {
        const float* x    = (const float*)d_in[6 * L + 0];
        const float* xp   = (const float*)d_in[6 * L + 1];
        const float* h    = (const float*)d_in[6 * L + 2];
        const float* c    = (const float*)d_in[6 * L + 3];
        const float* Wsrc = (const float*)d_in[6 * L + 4];
        const float* bias = (const float*)d_in[6 * L + 5];
        int Hh = HH[L];
        int S = NB * PP * Hh * Hh;
        float* oh = out + obase;
        float* oc = out + obase + S;
        obase += 2 * (size_t)S;

        zero_kernel<<<(S + 255) / 256, 256, 0, stream>>>(corrbuf, S, maxslots + L);

        switch (L) {
            case 0: corr_kernel<512, 64, 4, 2, 256><<<dim3(16, 8, 2), 256, 0, stream>>>(x, xp, corrbuf); break;
            case 1: corr_kernel<1024, 32, 4, 4, 128><<<dim3(8, 8, 4), 128, 0, stream>>>(x, xp, corrbuf); break;
            case 2: corr_kernel<512, 16, 8, 8, 128><<<dim3(2, 8, 8), 128, 0, stream>>>(x, xp, corrbuf); break;
            case 3: corr_kernel<256, 8, 8, 4, 64><<<dim3(1, 8, 4), 64, 0, stream>>>(x, xp, corrbuf); break;
            case 4: corr_kernel<256, 4, 4, 4, 64><<<dim3(1, 8, 4), 64, 0, stream>>>(x, xp, corrbuf); break;
            case 5: corr_kernel<256, 2, 2, 4, 64><<<dim3(1, 8, 4), 64, 0, stream>>>(x, xp, corrbuf); break;
        }

        int gz = (S + 255) / 256; if (gz > 1024) gz = 1024;
        leaky_max_kernel<<<gz, 256, 0, stream>>>(corrbuf, S, maxslots + L);

        if (L < 3) {
            pack_kernel<<<(9 * 8 * 32 * 64 * 8) / 256, 256, 0, stream>>>(Wsrc, Apack);
            switch (L) {
                case 0: conv_mfma_kernel<64><<<dim3(64, 8), 512, 0, stream>>>(corrbuf, h, c, Apack, bias, maxslots + L, oh, oc); break;
                case 1: conv_mfma_kernel<32><<<dim3(16, 8), 512, 0, stream>>>(corrbuf, h, c, Apack, bias, maxslots + L, oh, oc); break;
                case 2: conv_mfma_kernel<16><<<dim3(4, 8),  512, 0, stream>>>(corrbuf, h, c, Apack, bias, maxslots + L, oh, oc); break;
            }
        } else {
            wtrans_kernel<<<(PP * 242 * 9 * 4 + 255) / 256, 256, 0, stream>>>(Wsrc, Wt);
            switch (L) {
                case 3: conv_lstm_kernel<8, 4, 8, 512, 8, 1><<<dim3(2, 8, 8), 512, 0, stream>>>(corrbuf, h, c, Wt, bias, maxslots + L, oh, oc); break;
                case 4: conv_lstm_kernel<4, 4, 4, 256, 8, 1><<<dim3(1, 8, 8), 256, 0, stream>>>(corrbuf, h, c, Wt, bias, maxslots + L, oh, oc); break;
                case 5: conv_lstm_kernel<2, 2, 2, 256, 2, 1><<<dim3(1, 8, 2), 256, 0, stream>>>(corrbuf, h, c, Wt, bias, maxslots + L, oh, oc); break;
            }
        }
    }
}

// Round 3
// 1300.544 us; speedup vs baseline: 6.0288x; 2.4754x over previous
//
#include <hip/hip_runtime.h>
#include <hip/hip_bf16.h>
#include <cstdint>
#include <cstddef>

#define PD 11
#define PP 121
#define NB 8

typedef _Float16 f16x8 __attribute__((ext_vector_type(8)));
typedef float    f32x4 __attribute__((ext_vector_type(4)));

// ---------------------------------------------------------------------------
__global__ void init_slots_kernel(unsigned* __restrict__ slots) {
    if (threadIdx.x < 8) slots[threadIdx.x] = 0x007FFFFFu;  // enc(-inf)
}

// zero corr buffer + init max slot (fallback/VALU path)
__global__ void zero_kernel(float* __restrict__ p, int n, unsigned* __restrict__ slot) {
    int i = blockIdx.x * 256 + threadIdx.x;
    if (i < n) p[i] = 0.f;
    if (i == 0) *slot = 0x007FFFFFu;
}

// ---------------------------------------------------------------------------
// fp32 NCHW -> fp16 NHWC transpose (channel-last), tile 32c x 16x via LDS
template<int C, int H>
__global__ __launch_bounds__(256) void tpose_kernel(const float* __restrict__ in,
                                                    _Float16* __restrict__ out) {
    constexpr int W = H;
    constexpr int NXT = W / 16;
    const int t  = threadIdx.x;
    const int by = blockIdx.y;            // b*H + y
    const int b  = by / H, y = by % H;
    const int xc = (blockIdx.x % NXT) * 16;
    const int cc = (blockIdx.x / NXT) * 32;
    __shared__ float s[32][17];
    const int r = t >> 4, xcol = t & 15;
    s[r][xcol]      = in[((size_t)(b * C + cc + r) * H + y) * W + xc + xcol];
    s[r + 16][xcol] = in[((size_t)(b * C + cc + r + 16) * H + y) * W + xc + xcol];
    __syncthreads();
    int x = t >> 4, cp = (t & 15) * 2;
    union { _Float16 h[2]; unsigned u; } pk;
    pk.h[0] = (_Float16)s[cp][x];
    pk.h[1] = (_Float16)s[cp + 1][x];
    *(unsigned*)(out + ((size_t)(b * H + y) * W + xc + x) * C + cc + cp) = pk.u;
}

// ---------------------------------------------------------------------------
// MFMA correlation: per pixel tile, T[z][p] = sum_c xp_halo[z,c] * x[p,c]
// (GEMM over K=C), then corr[p][q] = T[p + d(q)][p], fused leaky + block max.
template<int C, int H, int TSY, int TSX>
__global__ __launch_bounds__(512, 1) void corr_mfma_kernel(
    const _Float16* __restrict__ xT, const _Float16* __restrict__ xpT,
    float* __restrict__ corr, unsigned* __restrict__ slot)
{
    constexpr int W  = H;
    constexpr int HY = TSY + 10, HX = TSX + 10;
    constexpr int MZ = HY * HX;
    constexpr int MT = (MZ + 15) / 16;
    constexpr int MTP = MT * 16;
    constexpr int MFRAG = (MT + 7) / 8;
    constexpr int NPX = TSY * TSX;       // power of 2
    constexpr int NT  = NPX / 16;
    constexpr int KC  = C / 32;
    constexpr int STAGE_B   = (MTP + NPX) * 64;
    constexpr int ST_STRIDE = NPX + 4;
    constexpr int ST_B      = MTP * ST_STRIDE * 4;
    constexpr int LDS_B     = STAGE_B > ST_B ? STAGE_B : ST_B;
    __shared__ char smem[LDS_B];
    __shared__ float sred[8];

    const int tid  = threadIdx.x;
    const int b    = blockIdx.y;
    constexpr int TXT = W / TSX;
    const int y0 = (blockIdx.x / TXT) * TSY;
    const int x0 = (blockIdx.x % TXT) * TSX;
    const int w = tid >> 6, lane = tid & 63;
    const int lcol = lane & 15, lkg = lane >> 4;

    f32x4 acc[MFRAG][NT];
#pragma unroll
    for (int i = 0; i < MFRAG; ++i)
#pragma unroll
        for (int nt = 0; nt < NT; ++nt)
            acc[i][nt] = (f32x4){0.f, 0.f, 0.f, 0.f};

#pragma unroll 1
    for (int kc = 0; kc < KC; ++kc) {
        __syncthreads();
        constexpr int UXP = MTP * 4;
        constexpr int U   = UXP + NPX * 4;
        for (int u = tid; u < U; u += 512) {
            f16x8 v = {0, 0, 0, 0, 0, 0, 0, 0};
            int dstbyte;
            if (u < UXP) {
                int z = u >> 2, kg = u & 3;
                dstbyte = z * 64 + (((kg ^ (z >> 2)) & 3) << 4);
                int zy = y0 + z / HX - 5, zx = x0 + z % HX - 5;
                if (z < MZ && zy >= 0 && zy < H && zx >= 0 && zx < W)
                    v = *(const f16x8*)(xpT + ((size_t)(b * H + zy) * W + zx) * C + kc * 32 + kg * 8);
            } else {
                int u2 = u - UXP;
                int p = u2 >> 2, kg = u2 & 3;
                dstbyte = MTP * 64 + p * 64 + (((kg ^ (p >> 2)) & 3) << 4);
                int gy = y0 + p / TSX, gx = x0 + p % TSX;
                v = *(const f16x8*)(xT + ((size_t)(b * H + gy) * W + gx) * C + kc * 32 + kg * 8);
            }
            *(f16x8*)(smem + dstbyte) = v;
        }
        __syncthreads();

        f16x8 bF[NT];
#pragma unroll
        for (int nt = 0; nt < NT; ++nt) {
            int p = nt * 16 + lcol;
            bF[nt] = *(const f16x8*)(smem + MTP * 64 + p * 64 + (((lkg ^ (p >> 2)) & 3) << 4));
        }
#pragma unroll
        for (int i = 0; i < MFRAG; ++i) {
            int mt = w + i * 8;
            if (mt < MT) {
                int z = mt * 16 + lcol;
                f16x8 aF = *(const f16x8*)(smem + z * 64 + (((lkg ^ (z >> 2)) & 3) << 4));
#pragma unroll
                for (int nt = 0; nt < NT; ++nt)
                    acc[i][nt] = __builtin_amdgcn_mfma_f32_16x16x32_f16(aF, bF[nt], acc[i][nt], 0, 0, 0);
            }
        }
    }
    __syncthreads();

    float* sT = (float*)smem;
#pragma unroll
    for (int i = 0; i < MFRAG; ++i) {
        int mt = w + i * 8;
        if (mt >= MT) continue;
        int z0 = mt * 16 + lkg * 4;
#pragma unroll
        for (int nt = 0; nt < NT; ++nt) {
            int p = nt * 16 + lcol;
#pragma unroll
            for (int r = 0; r < 4; ++r)
                sT[(z0 + r) * ST_STRIDE + p] = acc[i][nt][r];
        }
    }
    __syncthreads();

    float lmax = -3.4e38f;
    for (int o = tid; o < PP * NPX; o += 512) {
        int p = o & (NPX - 1);
        int q = o / NPX;
        int py = p / TSX, px = p % TSX;
        int dy = q / PD, dx = q % PD;
        float v = sT[((py + dy) * HX + (px + dx)) * ST_STRIDE + p];
        v = v > 0.f ? v : 0.01f * v;
        lmax = fmaxf(lmax, v);
        corr[(((size_t)b * PP + q) * H + (y0 + py)) * W + (x0 + px)] = v;
    }
    for (int off = 32; off; off >>= 1) lmax = fmaxf(lmax, __shfl_down(lmax, off));
    if (lane == 0) sred[w] = lmax;
    __syncthreads();
    if (tid == 0) {
        float m = sred[0];
        for (int i = 1; i < 8; ++i) m = fmaxf(m, sred[i]);
        unsigned eb = __float_as_uint(m);
        eb = (eb & 0x80000000u) ? ~eb : (eb | 0x80000000u);
        atomicMax(slot, eb);
    }
}

// ---------------------------------------------------------------------------
// VALU corr (kept for tiny levels + fallback)
template<int C, int H, int TH, int CS, int THREADS>
__global__ __launch_bounds__(THREADS) void corr_kernel(
    const float* __restrict__ x, const float* __restrict__ xp,
    float* __restrict__ corr)
{
    constexpr int W  = H;
    constexpr int RW = W + 10;
    constexpr int RR = TH + 10;
    constexpr int CC = 8;
    constexpr int CPER = C / CS;
    __shared__ float sXp[CC * RR * RW];

    const int tid = threadIdx.x;
    const int b  = blockIdx.y;
    const int y0 = blockIdx.x * TH;
    const int c_begin = blockIdx.z * CPER;
    const int row = tid / W;
    const int col = tid % W;
    const int y = y0 + row;
    const bool active = tid < TH * W;

    float acc[PP];
#pragma unroll
    for (int q = 0; q < PP; ++q) acc[q] = 0.f;

    for (int c0 = 0; c0 < CPER; c0 += CC) {
        __syncthreads();
        for (int fl = tid; fl < CC * RR * RW; fl += THREADS) {
            int c  = fl / (RR * RW);
            int r  = (fl / RW) % RR;
            int cx = fl % RW;
            int gy = y0 + r - 5;
            int gx = cx - 5;
            float v = 0.f;
            if (gy >= 0 && gy < H && gx >= 0 && gx < W)
                v = xp[(((size_t)b * C + (c_begin + c0 + c)) * H + gy) * W + gx];
            sXp[fl] = v;
        }
        __syncthreads();
        if (active) {
            for (int c = 0; c < CC; ++c) {
                float xv = x[(((size_t)b * C + (c_begin + c0 + c)) * H + y) * W + col];
                const float* lp = &sXp[(c * RR + row) * RW + col];
#pragma unroll
                for (int dy = 0; dy < PD; ++dy)
#pragma unroll
                    for (int dx = 0; dx < PD; ++dx)
                        acc[dy * PD + dx] = fmaf(xv, lp[dy * RW + dx], acc[dy * PD + dx]);
            }
        }
    }
    if (active) {
#pragma unroll
        for (int q = 0; q < PP; ++q)
            atomicAdd(&corr[(((size_t)b * PP + q) * H + y) * W + col], acc[q]);
    }
}

// ---------------------------------------------------------------------------
__global__ void leaky_max_kernel(float* __restrict__ corr, int S, unsigned* __restrict__ slot) {
    __shared__ float sred[16];
    float v = -3.4e38f;
    for (int i = blockIdx.x * blockDim.x + threadIdx.x; i < S; i += gridDim.x * blockDim.x) {
        float c = corr[i];
        c = c > 0.f ? c : 0.01f * c;
        corr[i] = c;
        v = fmaxf(v, c);
    }
    for (int off = 32; off; off >>= 1) v = fmaxf(v, __shfl_down(v, off));
    int wid = threadIdx.x >> 6;
    if ((threadIdx.x & 63) == 0) sred[wid] = v;
    __syncthreads();
    if (threadIdx.x == 0) {
        int nw = blockDim.x >> 6;
        float m = sred[0];
        for (int w = 1; w < nw; ++w) m = fmaxf(m, sred[w]);
        unsigned eb = __float_as_uint(m);
        eb = (eb & 0x80000000u) ? ~eb : (eb | 0x80000000u);
        atomicMax(slot, eb);
    }
}

// ---------------------------------------------------------------------------
__global__ void wtrans_kernel(const float* __restrict__ Wsrc, float* __restrict__ Wt) {
    int t = blockIdx.x * 256 + threadIdx.x;
    if (t >= PP * 242 * 9 * 4) return;
    int g  = t & 3;
    int kk = t >> 2;
    int k  = kk % 9;
    int icq = kk / 9;
    int ic = icq % 242;
    int q  = icq / 242;
    Wt[t] = Wsrc[(((g * PP + q) * 242 + ic) * 9) + k];
}

// ---------------------------------------------------------------------------
__global__ void pack_kernel(const float* __restrict__ Wsrc, _Float16* __restrict__ Apack) {
    int t = blockIdx.x * 256 + threadIdx.x;
    if (t >= 9 * 8 * 32 * 64 * 8) return;
    int e  = t & 7;
    int l  = (t >> 3) & 63;
    int mt = (t >> 9) & 31;
    int ks = (t >> 14) & 7;
    int k9 = t >> 17;
    int m    = mt * 16 + (l & 15);
    int kloc = (l >> 4) * 8 + e;
    int ic   = ks * 32 + kloc;
    float v = 0.f;
    if (m < 484 && ic < 242) {
        int q = m >> 2, g = m & 3;
        v = Wsrc[((g * PP + q) * 242 + ic) * 9 + k9];
    }
    Apack[t] = (_Float16)v;
}

// ---------------------------------------------------------------------------
template<int H>
__global__ __launch_bounds__(512, 4) void conv_mfma_kernel(
    const float* __restrict__ corr, const float* __restrict__ hpre,
    const float* __restrict__ cpre, const _Float16* __restrict__ Apack,
    const float* __restrict__ bias, const unsigned* __restrict__ maxslot,
    float* __restrict__ outh, float* __restrict__ outc)
{
    constexpr int W = H;
    constexpr int TILES_X = W / 16;
    __shared__ _Float16 sIn[6 * 18 * 256];

    const int tid  = threadIdx.x;
    const int b    = blockIdx.y;
    const int tile = blockIdx.x;
    const int ty0  = (tile / TILES_X) * 4;
    const int tx0  = (tile % TILES_X) * 16;

    unsigned mu = *maxslot;
    float maxv = (mu & 0x80000000u) ? __uint_as_float(mu ^ 0x80000000u) : __uint_as_float(~mu);
    float inv = 1.0f / maxv;

    char* sB = (char*)sIn;
    for (int it = 0; it < 27; ++it) {
        int flat = it * 512 + tid;
        int ix  = flat % 18;
        int iy  = (flat / 18) % 6;
        int icp = flat / 108;
        int gy = ty0 + iy - 1, gx = tx0 + ix - 1;
        float v0 = 0.f, v1 = 0.f;
        if (gy >= 0 && gy < H && gx >= 0 && gx < W) {
            int ic0 = icp * 2, ic1 = icp * 2 + 1;
            if (ic0 < PP)       v0 = corr[(((size_t)b * PP + ic0) * H + gy) * W + gx] * inv;
            else if (ic0 < 242) v0 = hpre[(((size_t)b * PP + (ic0 - PP)) * H + gy) * W + gx];
            if (ic1 < PP)       v1 = corr[(((size_t)b * PP + ic1) * H + gy) * W + gx] * inv;
            else if (ic1 < 242) v1 = hpre[(((size_t)b * PP + (ic1 - PP)) * H + gy) * W + gx];
        }
        union { _Float16 h[2]; unsigned u; } pk;
        pk.h[0] = (_Float16)v0; pk.h[1] = (_Float16)v1;
        int byteoff = ((iy * 18 + ix) * 256 + icp * 2) * 2;
        byteoff ^= ((ix & 7) << 4);
        *(unsigned*)(sB + byteoff) = pk.u;
    }
    __syncthreads();

    const int w    = tid >> 6;
    const int lane = tid & 63;
    const int pxx  = lane & 15;
    const int kg   = lane >> 4;

    f32x4 acc[4][4];
#pragma unroll
    for (int i = 0; i < 4; ++i) {
        int q = (w * 4 + i) * 4 + kg;
        f32x4 bv;
#pragma unroll
        for (int r = 0; r < 4; ++r) bv[r] = (q < PP) ? bias[r * PP + q] : 0.f;
#pragma unroll
        for (int nt = 0; nt < 4; ++nt) acc[i][nt] = bv;
    }

#pragma unroll 1
    for (int k9 = 0; k9 < 9; ++k9) {
        const int ky = k9 / 3, kx = k9 % 3;
        const int ix = pxx + kx;
        const int xsw = ((ix & 7) << 4);
        const f16x8* apb = (const f16x8*)Apack + ((size_t)(k9 * 8) * 32 + w * 4) * 64 + lane;
#pragma unroll 1
        for (int ks = 0; ks < 8; ++ks) {
            f16x8 bf[4];
#pragma unroll
            for (int nt = 0; nt < 4; ++nt) {
                int byteoff = (((nt + ky) * 18 + ix) * 512) + ks * 64 + kg * 16;
                bf[nt] = *(const f16x8*)(sB + (byteoff ^ xsw));
            }
            const f16x8* ap = apb + (size_t)ks * 32 * 64;
            f16x8 af4[4];
#pragma unroll
            for (int i = 0; i < 4; ++i) af4[i] = ap[i * 64];
#pragma unroll
            for (int i = 0; i < 4; ++i)
#pragma unroll
                for (int nt = 0; nt < 4; ++nt)
                    acc[i][nt] = __builtin_amdgcn_mfma_f32_16x16x32_f16(af4[i], bf[nt], acc[i][nt], 0, 0, 0);
        }
    }

    const int x = tx0 + pxx;
#pragma unroll
    for (int i = 0; i < 4; ++i) {
        int q = (w * 4 + i) * 4 + kg;
        if (q >= PP) continue;
#pragma unroll
        for (int nt = 0; nt < 4; ++nt) {
            int y = ty0 + nt;
            float ai = acc[i][nt][0];
            float af_ = acc[i][nt][1];
            float ao = acc[i][nt][2];
            float ag = acc[i][nt][3];
            float ig = 1.f / (1.f + expf(-ai));
            float fg = 1.f / (1.f + expf(-af_));
            float og = 1.f / (1.f + expf(-ao));
            float gg = tanhf(ag);
            size_t oidx = (((size_t)b * PP + q) * H + y) * W + x;
            float cp = cpre[oidx];
            float cn = fg * cp + ig * gg;
            outh[oidx] = og * tanhf(cn);
            outc[oidx] = cn;
        }
    }
}

// ---------------------------------------------------------------------------
template<int H, int TH, int TW, int THREADS, int QG, int J>
__global__ __launch_bounds__(THREADS) void conv_lstm_kernel(
    const float* __restrict__ corr, const float* __restrict__ hpre,
    const float* __restrict__ cpre, const float* __restrict__ Wt,
    const float* __restrict__ bias, const unsigned* __restrict__ maxslot,
    float* __restrict__ outh, float* __restrict__ outc)
{
    constexpr int W    = H;
    constexpr int PX   = TH * TW;
    constexpr int QS   = THREADS / PX;
    constexpr int SR   = TW + 2;
    constexpr int SROW = (TH + 2) * SR;
    constexpr int TILES_X = W / TW;
    __shared__ float sIn[242 * SROW];

    const int tid  = threadIdx.x;
    const int b    = blockIdx.y;
    const int tile = blockIdx.x;
    const int qg   = blockIdx.z;
    const int ty0  = (tile / TILES_X) * TH;
    const int tx0  = (tile % TILES_X) * TW;

    unsigned mu = *maxslot;
    float maxv = (mu & 0x80000000u) ? __uint_as_float(mu ^ 0x80000000u) : __uint_as_float(~mu);

    for (int fl = tid; fl < 242 * SROW; fl += THREADS) {
        int ic  = fl / SROW;
        int rem = fl % SROW;
        int iy  = rem / SR;
        int ix  = rem % SR;
        int gy = ty0 + iy - 1, gx = tx0 + ix - 1;
        float v = 0.f;
        if (gy >= 0 && gy < H && gx >= 0 && gx < W) {
            if (ic < PP) v = corr[(((size_t)b * PP + ic) * H + gy) * W + gx] / maxv;
            else         v = hpre[(((size_t)b * PP + (ic - PP)) * H + gy) * W + gx];
        }
        sIn[fl] = v;
    }
    __syncthreads();

    const int slot = tid / PX;
    const int px   = tid % PX;
    const int py = px / TW, pxx = px % TW;
    const int y = ty0 + py, x = tx0 + pxx;
    const float* lp0 = &sIn[py * SR + pxx];

    for (int j = 0; j < J; ++j) {
        int q = (qg * J + j) * QS + slot;
        if (q > 120) continue;
        float a0 = bias[q], a1 = bias[PP + q], a2 = bias[2 * PP + q], a3 = bias[3 * PP + q];
        const float4* wp = (const float4*)(Wt + (size_t)q * 242 * 9 * 4);
        for (int ic = 0; ic < 242; ++ic) {
            const float* lp = lp0 + ic * SROW;
#pragma unroll
            for (int ky = 0; ky < 3; ++ky)
#pragma unroll
                for (int kx = 0; kx < 3; ++kx) {
                    float v = lp[ky * SR + kx];
                    float4 wv = wp[ic * 9 + ky * 3 + kx];
                    a0 = fmaf(v, wv.x, a0);
                    a1 = fmaf(v, wv.y, a1);
                    a2 = fmaf(v, wv.z, a2);
                    a3 = fmaf(v, wv.w, a3);
                }
        }
        float ig = 1.f / (1.f + expf(-a0));
        float fg = 1.f / (1.f + expf(-a1));
        float og = 1.f / (1.f + expf(-a2));
        float gg = tanhf(a3);
        size_t oidx = (((size_t)b * PP + q) * H + y) * W + x;
        float cp = cpre[oidx];
        float cn = fg * cp + ig * gg;
        float hn = og * tanhf(cn);
        outh[oidx] = hn;
        outc[oidx] = cn;
    }
}

// ---------------------------------------------------------------------------
extern "C" void kernel_launch(void* const* d_in, const int* in_sizes, int n_in,
                              void* d_out, int out_size, void* d_ws, size_t ws_size,
                              hipStream_t stream) {
    (void)in_sizes; (void)n_in; (void)out_size;
    static const int HH[6] = {64, 32, 16, 8, 4, 2};

    unsigned* maxslots = (unsigned*)d_ws;
    float*     Wt    = (float*)((char*)d_ws + 256);
    _Float16*  Apack = (_Float16*)((char*)d_ws + 256);
    float* corrbuf   = (float*)((char*)d_ws + 256 + 4216832);
    _Float16* xTbuf  = (_Float16*)((char*)d_ws + 256 + 4216832 + 15872000);
    _Float16* xpTbuf = (_Float16*)((char*)d_ws + 256 + 4216832 + 15872000 + 33554432);
    const size_t ws_needed = 256 + 4216832 + 15872000 + 2ull * 33554432;
    const bool mfma_corr = ws_size >= ws_needed;

    float* out = (float*)d_out;
    size_t obase = 0;

    init_slots_kernel<<<1, 64, 0, stream>>>(maxslots);

    for (int L = 0; L < 6; ++L) {
        const float* x    = (const float*)d_in[6 * L + 0];
        const float* xp   = (const float*)d_in[6 * L + 1];
        const float* h    = (const float*)d_in[6 * L + 2];
        const float* c    = (const float*)d_in[6 * L + 3];
        const float* Wsrc = (const float*)d_in[6 * L + 4];
        const float* bias = (const float*)d_in[6 * L + 5];
        int Hh = HH[L];
        int S = NB * PP * Hh * Hh;
        float* oh = out + obase;
        float* oc = out + obase + S;
        obase += 2 * (size_t)S;

        if (L < 3 && mfma_corr) {
            // fp16 channel-last transposes
            switch (L) {
                case 0:
                    tpose_kernel<512, 64><<<dim3(4 * 16, NB * 64), 256, 0, stream>>>(x, xTbuf);
                    tpose_kernel<512, 64><<<dim3(4 * 16, NB * 64), 256, 0, stream>>>(xp, xpTbuf);
                    corr_mfma_kernel<512, 64, 8, 8><<<dim3(64, NB), 512, 0, stream>>>(xTbuf, xpTbuf, corrbuf, maxslots + L);
                    break;
                case 1:
                    tpose_kernel<1024, 32><<<dim3(2 * 32, NB * 32), 256, 0, stream>>>(x, xTbuf);
                    tpose_kernel<1024, 32><<<dim3(2 * 32, NB * 32), 256, 0, stream>>>(xp, xpTbuf);
                    corr_mfma_kernel<1024, 32, 4, 8><<<dim3(32, NB), 512, 0, stream>>>(xTbuf, xpTbuf, corrbuf, maxslots + L);
                    break;
                case 2:
                    tpose_kernel<512, 16><<<dim3(1 * 16, NB * 16), 256, 0, stream>>>(x, xTbuf);
                    tpose_kernel<512, 16><<<dim3(1 * 16, NB * 16), 256, 0, stream>>>(xp, xpTbuf);
                    corr_mfma_kernel<512, 16, 4, 4><<<dim3(16, NB), 512, 0, stream>>>(xTbuf, xpTbuf, corrbuf, maxslots + L);
                    break;
            }
        } else {
            zero_kernel<<<(S + 255) / 256, 256, 0, stream>>>(corrbuf, S, maxslots + L);
            switch (L) {
                case 0: corr_kernel<512, 64, 4, 2, 256><<<dim3(16, 8, 2), 256, 0, stream>>>(x, xp, corrbuf); break;
                case 1: corr_kernel<1024, 32, 4, 4, 128><<<dim3(8, 8, 4), 128, 0, stream>>>(x, xp, corrbuf); break;
                case 2: corr_kernel<512, 16, 8, 8, 128><<<dim3(2, 8, 8), 128, 0, stream>>>(x, xp, corrbuf); break;
                case 3: corr_kernel<256, 8, 8, 4, 64><<<dim3(1, 8, 4), 64, 0, stream>>>(x, xp, corrbuf); break;
                case 4: corr_kernel<256, 4, 4, 4, 64><<<dim3(1, 8, 4), 64, 0, stream>>>(x, xp, corrbuf); break;
                case 5: corr_kernel<256, 2, 2, 4, 64><<<dim3(1, 8, 4), 64, 0, stream>>>(x, xp, corrbuf); break;
            }
            int gz = (S + 255) / 256; if (gz > 1024) gz = 1024;
            leaky_max_kernel<<<gz, 256, 0, stream>>>(corrbuf, S, maxslots + L);
        }

        if (L < 3) {
            pack_kernel<<<(9 * 8 * 32 * 64 * 8) / 256, 256, 0, stream>>>(Wsrc, Apack);
            switch (L) {
                case 0: conv_mfma_kernel<64><<<dim3(64, 8), 512, 0, stream>>>(corrbuf, h, c, Apack, bias, maxslots + L, oh, oc); break;
                case 1: conv_mfma_kernel<32><<<dim3(16, 8), 512, 0, stream>>>(corrbuf, h, c, Apack, bias, maxslots + L, oh, oc); break;
                case 2: conv_mfma_kernel<16><<<dim3(4, 8),  512, 0, stream>>>(corrbuf, h, c, Apack, bias, maxslots + L, oh, oc); break;
            }
        } else {
            wtrans_kernel<<<(PP * 242 * 9 * 4 + 255) / 256, 256, 0, stream>>>(Wsrc, Wt);
            switch (L) {
                case 3: conv_lstm_kernel<8, 4, 8, 512, 8, 1><<<dim3(2, 8, 8), 512, 0, stream>>>(corrbuf, h, c, Wt, bias, maxslots + L, oh, oc); break;
                case 4: conv_lstm_kernel<4, 4, 4, 256, 8, 1><<<dim3(1, 8, 8), 256, 0, stream>>>(corrbuf, h, c, Wt, bias, maxslots + L, oh, oc); break;
                case 5: conv_lstm_kernel<2, 2, 2, 256, 2, 1><<<dim3(1, 8, 2), 256, 0, stream>>>(corrbuf, h, c, Wt, bias, maxslots + L, oh, oc); break;
            }
        }
    }
}

// Round 4
// 862.433 us; speedup vs baseline: 9.0914x; 1.5080x over previous
//
#include <hip/hip_runtime.h>
#include <hip/hip_bf16.h>
#include <cstdint>
#include <cstddef>

#define PD 11
#define PP 121
#define NB 8

typedef _Float16 f16x8 __attribute__((ext_vector_type(8)));
typedef float    f32x4 __attribute__((ext_vector_type(4)));

// ---------------------------------------------------------------------------
__global__ void init_slots_kernel(unsigned* __restrict__ slots) {
    if (threadIdx.x < 8) slots[threadIdx.x] = 0x007FFFFFu;  // enc(-inf)
}

// zero corr buffer + init max slot (fallback/VALU path)
__global__ void zero_kernel(float* __restrict__ p, int n, unsigned* __restrict__ slot) {
    int i = blockIdx.x * 256 + threadIdx.x;
    if (i < n) p[i] = 0.f;
    if (i == 0) *slot = 0x007FFFFFu;
}

// ---------------------------------------------------------------------------
// small-level corr: one thread per (q, pixel), scalar accumulator (no spill),
// cache-resident inputs, fused leaky + block-max.
template<int C, int H>
__global__ __launch_bounds__(256) void corr_small_kernel(
    const float* __restrict__ x, const float* __restrict__ xp,
    float* __restrict__ corr, unsigned* __restrict__ slot)
{
    constexpr int PX  = H * H;
    constexpr int TOT = PP * PX;
    const int b = blockIdx.y;
    const int o = blockIdx.x * 256 + threadIdx.x;
    float v = -3.4e38f;
    if (o < TOT) {
        int q = o / PX;
        int p = o % PX;
        int y = p / H, xx = p % H;
        int sy = y + q / PD - 5, sx = xx + q % PD - 5;
        float acc = 0.f;
        if (sy >= 0 && sy < H && sx >= 0 && sx < H) {
            const float* xb  = x  + (size_t)b * C * PX + p;
            const float* xpb = xp + (size_t)b * C * PX + sy * H + sx;
#pragma unroll 8
            for (int c = 0; c < C; ++c)
                acc = fmaf(xb[c * PX], xpb[c * PX], acc);
        }
        float lv = acc > 0.f ? acc : 0.01f * acc;
        corr[((size_t)b * PP + q) * PX + p] = lv;
        v = lv;
    }
    for (int off = 32; off; off >>= 1) v = fmaxf(v, __shfl_down(v, off));
    __shared__ float sred[4];
    if ((threadIdx.x & 63) == 0) sred[threadIdx.x >> 6] = v;
    __syncthreads();
    if (threadIdx.x == 0) {
        float m = fmaxf(fmaxf(sred[0], sred[1]), fmaxf(sred[2], sred[3]));
        unsigned eb = __float_as_uint(m);
        eb = (eb & 0x80000000u) ? ~eb : (eb | 0x80000000u);
        atomicMax(slot, eb);
    }
}

// ---------------------------------------------------------------------------
// fp32 NCHW -> fp16 NHWC transpose (channel-last), tile 32c x 16x via LDS
template<int C, int H>
__global__ __launch_bounds__(256) void tpose_kernel(const float* __restrict__ in,
                                                    _Float16* __restrict__ out) {
    constexpr int W = H;
    constexpr int NXT = W / 16;
    const int t  = threadIdx.x;
    const int by = blockIdx.y;            // b*H + y
    const int b  = by / H, y = by % H;
    const int xc = (blockIdx.x % NXT) * 16;
    const int cc = (blockIdx.x / NXT) * 32;
    __shared__ float s[32][17];
    const int r = t >> 4, xcol = t & 15;
    s[r][xcol]      = in[((size_t)(b * C + cc + r) * H + y) * W + xc + xcol];
    s[r + 16][xcol] = in[((size_t)(b * C + cc + r + 16) * H + y) * W + xc + xcol];
    __syncthreads();
    int x = t >> 4, cp = (t & 15) * 2;
    union { _Float16 h[2]; unsigned u; } pk;
    pk.h[0] = (_Float16)s[cp][x];
    pk.h[1] = (_Float16)s[cp + 1][x];
    *(unsigned*)(out + ((size_t)(b * H + y) * W + xc + x) * C + cc + cp) = pk.u;
}

// ---------------------------------------------------------------------------
// MFMA correlation: per pixel tile, T[z][p] = sum_c xp_halo[z,c] * x[p,c]
// (GEMM over K=C), then corr[p][q] = T[p + d(q)][p], fused leaky + block max.
template<int C, int H, int TSY, int TSX>
__global__ __launch_bounds__(512, 1) void corr_mfma_kernel(
    const _Float16* __restrict__ xT, const _Float16* __restrict__ xpT,
    float* __restrict__ corr, unsigned* __restrict__ slot)
{
    constexpr int W  = H;
    constexpr int HY = TSY + 10, HX = TSX + 10;
    constexpr int MZ = HY * HX;
    constexpr int MT = (MZ + 15) / 16;
    constexpr int MTP = MT * 16;
    constexpr int MFRAG = (MT + 7) / 8;
    constexpr int NPX = TSY * TSX;       // power of 2
    constexpr int NT  = NPX / 16;
    constexpr int KC  = C / 32;
    constexpr int STAGE_B   = (MTP + NPX) * 64;
    constexpr int ST_STRIDE = NPX + 4;
    constexpr int ST_B      = MTP * ST_STRIDE * 4;
    constexpr int LDS_B     = STAGE_B > ST_B ? STAGE_B : ST_B;
    __shared__ char smem[LDS_B];
    __shared__ float sred[8];

    const int tid  = threadIdx.x;
    const int b    = blockIdx.y;
    constexpr int TXT = W / TSX;
    const int y0 = (blockIdx.x / TXT) * TSY;
    const int x0 = (blockIdx.x % TXT) * TSX;
    const int w = tid >> 6, lane = tid & 63;
    const int lcol = lane & 15, lkg = lane >> 4;

    f32x4 acc[MFRAG][NT];
#pragma unroll
    for (int i = 0; i < MFRAG; ++i)
#pragma unroll
        for (int nt = 0; nt < NT; ++nt)
            acc[i][nt] = (f32x4){0.f, 0.f, 0.f, 0.f};

#pragma unroll 1
    for (int kc = 0; kc < KC; ++kc) {
        __syncthreads();
        constexpr int UXP = MTP * 4;
        constexpr int U   = UXP + NPX * 4;
        for (int u = tid; u < U; u += 512) {
            f16x8 v = {0, 0, 0, 0, 0, 0, 0, 0};
            int dstbyte;
            if (u < UXP) {
                int z = u >> 2, kg = u & 3;
                dstbyte = z * 64 + (((kg ^ (z >> 2)) & 3) << 4);
                int zy = y0 + z / HX - 5, zx = x0 + z % HX - 5;
                if (z < MZ && zy >= 0 && zy < H && zx >= 0 && zx < W)
                    v = *(const f16x8*)(xpT + ((size_t)(b * H + zy) * W + zx) * C + kc * 32 + kg * 8);
            } else {
                int u2 = u - UXP;
                int p = u2 >> 2, kg = u2 & 3;
                dstbyte = MTP * 64 + p * 64 + (((kg ^ (p >> 2)) & 3) << 4);
                int gy = y0 + p / TSX, gx = x0 + p % TSX;
                v = *(const f16x8*)(xT + ((size_t)(b * H + gy) * W + gx) * C + kc * 32 + kg * 8);
            }
            *(f16x8*)(smem + dstbyte) = v;
        }
        __syncthreads();

        f16x8 bF[NT];
#pragma unroll
        for (int nt = 0; nt < NT; ++nt) {
            int p = nt * 16 + lcol;
            bF[nt] = *(const f16x8*)(smem + MTP * 64 + p * 64 + (((lkg ^ (p >> 2)) & 3) << 4));
        }
#pragma unroll
        for (int i = 0; i < MFRAG; ++i) {
            int mt = w + i * 8;
            if (mt < MT) {
                int z = mt * 16 + lcol;
                f16x8 aF = *(const f16x8*)(smem + z * 64 + (((lkg ^ (z >> 2)) & 3) << 4));
#pragma unroll
                for (int nt = 0; nt < NT; ++nt)
                    acc[i][nt] = __builtin_amdgcn_mfma_f32_16x16x32_f16(aF, bF[nt], acc[i][nt], 0, 0, 0);
            }
        }
    }
    __syncthreads();

    float* sT = (float*)smem;
#pragma unroll
    for (int i = 0; i < MFRAG; ++i) {
        int mt = w + i * 8;
        if (mt >= MT) continue;
        int z0 = mt * 16 + lkg * 4;
#pragma unroll
        for (int nt = 0; nt < NT; ++nt) {
            int p = nt * 16 + lcol;
#pragma unroll
            for (int r = 0; r < 4; ++r)
                sT[(z0 + r) * ST_STRIDE + p] = acc[i][nt][r];
        }
    }
    __syncthreads();

    float lmax = -3.4e38f;
    for (int o = tid; o < PP * NPX; o += 512) {
        int p = o & (NPX - 1);
        int q = o / NPX;
        int py = p / TSX, px = p % TSX;
        int dy = q / PD, dx = q % PD;
        float v = sT[((py + dy) * HX + (px + dx)) * ST_STRIDE + p];
        v = v > 0.f ? v : 0.01f * v;
        lmax = fmaxf(lmax, v);
        corr[(((size_t)b * PP + q) * H + (y0 + py)) * W + (x0 + px)] = v;
    }
    for (int off = 32; off; off >>= 1) lmax = fmaxf(lmax, __shfl_down(lmax, off));
    if (lane == 0) sred[w] = lmax;
    __syncthreads();
    if (tid == 0) {
        float m = sred[0];
        for (int i = 1; i < 8; ++i) m = fmaxf(m, sred[i]);
        unsigned eb = __float_as_uint(m);
        eb = (eb & 0x80000000u) ? ~eb : (eb | 0x80000000u);
        atomicMax(slot, eb);
    }
}

// ---------------------------------------------------------------------------
// VALU corr (fallback only)
template<int C, int H, int TH, int CS, int THREADS>
__global__ __launch_bounds__(THREADS) void corr_kernel(
    const float* __restrict__ x, const float* __restrict__ xp,
    float* __restrict__ corr)
{
    constexpr int W  = H;
    constexpr int RW = W + 10;
    constexpr int RR = TH + 10;
    constexpr int CC = 8;
    constexpr int CPER = C / CS;
    __shared__ float sXp[CC * RR * RW];

    const int tid = threadIdx.x;
    const int b  = blockIdx.y;
    const int y0 = blockIdx.x * TH;
    const int c_begin = blockIdx.z * CPER;
    const int row = tid / W;
    const int col = tid % W;
    const int y = y0 + row;
    const bool active = tid < TH * W;

    float acc[PP];
#pragma unroll
    for (int q = 0; q < PP; ++q) acc[q] = 0.f;

    for (int c0 = 0; c0 < CPER; c0 += CC) {
        __syncthreads();
        for (int fl = tid; fl < CC * RR * RW; fl += THREADS) {
            int c  = fl / (RR * RW);
            int r  = (fl / RW) % RR;
            int cx = fl % RW;
            int gy = y0 + r - 5;
            int gx = cx - 5;
            float v = 0.f;
            if (gy >= 0 && gy < H && gx >= 0 && gx < W)
                v = xp[(((size_t)b * C + (c_begin + c0 + c)) * H + gy) * W + gx];
            sXp[fl] = v;
        }
        __syncthreads();
        if (active) {
            for (int c = 0; c < CC; ++c) {
                float xv = x[(((size_t)b * C + (c_begin + c0 + c)) * H + y) * W + col];
                const float* lp = &sXp[(c * RR + row) * RW + col];
#pragma unroll
                for (int dy = 0; dy < PD; ++dy)
#pragma unroll
                    for (int dx = 0; dx < PD; ++dx)
                        acc[dy * PD + dx] = fmaf(xv, lp[dy * RW + dx], acc[dy * PD + dx]);
            }
        }
    }
    if (active) {
#pragma unroll
        for (int q = 0; q < PP; ++q)
            atomicAdd(&corr[(((size_t)b * PP + q) * H + y) * W + col], acc[q]);
    }
}

// ---------------------------------------------------------------------------
__global__ void leaky_max_kernel(float* __restrict__ corr, int S, unsigned* __restrict__ slot) {
    __shared__ float sred[16];
    float v = -3.4e38f;
    for (int i = blockIdx.x * blockDim.x + threadIdx.x; i < S; i += gridDim.x * blockDim.x) {
        float c = corr[i];
        c = c > 0.f ? c : 0.01f * c;
        corr[i] = c;
        v = fmaxf(v, c);
    }
    for (int off = 32; off; off >>= 1) v = fmaxf(v, __shfl_down(v, off));
    int wid = threadIdx.x >> 6;
    if ((threadIdx.x & 63) == 0) sred[wid] = v;
    __syncthreads();
    if (threadIdx.x == 0) {
        int nw = blockDim.x >> 6;
        float m = sred[0];
        for (int w = 1; w < nw; ++w) m = fmaxf(m, sred[w]);
        unsigned eb = __float_as_uint(m);
        eb = (eb & 0x80000000u) ? ~eb : (eb | 0x80000000u);
        atomicMax(slot, eb);
    }
}

// ---------------------------------------------------------------------------
__global__ void wtrans_kernel(const float* __restrict__ Wsrc, float* __restrict__ Wt) {
    int t = blockIdx.x * 256 + threadIdx.x;
    if (t >= PP * 242 * 9 * 4) return;
    int g  = t & 3;
    int kk = t >> 2;
    int k  = kk % 9;
    int icq = kk / 9;
    int ic = icq % 242;
    int q  = icq / 242;
    Wt[t] = Wsrc[(((g * PP + q) * 242 + ic) * 9) + k];
}

// ---------------------------------------------------------------------------
__global__ void pack_kernel(const float* __restrict__ Wsrc, _Float16* __restrict__ Apack) {
    int t = blockIdx.x * 256 + threadIdx.x;
    if (t >= 9 * 8 * 32 * 64 * 8) return;
    int e  = t & 7;
    int l  = (t >> 3) & 63;
    int mt = (t >> 9) & 31;
    int ks = (t >> 14) & 7;
    int k9 = t >> 17;
    int m    = mt * 16 + (l & 15);
    int kloc = (l >> 4) * 8 + e;
    int ic   = ks * 32 + kloc;
    float v = 0.f;
    if (m < 484 && ic < 242) {
        int q = m >> 2, g = m & 3;
        v = Wsrc[((g * PP + q) * 242 + ic) * 9 + k9];
    }
    Apack[t] = (_Float16)v;
}

// ---------------------------------------------------------------------------
template<int H>
__global__ __launch_bounds__(512, 4) void conv_mfma_kernel(
    const float* __restrict__ corr, const float* __restrict__ hpre,
    const float* __restrict__ cpre, const _Float16* __restrict__ Apack,
    const float* __restrict__ bias, const unsigned* __restrict__ maxslot,
    float* __restrict__ outh, float* __restrict__ outc)
{
    constexpr int W = H;
    constexpr int TILES_X = W / 16;
    __shared__ _Float16 sIn[6 * 18 * 256];

    const int tid  = threadIdx.x;
    const int b    = blockIdx.y;
    const int tile = blockIdx.x;
    const int ty0  = (tile / TILES_X) * 4;
    const int tx0  = (tile % TILES_X) * 16;

    unsigned mu = *maxslot;
    float maxv = (mu & 0x80000000u) ? __uint_as_float(mu ^ 0x80000000u) : __uint_as_float(~mu);
    float inv = 1.0f / maxv;

    char* sB = (char*)sIn;
    for (int it = 0; it < 27; ++it) {
        int flat = it * 512 + tid;
        int ix  = flat % 18;
        int iy  = (flat / 18) % 6;
        int icp = flat / 108;
        int gy = ty0 + iy - 1, gx = tx0 + ix - 1;
        float v0 = 0.f, v1 = 0.f;
        if (gy >= 0 && gy < H && gx >= 0 && gx < W) {
            int ic0 = icp * 2, ic1 = icp * 2 + 1;
            if (ic0 < PP)       v0 = corr[(((size_t)b * PP + ic0) * H + gy) * W + gx] * inv;
            else if (ic0 < 242) v0 = hpre[(((size_t)b * PP + (ic0 - PP)) * H + gy) * W + gx];
            if (ic1 < PP)       v1 = corr[(((size_t)b * PP + ic1) * H + gy) * W + gx] * inv;
            else if (ic1 < 242) v1 = hpre[(((size_t)b * PP + (ic1 - PP)) * H + gy) * W + gx];
        }
        union { _Float16 h[2]; unsigned u; } pk;
        pk.h[0] = (_Float16)v0; pk.h[1] = (_Float16)v1;
        int byteoff = ((iy * 18 + ix) * 256 + icp * 2) * 2;
        byteoff ^= ((ix & 7) << 4);
        *(unsigned*)(sB + byteoff) = pk.u;
    }
    __syncthreads();

    const int w    = tid >> 6;
    const int lane = tid & 63;
    const int pxx  = lane & 15;
    const int kg   = lane >> 4;

    f32x4 acc[4][4];
#pragma unroll
    for (int i = 0; i < 4; ++i) {
        int q = (w * 4 + i) * 4 + kg;
        f32x4 bv;
#pragma unroll
        for (int r = 0; r < 4; ++r) bv[r] = (q < PP) ? bias[r * PP + q] : 0.f;
#pragma unroll
        for (int nt = 0; nt < 4; ++nt) acc[i][nt] = bv;
    }

#pragma unroll 1
    for (int k9 = 0; k9 < 9; ++k9) {
        const int ky = k9 / 3, kx = k9 % 3;
        const int ix = pxx + kx;
        const int xsw = ((ix & 7) << 4);
        const f16x8* apb = (const f16x8*)Apack + ((size_t)(k9 * 8) * 32 + w * 4) * 64 + lane;
#pragma unroll 1
        for (int ks = 0; ks < 8; ++ks) {
            f16x8 bf[4];
#pragma unroll
            for (int nt = 0; nt < 4; ++nt) {
                int byteoff = (((nt + ky) * 18 + ix) * 512) + ks * 64 + kg * 16;
                bf[nt] = *(const f16x8*)(sB + (byteoff ^ xsw));
            }
            const f16x8* ap = apb + (size_t)ks * 32 * 64;
            f16x8 af4[4];
#pragma unroll
            for (int i = 0; i < 4; ++i) af4[i] = ap[i * 64];
#pragma unroll
            for (int i = 0; i < 4; ++i)
#pragma unroll
                for (int nt = 0; nt < 4; ++nt)
                    acc[i][nt] = __builtin_amdgcn_mfma_f32_16x16x32_f16(af4[i], bf[nt], acc[i][nt], 0, 0, 0);
        }
    }

    const int x = tx0 + pxx;
#pragma unroll
    for (int i = 0; i < 4; ++i) {
        int q = (w * 4 + i) * 4 + kg;
        if (q >= PP) continue;
#pragma unroll
        for (int nt = 0; nt < 4; ++nt) {
            int y = ty0 + nt;
            float ai = acc[i][nt][0];
            float af_ = acc[i][nt][1];
            float ao = acc[i][nt][2];
            float ag = acc[i][nt][3];
            float ig = 1.f / (1.f + expf(-ai));
            float fg = 1.f / (1.f + expf(-af_));
            float og = 1.f / (1.f + expf(-ao));
            float gg = tanhf(ag);
            size_t oidx = (((size_t)b * PP + q) * H + y) * W + x;
            float cp = cpre[oidx];
            float cn = fg * cp + ig * gg;
            outh[oidx] = og * tanhf(cn);
            outc[oidx] = cn;
        }
    }
}

// ---------------------------------------------------------------------------
template<int H, int TH, int TW, int THREADS, int QG, int J>
__global__ __launch_bounds__(THREADS) void conv_lstm_kernel(
    const float* __restrict__ corr, const float* __restrict__ hpre,
    const float* __restrict__ cpre, const float* __restrict__ Wt,
    const float* __restrict__ bias, const unsigned* __restrict__ maxslot,
    float* __restrict__ outh, float* __restrict__ outc)
{
    constexpr int W    = H;
    constexpr int PX   = TH * TW;
    constexpr int QS   = THREADS / PX;
    constexpr int SR   = TW + 2;
    constexpr int SROW = (TH + 2) * SR;
    constexpr int TILES_X = W / TW;
    __shared__ float sIn[242 * SROW];

    const int tid  = threadIdx.x;
    const int b    = blockIdx.y;
    const int tile = blockIdx.x;
    const int qg   = blockIdx.z;
    const int ty0  = (tile / TILES_X) * TH;
    const int tx0  = (tile % TILES_X) * TW;

    unsigned mu = *maxslot;
    float maxv = (mu & 0x80000000u) ? __uint_as_float(mu ^ 0x80000000u) : __uint_as_float(~mu);

    for (int fl = tid; fl < 242 * SROW; fl += THREADS) {
        int ic  = fl / SROW;
        int rem = fl % SROW;
        int iy  = rem / SR;
        int ix  = rem % SR;
        int gy = ty0 + iy - 1, gx = tx0 + ix - 1;
        float v = 0.f;
        if (gy >= 0 && gy < H && gx >= 0 && gx < W) {
            if (ic < PP) v = corr[(((size_t)b * PP + ic) * H + gy) * W + gx] / maxv;
            else         v = hpre[(((size_t)b * PP + (ic - PP)) * H + gy) * W + gx];
        }
        sIn[fl] = v;
    }
    __syncthreads();

    const int slot = tid / PX;
    const int px   = tid % PX;
    const int py = px / TW, pxx = px % TW;
    const int y = ty0 + py, x = tx0 + pxx;
    const float* lp0 = &sIn[py * SR + pxx];

    for (int j = 0; j < J; ++j) {
        int q = (qg * J + j) * QS + slot;
        if (q > 120) continue;
        float a0 = bias[q], a1 = bias[PP + q], a2 = bias[2 * PP + q], a3 = bias[3 * PP + q];
        const float4* wp = (const float4*)(Wt + (size_t)q * 242 * 9 * 4);
        for (int ic = 0; ic < 242; ++ic) {
            const float* lp = lp0 + ic * SROW;
#pragma unroll
            for (int ky = 0; ky < 3; ++ky)
#pragma unroll
                for (int kx = 0; kx < 3; ++kx) {
                    float v = lp[ky * SR + kx];
                    float4 wv = wp[ic * 9 + ky * 3 + kx];
                    a0 = fmaf(v, wv.x, a0);
                    a1 = fmaf(v, wv.y, a1);
                    a2 = fmaf(v, wv.z, a2);
                    a3 = fmaf(v, wv.w, a3);
                }
        }
        float ig = 1.f / (1.f + expf(-a0));
        float fg = 1.f / (1.f + expf(-a1));
        float og = 1.f / (1.f + expf(-a2));
        float gg = tanhf(a3);
        size_t oidx = (((size_t)b * PP + q) * H + y) * W + x;
        float cp = cpre[oidx];
        float cn = fg * cp + ig * gg;
        float hn = og * tanhf(cn);
        outh[oidx] = hn;
        outc[oidx] = cn;
    }
}

// ---------------------------------------------------------------------------
extern "C" void kernel_launch(void* const* d_in, const int* in_sizes, int n_in,
                              void* d_out, int out_size, void* d_ws, size_t ws_size,
                              hipStream_t stream) {
    (void)in_sizes; (void)n_in; (void)out_size;
    static const int HH[6] = {64, 32, 16, 8, 4, 2};

    unsigned* maxslots = (unsigned*)d_ws;
    float*     Wt    = (float*)((char*)d_ws + 256);
    _Float16*  Apack = (_Float16*)((char*)d_ws + 256);
    float* corrbuf   = (float*)((char*)d_ws + 256 + 4216832);
    _Float16* xTbuf  = (_Float16*)((char*)d_ws + 256 + 4216832 + 15872000);
    _Float16* xpTbuf = (_Float16*)((char*)d_ws + 256 + 4216832 + 15872000 + 33554432);
    const size_t ws_needed = 256 + 4216832 + 15872000 + 2ull * 33554432;
    const bool mfma_corr = ws_size >= ws_needed;

    float* out = (float*)d_out;
    size_t obase = 0;

    init_slots_kernel<<<1, 64, 0, stream>>>(maxslots);

    for (int L = 0; L < 6; ++L) {
        const float* x    = (const float*)d_in[6 * L + 0];
        const float* xp   = (const float*)d_in[6 * L + 1];
        const float* h    = (const float*)d_in[6 * L + 2];
        const float* c    = (const float*)d_in[6 * L + 3];
        const float* Wsrc = (const float*)d_in[6 * L + 4];
        const float* bias = (const float*)d_in[6 * L + 5];
        int Hh = HH[L];
        int S = NB * PP * Hh * Hh;
        float* oh = out + obase;
        float* oc = out + obase + S;
        obase += 2 * (size_t)S;

        if (L < 3 && mfma_corr) {
            switch (L) {
                case 0:
                    tpose_kernel<512, 64><<<dim3(4 * 16, NB * 64), 256, 0, stream>>>(x, xTbuf);
                    tpose_kernel<512, 64><<<dim3(4 * 16, NB * 64), 256, 0, stream>>>(xp, xpTbuf);
                    corr_mfma_kernel<512, 64, 8, 8><<<dim3(64, NB), 512, 0, stream>>>(xTbuf, xpTbuf, corrbuf, maxslots + L);
                    break;
                case 1:
                    tpose_kernel<1024, 32><<<dim3(2 * 32, NB * 32), 256, 0, stream>>>(x, xTbuf);
                    tpose_kernel<1024, 32><<<dim3(2 * 32, NB * 32), 256, 0, stream>>>(xp, xpTbuf);
                    corr_mfma_kernel<1024, 32, 4, 8><<<dim3(32, NB), 512, 0, stream>>>(xTbuf, xpTbuf, corrbuf, maxslots + L);
                    break;
                case 2:
                    tpose_kernel<512, 16><<<dim3(1 * 16, NB * 16), 256, 0, stream>>>(x, xTbuf);
                    tpose_kernel<512, 16><<<dim3(1 * 16, NB * 16), 256, 0, stream>>>(xp, xpTbuf);
                    corr_mfma_kernel<512, 16, 4, 4><<<dim3(16, NB), 512, 0, stream>>>(xTbuf, xpTbuf, corrbuf, maxslots + L);
                    break;
            }
        } else if (L < 3) {
            zero_kernel<<<(S + 255) / 256, 256, 0, stream>>>(corrbuf, S, maxslots + L);
            switch (L) {
                case 0: corr_kernel<512, 64, 4, 2, 256><<<dim3(16, 8, 2), 256, 0, stream>>>(x, xp, corrbuf); break;
                case 1: corr_kernel<1024, 32, 4, 4, 128><<<dim3(8, 8, 4), 128, 0, stream>>>(x, xp, corrbuf); break;
                case 2: corr_kernel<512, 16, 8, 8, 128><<<dim3(2, 8, 8), 128, 0, stream>>>(x, xp, corrbuf); break;
            }
            int gz = (S + 255) / 256; if (gz > 1024) gz = 1024;
            leaky_max_kernel<<<gz, 256, 0, stream>>>(corrbuf, S, maxslots + L);
        } else {
            // tiny levels: fused corr + leaky + max, scalar-per-thread
            switch (L) {
                case 3: corr_small_kernel<256, 8><<<dim3((PP * 64 + 255) / 256, NB), 256, 0, stream>>>(x, xp, corrbuf, maxslots + L); break;
                case 4: corr_small_kernel<256, 4><<<dim3((PP * 16 + 255) / 256, NB), 256, 0, stream>>>(x, xp, corrbuf, maxslots + L); break;
                case 5: corr_small_kernel<256, 2><<<dim3((PP * 4 + 255) / 256, NB), 256, 0, stream>>>(x, xp, corrbuf, maxslots + L); break;
            }
        }

        if (L < 3) {
            pack_kernel<<<(9 * 8 * 32 * 64 * 8) / 256, 256, 0, stream>>>(Wsrc, Apack);
            switch (L) {
                case 0: conv_mfma_kernel<64><<<dim3(64, 8), 512, 0, stream>>>(corrbuf, h, c, Apack, bias, maxslots + L, oh, oc); break;
                case 1: conv_mfma_kernel<32><<<dim3(16, 8), 512, 0, stream>>>(corrbuf, h, c, Apack, bias, maxslots + L, oh, oc); break;
                case 2: conv_mfma_kernel<16><<<dim3(4, 8),  512, 0, stream>>>(corrbuf, h, c, Apack, bias, maxslots + L, oh, oc); break;
            }
        } else {
            wtrans_kernel<<<(PP * 242 * 9 * 4 + 255) / 256, 256, 0, stream>>>(Wsrc, Wt);
            switch (L) {
                case 3: conv_lstm_kernel<8, 4, 8, 512, 8, 1><<<dim3(2, 8, 8), 512, 0, stream>>>(corrbuf, h, c, Wt, bias, maxslots + L, oh, oc); break;
                case 4: conv_lstm_kernel<4, 4, 4, 256, 8, 1><<<dim3(1, 8, 8), 256, 0, stream>>>(corrbuf, h, c, Wt, bias, maxslots + L, oh, oc); break;
                case 5: conv_lstm_kernel<2, 2, 2, 256, 2, 1><<<dim3(1, 8, 2), 256, 0, stream>>>(corrbuf, h, c, Wt, bias, maxslots + L, oh, oc); break;
            }
        }
    }
}

// Round 5
// 761.013 us; speedup vs baseline: 10.3030x; 1.1333x over previous
//
#include <hip/hip_runtime.h>
#include <hip/hip_bf16.h>
#include <cstdint>
#include <cstddef>

#define PD 11
#define PP 121
#define NB 8

typedef _Float16 f16x8 __attribute__((ext_vector_type(8)));
typedef float    f32x4 __attribute__((ext_vector_type(4)));

// ---------------------------------------------------------------------------
__global__ void init_slots_kernel(unsigned* __restrict__ slots) {
    if (threadIdx.x < 8) slots[threadIdx.x] = 0x007FFFFFu;  // enc(-inf)
}

// zero corr buffer + init max slot (fallback/VALU path)
__global__ void zero_kernel(float* __restrict__ p, int n, unsigned* __restrict__ slot) {
    int i = blockIdx.x * 256 + threadIdx.x;
    if (i < n) p[i] = 0.f;
    if (i == 0) *slot = 0x007FFFFFu;
}

// ---------------------------------------------------------------------------
// small-level corr: one thread per (q, pixel), scalar accumulator (no spill),
// cache-resident inputs, fused leaky + block-max.
template<int C, int H>
__global__ __launch_bounds__(256) void corr_small_kernel(
    const float* __restrict__ x, const float* __restrict__ xp,
    float* __restrict__ corr, unsigned* __restrict__ slot)
{
    constexpr int PX  = H * H;
    constexpr int TOT = PP * PX;
    const int b = blockIdx.y;
    const int o = blockIdx.x * 256 + threadIdx.x;
    float v = -3.4e38f;
    if (o < TOT) {
        int q = o / PX;
        int p = o % PX;
        int y = p / H, xx = p % H;
        int sy = y + q / PD - 5, sx = xx + q % PD - 5;
        float acc = 0.f;
        if (sy >= 0 && sy < H && sx >= 0 && sx < H) {
            const float* xb  = x  + (size_t)b * C * PX + p;
            const float* xpb = xp + (size_t)b * C * PX + sy * H + sx;
#pragma unroll 8
            for (int c = 0; c < C; ++c)
                acc = fmaf(xb[c * PX], xpb[c * PX], acc);
        }
        float lv = acc > 0.f ? acc : 0.01f * acc;
        corr[((size_t)b * PP + q) * PX + p] = lv;
        v = lv;
    }
    for (int off = 32; off; off >>= 1) v = fmaxf(v, __shfl_down(v, off));
    __shared__ float sred[4];
    if ((threadIdx.x & 63) == 0) sred[threadIdx.x >> 6] = v;
    __syncthreads();
    if (threadIdx.x == 0) {
        float m = fmaxf(fmaxf(sred[0], sred[1]), fmaxf(sred[2], sred[3]));
        unsigned eb = __float_as_uint(m);
        eb = (eb & 0x80000000u) ? ~eb : (eb | 0x80000000u);
        atomicMax(slot, eb);
    }
}

// ---------------------------------------------------------------------------
// fp32 NCHW -> fp16 NHWC transpose (channel-last), tile 32c x 16x via LDS
template<int C, int H>
__global__ __launch_bounds__(256) void tpose_kernel(const float* __restrict__ in,
                                                    _Float16* __restrict__ out) {
    constexpr int W = H;
    constexpr int NXT = W / 16;
    const int t  = threadIdx.x;
    const int by = blockIdx.y;            // b*H + y
    const int b  = by / H, y = by % H;
    const int xc = (blockIdx.x % NXT) * 16;
    const int cc = (blockIdx.x / NXT) * 32;
    __shared__ float s[32][17];
    const int r = t >> 4, xcol = t & 15;
    s[r][xcol]      = in[((size_t)(b * C + cc + r) * H + y) * W + xc + xcol];
    s[r + 16][xcol] = in[((size_t)(b * C + cc + r + 16) * H + y) * W + xc + xcol];
    __syncthreads();
    int x = t >> 4, cp = (t & 15) * 2;
    union { _Float16 h[2]; unsigned u; } pk;
    pk.h[0] = (_Float16)s[cp][x];
    pk.h[1] = (_Float16)s[cp + 1][x];
    *(unsigned*)(out + ((size_t)(b * H + y) * W + xc + x) * C + cc + cp) = pk.u;
}

// ---------------------------------------------------------------------------
// MFMA correlation: per pixel tile, T[z][p] = sum_c xp_halo[z,c] * x[p,c]
// (GEMM over K=C), then corr[p][q] = T[p + d(q)][p], fused leaky + block max.
template<int C, int H, int TSY, int TSX>
__global__ __launch_bounds__(512, 1) void corr_mfma_kernel(
    const _Float16* __restrict__ xT, const _Float16* __restrict__ xpT,
    float* __restrict__ corr, unsigned* __restrict__ slot)
{
    constexpr int W  = H;
    constexpr int HY = TSY + 10, HX = TSX + 10;
    constexpr int MZ = HY * HX;
    constexpr int MT = (MZ + 15) / 16;
    constexpr int MTP = MT * 16;
    constexpr int MFRAG = (MT + 7) / 8;
    constexpr int NPX = TSY * TSX;       // power of 2
    constexpr int NT  = NPX / 16;
    constexpr int KC  = C / 32;
    constexpr int STAGE_B   = (MTP + NPX) * 64;
    constexpr int ST_STRIDE = NPX + 4;
    constexpr int ST_B      = MTP * ST_STRIDE * 4;
    constexpr int LDS_B     = STAGE_B > ST_B ? STAGE_B : ST_B;
    __shared__ char smem[LDS_B];
    __shared__ float sred[8];

    const int tid  = threadIdx.x;
    const int b    = blockIdx.y;
    constexpr int TXT = W / TSX;
    const int y0 = (blockIdx.x / TXT) * TSY;
    const int x0 = (blockIdx.x % TXT) * TSX;
    const int w = tid >> 6, lane = tid & 63;
    const int lcol = lane & 15, lkg = lane >> 4;

    f32x4 acc[MFRAG][NT];
#pragma unroll
    for (int i = 0; i < MFRAG; ++i)
#pragma unroll
        for (int nt = 0; nt < NT; ++nt)
            acc[i][nt] = (f32x4){0.f, 0.f, 0.f, 0.f};

#pragma unroll 1
    for (int kc = 0; kc < KC; ++kc) {
        __syncthreads();
        constexpr int UXP = MTP * 4;
        constexpr int U   = UXP + NPX * 4;
        for (int u = tid; u < U; u += 512) {
            f16x8 v = {0, 0, 0, 0, 0, 0, 0, 0};
            int dstbyte;
            if (u < UXP) {
                int z = u >> 2, kg = u & 3;
                dstbyte = z * 64 + (((kg ^ (z >> 2)) & 3) << 4);
                int zy = y0 + z / HX - 5, zx = x0 + z % HX - 5;
                if (z < MZ && zy >= 0 && zy < H && zx >= 0 && zx < W)
                    v = *(const f16x8*)(xpT + ((size_t)(b * H + zy) * W + zx) * C + kc * 32 + kg * 8);
            } else {
                int u2 = u - UXP;
                int p = u2 >> 2, kg = u2 & 3;
                dstbyte = MTP * 64 + p * 64 + (((kg ^ (p >> 2)) & 3) << 4);
                int gy = y0 + p / TSX, gx = x0 + p % TSX;
                v = *(const f16x8*)(xT + ((size_t)(b * H + gy) * W + gx) * C + kc * 32 + kg * 8);
            }
            *(f16x8*)(smem + dstbyte) = v;
        }
        __syncthreads();

        f16x8 bF[NT];
#pragma unroll
        for (int nt = 0; nt < NT; ++nt) {
            int p = nt * 16 + lcol;
            bF[nt] = *(const f16x8*)(smem + MTP * 64 + p * 64 + (((lkg ^ (p >> 2)) & 3) << 4));
        }
#pragma unroll
        for (int i = 0; i < MFRAG; ++i) {
            int mt = w + i * 8;
            if (mt < MT) {
                int z = mt * 16 + lcol;
                f16x8 aF = *(const f16x8*)(smem + z * 64 + (((lkg ^ (z >> 2)) & 3) << 4));
#pragma unroll
                for (int nt = 0; nt < NT; ++nt)
                    acc[i][nt] = __builtin_amdgcn_mfma_f32_16x16x32_f16(aF, bF[nt], acc[i][nt], 0, 0, 0);
            }
        }
    }
    __syncthreads();

    float* sT = (float*)smem;
#pragma unroll
    for (int i = 0; i < MFRAG; ++i) {
        int mt = w + i * 8;
        if (mt >= MT) continue;
        int z0 = mt * 16 + lkg * 4;
#pragma unroll
        for (int nt = 0; nt < NT; ++nt) {
            int p = nt * 16 + lcol;
#pragma unroll
            for (int r = 0; r < 4; ++r)
                sT[(z0 + r) * ST_STRIDE + p] = acc[i][nt][r];
        }
    }
    __syncthreads();

    float lmax = -3.4e38f;
    for (int o = tid; o < PP * NPX; o += 512) {
        int p = o & (NPX - 1);
        int q = o / NPX;
        int py = p / TSX, px = p % TSX;
        int dy = q / PD, dx = q % PD;
        float v = sT[((py + dy) * HX + (px + dx)) * ST_STRIDE + p];
        v = v > 0.f ? v : 0.01f * v;
        lmax = fmaxf(lmax, v);
        corr[(((size_t)b * PP + q) * H + (y0 + py)) * W + (x0 + px)] = v;
    }
    for (int off = 32; off; off >>= 1) lmax = fmaxf(lmax, __shfl_down(lmax, off));
    if (lane == 0) sred[w] = lmax;
    __syncthreads();
    if (tid == 0) {
        float m = sred[0];
        for (int i = 1; i < 8; ++i) m = fmaxf(m, sred[i]);
        unsigned eb = __float_as_uint(m);
        eb = (eb & 0x80000000u) ? ~eb : (eb | 0x80000000u);
        atomicMax(slot, eb);
    }
}

// ---------------------------------------------------------------------------
// VALU corr (fallback only, if ws too small for MFMA path)
template<int C, int H, int TH, int CS, int THREADS>
__global__ __launch_bounds__(THREADS) void corr_kernel(
    const float* __restrict__ x, const float* __restrict__ xp,
    float* __restrict__ corr)
{
    constexpr int W  = H;
    constexpr int RW = W + 10;
    constexpr int RR = TH + 10;
    constexpr int CC = 8;
    constexpr int CPER = C / CS;
    __shared__ float sXp[CC * RR * RW];

    const int tid = threadIdx.x;
    const int b  = blockIdx.y;
    const int y0 = blockIdx.x * TH;
    const int c_begin = blockIdx.z * CPER;
    const int row = tid / W;
    const int col = tid % W;
    const int y = y0 + row;
    const bool active = tid < TH * W;

    float acc[PP];
#pragma unroll
    for (int q = 0; q < PP; ++q) acc[q] = 0.f;

    for (int c0 = 0; c0 < CPER; c0 += CC) {
        __syncthreads();
        for (int fl = tid; fl < CC * RR * RW; fl += THREADS) {
            int c  = fl / (RR * RW);
            int r  = (fl / RW) % RR;
            int cx = fl % RW;
            int gy = y0 + r - 5;
            int gx = cx - 5;
            float v = 0.f;
            if (gy >= 0 && gy < H && gx >= 0 && gx < W)
                v = xp[(((size_t)b * C + (c_begin + c0 + c)) * H + gy) * W + gx];
            sXp[fl] = v;
        }
        __syncthreads();
        if (active) {
            for (int c = 0; c < CC; ++c) {
                float xv = x[(((size_t)b * C + (c_begin + c0 + c)) * H + y) * W + col];
                const float* lp = &sXp[(c * RR + row) * RW + col];
#pragma unroll
                for (int dy = 0; dy < PD; ++dy)
#pragma unroll
                    for (int dx = 0; dx < PD; ++dx)
                        acc[dy * PD + dx] = fmaf(xv, lp[dy * RW + dx], acc[dy * PD + dx]);
            }
        }
    }
    if (active) {
#pragma unroll
        for (int q = 0; q < PP; ++q)
            atomicAdd(&corr[(((size_t)b * PP + q) * H + y) * W + col], acc[q]);
    }
}

// ---------------------------------------------------------------------------
__global__ void leaky_max_kernel(float* __restrict__ corr, int S, unsigned* __restrict__ slot) {
    __shared__ float sred[16];
    float v = -3.4e38f;
    for (int i = blockIdx.x * blockDim.x + threadIdx.x; i < S; i += gridDim.x * blockDim.x) {
        float c = corr[i];
        c = c > 0.f ? c : 0.01f * c;
        corr[i] = c;
        v = fmaxf(v, c);
    }
    for (int off = 32; off; off >>= 1) v = fmaxf(v, __shfl_down(v, off));
    int wid = threadIdx.x >> 6;
    if ((threadIdx.x & 63) == 0) sred[wid] = v;
    __syncthreads();
    if (threadIdx.x == 0) {
        int nw = blockDim.x >> 6;
        float m = sred[0];
        for (int w = 1; w < nw; ++w) m = fmaxf(m, sred[w]);
        unsigned eb = __float_as_uint(m);
        eb = (eb & 0x80000000u) ? ~eb : (eb | 0x80000000u);
        atomicMax(slot, eb);
    }
}

// ---------------------------------------------------------------------------
// weight pack for the MFMA conv (all levels): fragment-linear fp16.
// Apack[(((k9*8+ks)*32+mt)*64+l)*8+e] = W[m=mt*16+(l&15)][ic=ks*32+(l>>4)*8+e]
// with m = q*4+gate  (so one lane's 4 C-regs are the 4 gates of one q).
__global__ void pack_kernel(const float* __restrict__ Wsrc, _Float16* __restrict__ Apack) {
    int t = blockIdx.x * 256 + threadIdx.x;
    if (t >= 9 * 8 * 32 * 64 * 8) return;
    int e  = t & 7;
    int l  = (t >> 3) & 63;
    int mt = (t >> 9) & 31;
    int ks = (t >> 14) & 7;
    int k9 = t >> 17;
    int m    = mt * 16 + (l & 15);
    int kloc = (l >> 4) * 8 + e;
    int ic   = ks * 32 + kloc;
    float v = 0.f;
    if (m < 484 && ic < 242) {
        int q = m >> 2, g = m & 3;
        v = Wsrc[((g * PP + q) * 242 + ic) * 9 + k9];
    }
    Apack[t] = (_Float16)v;
}

// ---------------------------------------------------------------------------
// MFMA conv3x3 (242 -> 4*121) + fused LSTM, generalized pixel tile TR x TC.
// Block: 512 thr = 8 waves; M padded to 512 (32 m-tiles, 4 per wave).
// NPX = TR*TC pixels per block; NT = ceil(NPX/16) n-tiles (NPX<16 -> padded).
// Input tile channel-last fp16 in LDS [iy][ix][ic256], XOR-swizzled on ix.
template<int H, int TR, int TC>
__global__ __launch_bounds__(512, 4) void conv_mfma_kernel(
    const float* __restrict__ corr, const float* __restrict__ hpre,
    const float* __restrict__ cpre, const _Float16* __restrict__ Apack,
    const float* __restrict__ bias, const unsigned* __restrict__ maxslot,
    float* __restrict__ outh, float* __restrict__ outc)
{
    constexpr int W = H;
    constexpr int TILES_X = (W >= TC) ? (W / TC) : 1;
    constexpr int NPX   = TR * TC;
    constexpr int NT    = (NPX + 15) / 16;
    constexpr int SR    = TC + 2;
    constexpr int SROWS = TR + 2;
    constexpr int NPOS  = SROWS * SR;
    __shared__ _Float16 sIn[NPOS * 256];

    const int tid  = threadIdx.x;
    const int b    = blockIdx.y;
    const int tile = blockIdx.x;
    const int ty0  = (tile / TILES_X) * TR;
    const int tx0  = (tile % TILES_X) * TC;

    unsigned mu = *maxslot;
    float maxv = (mu & 0x80000000u) ? __uint_as_float(mu ^ 0x80000000u) : __uint_as_float(~mu);
    float inv = 1.0f / maxv;

    // ---- stage input tile (fp32 -> fp16, channel-last, swizzled) ----
    char* sB = (char*)sIn;
    constexpr int WORDS = NPOS * 128;    // u32 words (2 ch each)
    for (int flat = tid; flat < WORDS; flat += 512) {
        int ix  = flat % SR;
        int iy  = (flat / SR) % SROWS;
        int icp = flat / NPOS;
        int gy = ty0 + iy - 1, gx = tx0 + ix - 1;
        float v0 = 0.f, v1 = 0.f;
        if (gy >= 0 && gy < H && gx >= 0 && gx < W) {
            int ic0 = icp * 2, ic1 = icp * 2 + 1;
            if (ic0 < PP)       v0 = corr[(((size_t)b * PP + ic0) * H + gy) * W + gx] * inv;
            else if (ic0 < 242) v0 = hpre[(((size_t)b * PP + (ic0 - PP)) * H + gy) * W + gx];
            if (ic1 < PP)       v1 = corr[(((size_t)b * PP + ic1) * H + gy) * W + gx] * inv;
            else if (ic1 < 242) v1 = hpre[(((size_t)b * PP + (ic1 - PP)) * H + gy) * W + gx];
        }
        union { _Float16 h[2]; unsigned u; } pk;
        pk.h[0] = (_Float16)v0; pk.h[1] = (_Float16)v1;
        int byteoff = ((iy * SR + ix) * 256 + icp * 2) * 2;
        byteoff ^= ((ix & 7) << 4);
        *(unsigned*)(sB + byteoff) = pk.u;
    }
    __syncthreads();

    const int w    = tid >> 6;
    const int lane = tid & 63;
    const int lcol = lane & 15;
    const int kg   = lane >> 4;

    // ---- accumulators init = bias ----
    f32x4 acc[4][NT];
#pragma unroll
    for (int i = 0; i < 4; ++i) {
        int q = (w * 4 + i) * 4 + kg;
        f32x4 bv;
#pragma unroll
        for (int r = 0; r < 4; ++r) bv[r] = (q < PP) ? bias[r * PP + q] : 0.f;
#pragma unroll
        for (int nt = 0; nt < NT; ++nt) acc[i][nt] = bv;
    }

    // ---- K loop: 9 shifts x 8 k-steps of 32 ----
#pragma unroll 1
    for (int k9 = 0; k9 < 9; ++k9) {
        const int ky = k9 / 3, kx = k9 % 3;
        int basev[NT], xswv[NT];
#pragma unroll
        for (int nt = 0; nt < NT; ++nt) {
            int p = nt * 16 + lcol;
            int pc = (NPX < 16 && p >= NPX) ? 0 : p;
            int py = pc / TC, px = pc % TC;
            int iy = py + ky, ix = px + kx;
            basev[nt] = (iy * SR + ix) * 512 + kg * 16;
            xswv[nt]  = (ix & 7) << 4;
        }
        const f16x8* apb = (const f16x8*)Apack + ((size_t)(k9 * 8) * 32 + w * 4) * 64 + lane;
#pragma unroll 1
        for (int ks = 0; ks < 8; ++ks) {
            f16x8 bf[NT];
#pragma unroll
            for (int nt = 0; nt < NT; ++nt) {
                int byteoff = (basev[nt] + ks * 64) ^ xswv[nt];
                bf[nt] = *(const f16x8*)(sB + byteoff);
                if (NPX < 16 && nt * 16 + lcol >= NPX) bf[nt] = (f16x8){};
            }
            const f16x8* ap = apb + (size_t)ks * 32 * 64;
            f16x8 af4[4];
#pragma unroll
            for (int i = 0; i < 4; ++i) af4[i] = ap[i * 64];
#pragma unroll
            for (int i = 0; i < 4; ++i)
#pragma unroll
                for (int nt = 0; nt < NT; ++nt)
                    acc[i][nt] = __builtin_amdgcn_mfma_f32_16x16x32_f16(af4[i], bf[nt], acc[i][nt], 0, 0, 0);
        }
    }

    // ---- fused LSTM epilogue (lane-local: 4 regs = 4 gates of one q) ----
#pragma unroll
    for (int i = 0; i < 4; ++i) {
        int q = (w * 4 + i) * 4 + kg;
        if (q >= PP) continue;
#pragma unroll
        for (int nt = 0; nt < NT; ++nt) {
            int p = nt * 16 + lcol;
            if (NPX < 16 && p >= NPX) continue;
            int py = p / TC, px = p % TC;
            int y = ty0 + py, x = tx0 + px;
            float ai = acc[i][nt][0];
            float af_ = acc[i][nt][1];
            float ao = acc[i][nt][2];
            float ag = acc[i][nt][3];
            float ig = 1.f / (1.f + expf(-ai));
            float fg = 1.f / (1.f + expf(-af_));
            float og = 1.f / (1.f + expf(-ao));
            float gg = tanhf(ag);
            size_t oidx = (((size_t)b * PP + q) * H + y) * W + x;
            float cp = cpre[oidx];
            float cn = fg * cp + ig * gg;
            outh[oidx] = og * tanhf(cn);
            outc[oidx] = cn;
        }
    }
}

// ---------------------------------------------------------------------------
extern "C" void kernel_launch(void* const* d_in, const int* in_sizes, int n_in,
                              void* d_out, int out_size, void* d_ws, size_t ws_size,
                              hipStream_t stream) {
    (void)in_sizes; (void)n_in; (void)out_size;
    static const int HH[6] = {64, 32, 16, 8, 4, 2};

    unsigned* maxslots = (unsigned*)d_ws;
    _Float16*  Apack = (_Float16*)((char*)d_ws + 256);
    float* corrbuf   = (float*)((char*)d_ws + 256 + 4216832);
    _Float16* xTbuf  = (_Float16*)((char*)d_ws + 256 + 4216832 + 15872000);
    _Float16* xpTbuf = (_Float16*)((char*)d_ws + 256 + 4216832 + 15872000 + 33554432);
    const size_t ws_needed = 256 + 4216832 + 15872000 + 2ull * 33554432;
    const bool mfma_corr = ws_size >= ws_needed;

    float* out = (float*)d_out;
    size_t obase = 0;

    init_slots_kernel<<<1, 64, 0, stream>>>(maxslots);

    for (int L = 0; L < 6; ++L) {
        const float* x    = (const float*)d_in[6 * L + 0];
        const float* xp   = (const float*)d_in[6 * L + 1];
        const float* h    = (const float*)d_in[6 * L + 2];
        const float* c    = (const float*)d_in[6 * L + 3];
        const float* Wsrc = (const float*)d_in[6 * L + 4];
        const float* bias = (const float*)d_in[6 * L + 5];
        int Hh = HH[L];
        int S = NB * PP * Hh * Hh;
        float* oh = out + obase;
        float* oc = out + obase + S;
        obase += 2 * (size_t)S;

        if (L < 3 && mfma_corr) {
            switch (L) {
                case 0:
                    tpose_kernel<512, 64><<<dim3(4 * 16, NB * 64), 256, 0, stream>>>(x, xTbuf);
                    tpose_kernel<512, 64><<<dim3(4 * 16, NB * 64), 256, 0, stream>>>(xp, xpTbuf);
                    corr_mfma_kernel<512, 64, 8, 8><<<dim3(64, NB), 512, 0, stream>>>(xTbuf, xpTbuf, corrbuf, maxslots + L);
                    break;
                case 1:
                    tpose_kernel<1024, 32><<<dim3(2 * 32, NB * 32), 256, 0, stream>>>(x, xTbuf);
                    tpose_kernel<1024, 32><<<dim3(2 * 32, NB * 32), 256, 0, stream>>>(xp, xpTbuf);
                    corr_mfma_kernel<1024, 32, 4, 8><<<dim3(32, NB), 512, 0, stream>>>(xTbuf, xpTbuf, corrbuf, maxslots + L);
                    break;
                case 2:
                    tpose_kernel<512, 16><<<dim3(1 * 16, NB * 16), 256, 0, stream>>>(x, xTbuf);
                    tpose_kernel<512, 16><<<dim3(1 * 16, NB * 16), 256, 0, stream>>>(xp, xpTbuf);
                    corr_mfma_kernel<512, 16, 4, 4><<<dim3(16, NB), 512, 0, stream>>>(xTbuf, xpTbuf, corrbuf, maxslots + L);
                    break;
            }
        } else if (L < 3) {
            zero_kernel<<<(S + 255) / 256, 256, 0, stream>>>(corrbuf, S, maxslots + L);
            switch (L) {
                case 0: corr_kernel<512, 64, 4, 2, 256><<<dim3(16, 8, 2), 256, 0, stream>>>(x, xp, corrbuf); break;
                case 1: corr_kernel<1024, 32, 4, 4, 128><<<dim3(8, 8, 4), 128, 0, stream>>>(x, xp, corrbuf); break;
                case 2: corr_kernel<512, 16, 8, 8, 128><<<dim3(2, 8, 8), 128, 0, stream>>>(x, xp, corrbuf); break;
            }
            int gz = (S + 255) / 256; if (gz > 1024) gz = 1024;
            leaky_max_kernel<<<gz, 256, 0, stream>>>(corrbuf, S, maxslots + L);
        } else {
            switch (L) {
                case 3: corr_small_kernel<256, 8><<<dim3((PP * 64 + 255) / 256, NB), 256, 0, stream>>>(x, xp, corrbuf, maxslots + L); break;
                case 4: corr_small_kernel<256, 4><<<dim3((PP * 16 + 255) / 256, NB), 256, 0, stream>>>(x, xp, corrbuf, maxslots + L); break;
                case 5: corr_small_kernel<256, 2><<<dim3((PP * 4 + 255) / 256, NB), 256, 0, stream>>>(x, xp, corrbuf, maxslots + L); break;
            }
        }

        pack_kernel<<<(9 * 8 * 32 * 64 * 8) / 256, 256, 0, stream>>>(Wsrc, Apack);
        switch (L) {
            case 0: conv_mfma_kernel<64, 4, 16><<<dim3(64, 8), 512, 0, stream>>>(corrbuf, h, c, Apack, bias, maxslots + L, oh, oc); break;
            case 1: conv_mfma_kernel<32, 4, 16><<<dim3(16, 8), 512, 0, stream>>>(corrbuf, h, c, Apack, bias, maxslots + L, oh, oc); break;
            case 2: conv_mfma_kernel<16, 4, 16><<<dim3(4, 8),  512, 0, stream>>>(corrbuf, h, c, Apack, bias, maxslots + L, oh, oc); break;
            case 3: conv_mfma_kernel<8, 8, 8><<<dim3(1, 8),   512, 0, stream>>>(corrbuf, h, c, Apack, bias, maxslots + L, oh, oc); break;
            case 4: conv_mfma_kernel<4, 4, 4><<<dim3(1, 8),   512, 0, stream>>>(corrbuf, h, c, Apack, bias, maxslots + L, oh, oc); break;
            case 5: conv_mfma_kernel<2, 2, 2><<<dim3(1, 8),   512, 0, stream>>>(corrbuf, h, c, Apack, bias, maxslots + L, oh, oc); break;
        }
    }
}

// Round 6
// 650.692 us; speedup vs baseline: 12.0498x; 1.1695x over previous
//
#include <hip/hip_runtime.h>
#include <hip/hip_bf16.h>
#include <cstdint>
#include <cstddef>

#define PD 11
#define PP 121
#define NB 8

typedef _Float16 f16x8 __attribute__((ext_vector_type(8)));
typedef float    f32x4 __attribute__((ext_vector_type(4)));

// ---------------------------------------------------------------------------
__global__ void init_slots_kernel(unsigned* __restrict__ slots) {
    if (threadIdx.x < 8) slots[threadIdx.x] = 0x007FFFFFu;  // enc(-inf)
}

// ---------------------------------------------------------------------------
// fused fp32 NCHW -> fp16 NHWC transpose for x AND xp (blockIdx.z selects).
// Tile 64ch x TPX px; float4 reads, col-XOR LDS (conflict-free), f16x8 writes.
template<int C, int H, int TPX>
__global__ __launch_bounds__(256) void tpose_kernel(
    const float* __restrict__ xin, const float* __restrict__ xpin,
    _Float16* __restrict__ xT, _Float16* __restrict__ xpT)
{
    constexpr int W = H;
    const float* in  = blockIdx.z ? xpin : xin;
    _Float16*   out  = blockIdx.z ? xpT  : xT;
    const int by = blockIdx.y;            // b*H + y
    const int b  = by / H, y = by % H;
    constexpr int NXT = W / TPX;
    const int x0 = (blockIdx.x % NXT) * TPX;
    const int cc = (blockIdx.x / NXT) * 64;
    __shared__ float s[64][36];

    constexpr int NF4 = 64 * TPX / 4;
    for (int f = threadIdx.x; f < NF4; f += 256) {
        int r  = f / (TPX / 4);
        int xq = f % (TPX / 4);
        int col = (xq * 4) ^ (((r >> 3) & 7) * 4);
        *(float4*)&s[r][col] =
            *(const float4*)&in[((size_t)(b * C + cc + r) * H + y) * W + x0 + xq * 4];
    }
    __syncthreads();
    constexpr int NWT = TPX * 8;
    for (int t = threadIdx.x; t < NWT; t += 256) {
        int pix = t >> 3, ck = t & 7;
        union { _Float16 h[8]; f16x8 v; } d;
#pragma unroll
        for (int j = 0; j < 8; ++j)
            d.h[j] = (_Float16)s[ck * 8 + j][pix ^ (ck * 4)];
        *(f16x8*)&out[((size_t)(b * H + y) * W + x0 + pix) * C + cc + ck * 8] = d.v;
    }
}

// ---------------------------------------------------------------------------
// MFMA correlation: T[z][p] = sum_c xp_halo[z,c] * x[p,c] (GEMM over K=C),
// T staged to LDS as fp16, then gather writes leaky'd corr channels [0,128)
// of inT (unnormalized; build_kernel scales later) + block max -> atomicMax.
template<int C, int H, int TSY, int TSX>
__global__ __launch_bounds__(512, 1) void corr_mfma_kernel(
    const _Float16* __restrict__ xT, const _Float16* __restrict__ xpT,
    _Float16* __restrict__ inT, unsigned* __restrict__ slot)
{
    constexpr int W  = H;
    constexpr int HY = TSY + 10, HX = TSX + 10;
    constexpr int MZ = HY * HX;
    constexpr int MT = (MZ + 15) / 16;
    constexpr int MTP = MT * 16;
    constexpr int MFRAG = (MT + 7) / 8;
    constexpr int NPX = TSY * TSX;
    constexpr int NT  = NPX / 16;
    constexpr int KC  = C / 32;
    constexpr int STAGE_B = (MTP + NPX) * 64;
    constexpr int ST2     = NPX + 8;               // fp16 row stride
    constexpr int ST_B    = MTP * ST2 * 2;
    constexpr int LDS_B   = STAGE_B > ST_B ? STAGE_B : ST_B;
    __shared__ char smem[LDS_B];
    __shared__ float sred[8];

    const int tid  = threadIdx.x;
    const int b    = blockIdx.y;
    constexpr int TXT = W / TSX;
    const int y0 = (blockIdx.x / TXT) * TSY;
    const int x0 = (blockIdx.x % TXT) * TSX;
    const int w = tid >> 6, lane = tid & 63;
    const int lcol = lane & 15, lkg = lane >> 4;

    f32x4 acc[MFRAG][NT];
#pragma unroll
    for (int i = 0; i < MFRAG; ++i)
#pragma unroll
        for (int nt = 0; nt < NT; ++nt)
            acc[i][nt] = (f32x4){0.f, 0.f, 0.f, 0.f};

#pragma unroll 1
    for (int kc = 0; kc < KC; ++kc) {
        __syncthreads();
        constexpr int UXP = MTP * 4;
        constexpr int U   = UXP + NPX * 4;
        for (int u = tid; u < U; u += 512) {
            f16x8 v = {0, 0, 0, 0, 0, 0, 0, 0};
            int dstbyte;
            if (u < UXP) {
                int z = u >> 2, kg = u & 3;
                dstbyte = z * 64 + (((kg ^ (z >> 2)) & 3) << 4);
                int zy = y0 + z / HX - 5, zx = x0 + z % HX - 5;
                if (z < MZ && zy >= 0 && zy < H && zx >= 0 && zx < W)
                    v = *(const f16x8*)(xpT + ((size_t)(b * H + zy) * W + zx) * C + kc * 32 + kg * 8);
            } else {
                int u2 = u - UXP;
                int p = u2 >> 2, kg = u2 & 3;
                dstbyte = MTP * 64 + p * 64 + (((kg ^ (p >> 2)) & 3) << 4);
                int gy = y0 + p / TSX, gx = x0 + p % TSX;
                v = *(const f16x8*)(xT + ((size_t)(b * H + gy) * W + gx) * C + kc * 32 + kg * 8);
            }
            *(f16x8*)(smem + dstbyte) = v;
        }
        __syncthreads();

        f16x8 bF[NT];
#pragma unroll
        for (int nt = 0; nt < NT; ++nt) {
            int p = nt * 16 + lcol;
            bF[nt] = *(const f16x8*)(smem + MTP * 64 + p * 64 + (((lkg ^ (p >> 2)) & 3) << 4));
        }
#pragma unroll
        for (int i = 0; i < MFRAG; ++i) {
            int mt = w + i * 8;
            if (mt < MT) {
                int z = mt * 16 + lcol;
                f16x8 aF = *(const f16x8*)(smem + z * 64 + (((lkg ^ (z >> 2)) & 3) << 4));
#pragma unroll
                for (int nt = 0; nt < NT; ++nt)
                    acc[i][nt] = __builtin_amdgcn_mfma_f32_16x16x32_f16(aF, bF[nt], acc[i][nt], 0, 0, 0);
            }
        }
    }
    __syncthreads();

    // T -> LDS as fp16
    _Float16* sT = (_Float16*)smem;
#pragma unroll
    for (int i = 0; i < MFRAG; ++i) {
        int mt = w + i * 8;
        if (mt >= MT) continue;
        int z0 = mt * 16 + lkg * 4;
#pragma unroll
        for (int nt = 0; nt < NT; ++nt) {
            int p = nt * 16 + lcol;
#pragma unroll
            for (int r = 0; r < 4; ++r)
                sT[(z0 + r) * ST2 + p] = (_Float16)acc[i][nt][r];
        }
    }
    __syncthreads();

    // gather: thread (p, qg) -> 16 channels [qg*16, qg*16+16) of pixel p
    float lmax = -3.4e38f;
    if (tid < NPX * 8) {
        int p  = tid >> 3;
        int qg = tid & 7;
        int py = p / TSX, px = p % TSX;
        size_t pix = (size_t)(b * H + y0 + py) * W + (x0 + px);
        unsigned* dst = (unsigned*)(inT + pix * 256) + qg * 8;
#pragma unroll
        for (int j2 = 0; j2 < 8; ++j2) {
            int q0 = qg * 16 + j2 * 2, q1 = q0 + 1;
            int qc0 = q0 < PP ? q0 : PP - 1;
            int qc1 = q1 < PP ? q1 : PP - 1;
            float v0 = (float)sT[((py + qc0 / PD) * HX + (px + qc0 % PD)) * ST2 + p];
            float v1 = (float)sT[((py + qc1 / PD) * HX + (px + qc1 % PD)) * ST2 + p];
            v0 = v0 > 0.f ? v0 : 0.01f * v0;
            v1 = v1 > 0.f ? v1 : 0.01f * v1;
            if (q0 < PP) lmax = fmaxf(lmax, v0);
            if (q1 < PP) lmax = fmaxf(lmax, v1);
            union { _Float16 h[2]; unsigned u; } pk;
            pk.h[0] = (_Float16)v0; pk.h[1] = (_Float16)v1;
            dst[j2] = pk.u;
        }
    }
    for (int off = 32; off; off >>= 1) lmax = fmaxf(lmax, __shfl_down(lmax, off));
    if (lane == 0) sred[w] = lmax;
    __syncthreads();
    if (tid == 0) {
        float m = sred[0];
        for (int i = 1; i < 8; ++i) m = fmaxf(m, sred[i]);
        unsigned eb = __float_as_uint(m);
        eb = (eb & 0x80000000u) ? ~eb : (eb | 0x80000000u);
        atomicMax(slot, eb);
    }
}

// ---------------------------------------------------------------------------
// small-level corr: one thread per (pixel, q) -> writes inT channel q (2B,
// q-contiguous across lanes), fused leaky + block max.
template<int C, int H>
__global__ __launch_bounds__(256) void corr_small_kernel(
    const float* __restrict__ x, const float* __restrict__ xp,
    _Float16* __restrict__ inT, unsigned* __restrict__ slot)
{
    constexpr int PX  = H * H;
    constexpr int TOT = PX * PP;
    const int b = blockIdx.y;
    const int o = blockIdx.x * 256 + threadIdx.x;
    float v = -3.4e38f;
    if (o < TOT) {
        int p = o / PP;
        int q = o % PP;
        int y = p / H, xx = p % H;
        int sy = y + q / PD - 5, sx = xx + q % PD - 5;
        float acc = 0.f;
        if (sy >= 0 && sy < H && sx >= 0 && sx < H) {
            const float* xb  = x  + (size_t)b * C * PX + p;
            const float* xpb = xp + (size_t)b * C * PX + sy * H + sx;
#pragma unroll 8
            for (int c = 0; c < C; ++c)
                acc = fmaf(xb[c * PX], xpb[c * PX], acc);
        }
        float lv = acc > 0.f ? acc : 0.01f * acc;
        inT[((size_t)b * PX + p) * 256 + q] = (_Float16)lv;
        v = lv;
    }
    for (int off = 32; off; off >>= 1) v = fmaxf(v, __shfl_down(v, off));
    __shared__ float sred[4];
    if ((threadIdx.x & 63) == 0) sred[threadIdx.x >> 6] = v;
    __syncthreads();
    if (threadIdx.x == 0) {
        float m = fmaxf(fmaxf(sred[0], sred[1]), fmaxf(sred[2], sred[3]));
        unsigned eb = __float_as_uint(m);
        eb = (eb & 0x80000000u) ? ~eb : (eb | 0x80000000u);
        atomicMax(slot, eb);
    }
}

// ---------------------------------------------------------------------------
// build inT: scale corr channels [0,121) by 1/max, fill [121,242) from hpre,
// zero [242,256). Chunk-major mapping (coalesced hpre reads).
template<int H>
__global__ __launch_bounds__(256) void build_kernel(
    _Float16* __restrict__ inT, const float* __restrict__ hpre,
    const unsigned* __restrict__ slot)
{
    constexpr int HW = H * H;
    constexpr int NP = NB * HW;
    int idx = blockIdx.x * 256 + threadIdx.x;
    if (idx >= NP * 32) return;
    int c   = idx / NP;
    int pix = idx % NP;
    int b = pix / HW, p2 = pix % HW;
    unsigned mu = *slot;
    float maxv = (mu & 0x80000000u) ? __uint_as_float(mu ^ 0x80000000u) : __uint_as_float(~mu);
    float inv = 1.0f / maxv;
    _Float16* base = inT + (size_t)pix * 256 + c * 8;
    union { _Float16 h[8]; uint4 u; } d;
    if (c <= 14) {
        d.u = *(const uint4*)base;
#pragma unroll
        for (int j = 0; j < 8; ++j) d.h[j] = (_Float16)((float)d.h[j] * inv);
    } else if (c == 15) {
        d.u = *(const uint4*)base;
        d.h[0] = (_Float16)((float)d.h[0] * inv);              // ch 120
#pragma unroll
        for (int j = 1; j < 8; ++j)                            // ch 121..127 = h 0..6
            d.h[j] = (_Float16)hpre[((size_t)b * PP + (j - 1)) * HW + p2];
    } else if (c <= 29) {
#pragma unroll
        for (int j = 0; j < 8; ++j)                            // h 7..118
            d.h[j] = (_Float16)hpre[((size_t)b * PP + (c * 8 + j - 121)) * HW + p2];
    } else if (c == 30) {
        d.h[0] = (_Float16)hpre[((size_t)b * PP + 119) * HW + p2];
        d.h[1] = (_Float16)hpre[((size_t)b * PP + 120) * HW + p2];
#pragma unroll
        for (int j = 2; j < 8; ++j) d.h[j] = (_Float16)0.f;
    } else {
#pragma unroll
        for (int j = 0; j < 8; ++j) d.h[j] = (_Float16)0.f;
    }
    *(uint4*)base = d.u;
}

// ---------------------------------------------------------------------------
// weight pack: Apack[(((k9*8+ks)*32+mt)*64+l)*8+e] = W[m=mt*16+(l&15)][ic],
// ic = ks*32+(l>>4)*8+e, m = q*4+gate.
__global__ void pack_kernel(const float* __restrict__ Wsrc, _Float16* __restrict__ Apack) {
    int t = blockIdx.x * 256 + threadIdx.x;
    if (t >= 9 * 8 * 32 * 64 * 8) return;
    int e  = t & 7;
    int l  = (t >> 3) & 63;
    int mt = (t >> 9) & 31;
    int ks = (t >> 14) & 7;
    int k9 = t >> 17;
    int m    = mt * 16 + (l & 15);
    int kloc = (l >> 4) * 8 + e;
    int ic   = ks * 32 + kloc;
    float v = 0.f;
    if (m < 484 && ic < 242) {
        int q = m >> 2, g = m & 3;
        v = Wsrc[((g * PP + q) * 242 + ic) * 9 + k9];
    }
    Apack[t] = (_Float16)v;
}

// ---------------------------------------------------------------------------
// MFMA conv3x3 (242 -> 4*121) + fused LSTM, pixel tile TR x TC; input from
// pre-built inT (normalized fp16 channel-last) -> staging is pure f16x8 copy.
template<int H, int TR, int TC>
__global__ __launch_bounds__(512, 4) void conv_mfma_kernel(
    const _Float16* __restrict__ inT, const float* __restrict__ cpre,
    const _Float16* __restrict__ Apack, const float* __restrict__ bias,
    float* __restrict__ outh, float* __restrict__ outc)
{
    constexpr int W = H;
    constexpr int TILES_X = (W >= TC) ? (W / TC) : 1;
    constexpr int NPX   = TR * TC;
    constexpr int NT    = (NPX + 15) / 16;
    constexpr int SR    = TC + 2;
    constexpr int SROWS = TR + 2;
    constexpr int NPOS  = SROWS * SR;
    __shared__ _Float16 sIn[NPOS * 256];

    const int tid  = threadIdx.x;
    const int b    = blockIdx.y;
    const int tile = blockIdx.x;
    const int ty0  = (tile / TILES_X) * TR;
    const int tx0  = (tile % TILES_X) * TC;

    // ---- stage input tile: uniform f16x8 copies, linear 16B LDS writes ----
    char* sB = (char*)sIn;
    constexpr int CHUNKS = NPOS * 32;
    for (int flat = tid; flat < CHUNKS; flat += 512) {
        int cg  = flat & 31;
        int pos = flat >> 5;
        int iy = pos / SR, ix = pos % SR;
        int gy = ty0 + iy - 1, gx = tx0 + ix - 1;
        f16x8 v = {0, 0, 0, 0, 0, 0, 0, 0};
        if (gy >= 0 && gy < H && gx >= 0 && gx < W)
            v = *(const f16x8*)(inT + ((size_t)(b * H + gy) * W + gx) * 256 + cg * 8);
        int dst = (pos * 512 + cg * 16) ^ ((ix & 7) << 4);
        *(f16x8*)(sB + dst) = v;
    }
    __syncthreads();

    const int w    = tid >> 6;
    const int lane = tid & 63;
    const int lcol = lane & 15;
    const int kg   = lane >> 4;

    f32x4 acc[4][NT];
#pragma unroll
    for (int i = 0; i < 4; ++i) {
        int q = (w * 4 + i) * 4 + kg;
        f32x4 bv;
#pragma unroll
        for (int r = 0; r < 4; ++r) bv[r] = (q < PP) ? bias[r * PP + q] : 0.f;
#pragma unroll
        for (int nt = 0; nt < NT; ++nt) acc[i][nt] = bv;
    }

#pragma unroll 1
    for (int k9 = 0; k9 < 9; ++k9) {
        const int ky = k9 / 3, kx = k9 % 3;
        int basev[NT], xswv[NT];
#pragma unroll
        for (int nt = 0; nt < NT; ++nt) {
            int p = nt * 16 + lcol;
            int pc = (NPX < 16 && p >= NPX) ? 0 : p;
            int py = pc / TC, px = pc % TC;
            int iy = py + ky, ix = px + kx;
            basev[nt] = (iy * SR + ix) * 512 + kg * 16;
            xswv[nt]  = (ix & 7) << 4;
        }
        const f16x8* apb = (const f16x8*)Apack + ((size_t)(k9 * 8) * 32 + w * 4) * 64 + lane;
#pragma unroll 1
        for (int ks = 0; ks < 8; ++ks) {
            f16x8 bf[NT];
#pragma unroll
            for (int nt = 0; nt < NT; ++nt) {
                int byteoff = (basev[nt] + ks * 64) ^ xswv[nt];
                bf[nt] = *(const f16x8*)(sB + byteoff);
                if (NPX < 16 && nt * 16 + lcol >= NPX) bf[nt] = (f16x8){};
            }
            const f16x8* ap = apb + (size_t)ks * 32 * 64;
            f16x8 af4[4];
#pragma unroll
            for (int i = 0; i < 4; ++i) af4[i] = ap[i * 64];
#pragma unroll
            for (int i = 0; i < 4; ++i)
#pragma unroll
                for (int nt = 0; nt < NT; ++nt)
                    acc[i][nt] = __builtin_amdgcn_mfma_f32_16x16x32_f16(af4[i], bf[nt], acc[i][nt], 0, 0, 0);
        }
    }

    // ---- fused LSTM epilogue ----
#pragma unroll
    for (int i = 0; i < 4; ++i) {
        int q = (w * 4 + i) * 4 + kg;
        if (q >= PP) continue;
#pragma unroll
        for (int nt = 0; nt < NT; ++nt) {
            int p = nt * 16 + lcol;
            if (NPX < 16 && p >= NPX) continue;
            int py = p / TC, px = p % TC;
            int y = ty0 + py, x = tx0 + px;
            float ai = acc[i][nt][0];
            float af_ = acc[i][nt][1];
            float ao = acc[i][nt][2];
            float ag = acc[i][nt][3];
            float ig = 1.f / (1.f + expf(-ai));
            float fg = 1.f / (1.f + expf(-af_));
            float og = 1.f / (1.f + expf(-ao));
            float gg = tanhf(ag);
            size_t oidx = (((size_t)b * PP + q) * H + y) * W + x;
            float cp = cpre[oidx];
            float cn = fg * cp + ig * gg;
            outh[oidx] = og * tanhf(cn);
            outc[oidx] = cn;
        }
    }
}

// ---------------------------------------------------------------------------
extern "C" void kernel_launch(void* const* d_in, const int* in_sizes, int n_in,
                              void* d_out, int out_size, void* d_ws, size_t ws_size,
                              hipStream_t stream) {
    (void)in_sizes; (void)n_in; (void)out_size; (void)ws_size;
    static const int HH[6] = {64, 32, 16, 8, 4, 2};

    unsigned* maxslots = (unsigned*)d_ws;
    _Float16* Apack = (_Float16*)((char*)d_ws + 256);
    _Float16* inT   = (_Float16*)((char*)d_ws + 2359808);
    _Float16* xT    = (_Float16*)((char*)d_ws + 19137024);
    _Float16* xpT   = (_Float16*)((char*)d_ws + 52691456);   // end 86,245,888 B

    float* out = (float*)d_out;
    size_t obase = 0;

    init_slots_kernel<<<1, 64, 0, stream>>>(maxslots);

    for (int L = 0; L < 6; ++L) {
        const float* x    = (const float*)d_in[6 * L + 0];
        const float* xp   = (const float*)d_in[6 * L + 1];
        const float* h    = (const float*)d_in[6 * L + 2];
        const float* c    = (const float*)d_in[6 * L + 3];
        const float* Wsrc = (const float*)d_in[6 * L + 4];
        const float* bias = (const float*)d_in[6 * L + 5];
        int Hh = HH[L];
        int S = NB * PP * Hh * Hh;
        float* oh = out + obase;
        float* oc = out + obase + S;
        obase += 2 * (size_t)S;

        // ---- corr -> inT channels [0,121) + global max ----
        switch (L) {
            case 0:
                tpose_kernel<512, 64, 32><<<dim3(2 * 8, NB * 64, 2), 256, 0, stream>>>(x, xp, xT, xpT);
                corr_mfma_kernel<512, 64, 8, 8><<<dim3(64, NB), 512, 0, stream>>>(xT, xpT, inT, maxslots + L);
                break;
            case 1:
                tpose_kernel<1024, 32, 32><<<dim3(1 * 16, NB * 32, 2), 256, 0, stream>>>(x, xp, xT, xpT);
                corr_mfma_kernel<1024, 32, 4, 8><<<dim3(32, NB), 512, 0, stream>>>(xT, xpT, inT, maxslots + L);
                break;
            case 2:
                tpose_kernel<512, 16, 16><<<dim3(1 * 8, NB * 16, 2), 256, 0, stream>>>(x, xp, xT, xpT);
                corr_mfma_kernel<512, 16, 4, 4><<<dim3(16, NB), 512, 0, stream>>>(xT, xpT, inT, maxslots + L);
                break;
            case 3: corr_small_kernel<256, 8><<<dim3((64 * PP + 255) / 256, NB), 256, 0, stream>>>(x, xp, inT, maxslots + L); break;
            case 4: corr_small_kernel<256, 4><<<dim3((16 * PP + 255) / 256, NB), 256, 0, stream>>>(x, xp, inT, maxslots + L); break;
            case 5: corr_small_kernel<256, 2><<<dim3((4 * PP + 255) / 256, NB), 256, 0, stream>>>(x, xp, inT, maxslots + L); break;
        }

        // ---- normalize + h-fill + zero-pad ----
        switch (L) {
            case 0: build_kernel<64><<<(NB * 64 * 64 * 32) / 256, 256, 0, stream>>>(inT, h, maxslots + L); break;
            case 1: build_kernel<32><<<(NB * 32 * 32 * 32) / 256, 256, 0, stream>>>(inT, h, maxslots + L); break;
            case 2: build_kernel<16><<<(NB * 16 * 16 * 32) / 256, 256, 0, stream>>>(inT, h, maxslots + L); break;
            case 3: build_kernel<8><<<(NB * 8 * 8 * 32) / 256, 256, 0, stream>>>(inT, h, maxslots + L); break;
            case 4: build_kernel<4><<<(NB * 4 * 4 * 32) / 256, 256, 0, stream>>>(inT, h, maxslots + L); break;
            case 5: build_kernel<2><<<(NB * 2 * 2 * 32) / 256, 256, 0, stream>>>(inT, h, maxslots + L); break;
        }

        pack_kernel<<<(9 * 8 * 32 * 64 * 8) / 256, 256, 0, stream>>>(Wsrc, Apack);

        switch (L) {
            case 0: conv_mfma_kernel<64, 4, 16><<<dim3(64, 8), 512, 0, stream>>>(inT, c, Apack, bias, oh, oc); break;
            case 1: conv_mfma_kernel<32, 4, 16><<<dim3(16, 8), 512, 0, stream>>>(inT, c, Apack, bias, oh, oc); break;
            case 2: conv_mfma_kernel<16, 4, 16><<<dim3(4, 8),  512, 0, stream>>>(inT, c, Apack, bias, oh, oc); break;
            case 3: conv_mfma_kernel<8, 8, 8><<<dim3(1, 8),    512, 0, stream>>>(inT, c, Apack, bias, oh, oc); break;
            case 4: conv_mfma_kernel<4, 4, 4><<<dim3(1, 8),    512, 0, stream>>>(inT, c, Apack, bias, oh, oc); break;
            case 5: conv_mfma_kernel<2, 2, 2><<<dim3(1, 8),    512, 0, stream>>>(inT, c, Apack, bias, oh, oc); break;
        }
    }
}

// Round 8
// 575.085 us; speedup vs baseline: 13.6340x; 1.1315x over previous
//
#include <hip/hip_runtime.h>
#include <hip/hip_bf16.h>
#include <cstdint>
#include <cstddef>

#define PD 11
#define PP 121
#define NB 8

typedef _Float16 f16x8 __attribute__((ext_vector_type(8)));
typedef float    f32x4 __attribute__((ext_vector_type(4)));

// async global->LDS, 16B per lane, dest = lds_base + lane*16
#define GLOAD16(SRC, DST) __builtin_amdgcn_global_load_lds( \
    (const __attribute__((address_space(1))) void*)(SRC),   \
    (__attribute__((address_space(3))) void*)(DST), 16, 0, 0)

// ---------------------------------------------------------------------------
__global__ void init_kernel(unsigned* __restrict__ slots, float* __restrict__ zg) {
    int t = threadIdx.x;
    if (t < 8) slots[t] = 0x007FFFFFu;  // enc(-inf)
    for (int i = t; i < 1024; i += 256) zg[i] = 0.f;
}

// ---------------------------------------------------------------------------
// fused fp32 NCHW -> fp16 NHWC transpose for x AND xp (blockIdx.z selects).
template<int C, int H, int TPX>
__global__ __launch_bounds__(256) void tpose_kernel(
    const float* __restrict__ xin, const float* __restrict__ xpin,
    _Float16* __restrict__ xT, _Float16* __restrict__ xpT)
{
    constexpr int W = H;
    const float* in  = blockIdx.z ? xpin : xin;
    _Float16*   out  = blockIdx.z ? xpT  : xT;
    const int by = blockIdx.y;            // b*H + y
    const int b  = by / H, y = by % H;
    constexpr int NXT = W / TPX;
    const int x0 = (blockIdx.x % NXT) * TPX;
    const int cc = (blockIdx.x / NXT) * 64;
    __shared__ float s[64][36];

    constexpr int NF4 = 64 * TPX / 4;
    for (int f = threadIdx.x; f < NF4; f += 256) {
        int r  = f / (TPX / 4);
        int xq = f % (TPX / 4);
        int col = (xq * 4) ^ (((r >> 3) & 7) * 4);
        *(float4*)&s[r][col] =
            *(const float4*)&in[((size_t)(b * C + cc + r) * H + y) * W + x0 + xq * 4];
    }
    __syncthreads();
    constexpr int NWT = TPX * 8;
    for (int t = threadIdx.x; t < NWT; t += 256) {
        int pix = t >> 3, ck = t & 7;
        union { _Float16 h[8]; f16x8 v; } d;
#pragma unroll
        for (int j = 0; j < 8; ++j)
            d.h[j] = (_Float16)s[ck * 8 + j][pix ^ (ck * 4)];
        *(f16x8*)&out[((size_t)(b * H + y) * W + x0 + pix) * C + cc + ck * 8] = d.v;
    }
}

// ---------------------------------------------------------------------------
// MFMA correlation, double-buffered gload_lds staging.
// T[z][p] = sum_c xp_halo[z,c]*x[p,c]; gather corr[p][q] = T[p+d(q)][p]
// -> inT channels [0,128) (unnormalized) + block max -> atomicMax.
template<int C, int H, int TSY, int TSX>
__global__ __launch_bounds__(512, 2) void corr_mfma_kernel(
    const _Float16* __restrict__ xT, const _Float16* __restrict__ xpT,
    const _Float16* __restrict__ zg,
    _Float16* __restrict__ inT, unsigned* __restrict__ slot)
{
    constexpr int W  = H;
    constexpr int HY = TSY + 10, HX = TSX + 10;
    constexpr int MZ = HY * HX;
    constexpr int MT = (MZ + 15) / 16;
    constexpr int MTP = MT * 16;
    constexpr int MFRAG = (MT + 7) / 8;
    constexpr int NPX = TSY * TSX;
    constexpr int NT  = NPX / 16;
    constexpr int KC  = C / 32;
    constexpr int ABYTES = MTP * 64;
    constexpr int BUF    = ABYTES + NPX * 64;
    constexpr int NLOAD  = BUF / 1024;
    constexpr int ST2    = NPX + 8;
    constexpr int ST_B   = MTP * ST2 * 2;
    constexpr int LDS_B  = (2 * BUF > ST_B) ? 2 * BUF : ST_B;
    __shared__ char smem[LDS_B];
    __shared__ float sred[8];

    const int tid  = threadIdx.x;
    const int b    = blockIdx.y;
    constexpr int TXT = W / TSX;
    const int y0 = (blockIdx.x / TXT) * TSY;
    const int x0 = (blockIdx.x % TXT) * TSX;
    const int w = tid >> 6, lane = tid & 63;
    const int lcol = lane & 15, lkg = lane >> 4;

    auto STAGE = [&](int bufsel, int kc) {
        char* dstb = smem + bufsel * BUF;
        int c = lane & 3;
        for (int it = w; it < NLOAD; it += 8) {
            const void* src;
            if (it < MTP / 16) {
                int z = it * 16 + (lane >> 2);
                int zy = y0 + z / HX - 5, zx = x0 + z % HX - 5;
                if (z < MZ && zy >= 0 && zy < H && zx >= 0 && zx < W)
                    src = xpT + ((size_t)(b * H + zy) * W + zx) * C + kc * 32 + ((c ^ (z >> 2)) & 3) * 8;
                else
                    src = zg + lane * 8;
            } else {
                int p = (it - MTP / 16) * 16 + (lane >> 2);
                int gy = y0 + p / TSX, gx = x0 + p % TSX;
                src = xT + ((size_t)(b * H + gy) * W + gx) * C + kc * 32 + ((c ^ (p >> 2)) & 3) * 8;
            }
            GLOAD16(src, dstb + it * 1024);
        }
    };

    f32x4 acc[MFRAG][NT];
#pragma unroll
    for (int i = 0; i < MFRAG; ++i)
#pragma unroll
        for (int nt = 0; nt < NT; ++nt)
            acc[i][nt] = (f32x4){0.f, 0.f, 0.f, 0.f};

    STAGE(0, 0);
    __syncthreads();
#pragma unroll 1
    for (int kc = 0; kc < KC; ++kc) {
        if (kc + 1 < KC) STAGE((kc + 1) & 1, kc + 1);
        const char* bb = smem + (kc & 1) * BUF;
        f16x8 bF[NT];
#pragma unroll
        for (int nt = 0; nt < NT; ++nt) {
            int p = nt * 16 + lcol;
            bF[nt] = *(const f16x8*)(bb + ABYTES + p * 64 + (((lkg ^ (p >> 2)) & 3) << 4));
        }
#pragma unroll
        for (int i = 0; i < MFRAG; ++i) {
            int mt = w + i * 8;
            if (mt < MT) {
                int z = mt * 16 + lcol;
                f16x8 aF = *(const f16x8*)(bb + z * 64 + (((lkg ^ (z >> 2)) & 3) << 4));
#pragma unroll
                for (int nt = 0; nt < NT; ++nt)
                    acc[i][nt] = __builtin_amdgcn_mfma_f32_16x16x32_f16(aF, bF[nt], acc[i][nt], 0, 0, 0);
            }
        }
        __syncthreads();
    }

    // T -> LDS as fp16
    _Float16* sT = (_Float16*)smem;
#pragma unroll
    for (int i = 0; i < MFRAG; ++i) {
        int mt = w + i * 8;
        if (mt >= MT) continue;
        int z0 = mt * 16 + lkg * 4;
#pragma unroll
        for (int nt = 0; nt < NT; ++nt) {
            int p = nt * 16 + lcol;
#pragma unroll
            for (int r = 0; r < 4; ++r)
                sT[(z0 + r) * ST2 + p] = (_Float16)acc[i][nt][r];
        }
    }
    __syncthreads();

    // gather: thread (p, qg) -> 16 channels of pixel p
    float lmax = -3.4e38f;
    if (tid < NPX * 8) {
        int p  = tid >> 3;
        int qg = tid & 7;
        int py = p / TSX, px = p % TSX;
        size_t pix = (size_t)(b * H + y0 + py) * W + (x0 + px);
        unsigned* dst = (unsigned*)(inT + pix * 256) + qg * 8;
#pragma unroll
        for (int j2 = 0; j2 < 8; ++j2) {
            int q0 = qg * 16 + j2 * 2, q1 = q0 + 1;
            int qc0 = q0 < PP ? q0 : PP - 1;
            int qc1 = q1 < PP ? q1 : PP - 1;
            float v0 = (float)sT[((py + qc0 / PD) * HX + (px + qc0 % PD)) * ST2 + p];
            float v1 = (float)sT[((py + qc1 / PD) * HX + (px + qc1 % PD)) * ST2 + p];
            v0 = v0 > 0.f ? v0 : 0.01f * v0;
            v1 = v1 > 0.f ? v1 : 0.01f * v1;
            if (q0 < PP) lmax = fmaxf(lmax, v0);
            if (q1 < PP) lmax = fmaxf(lmax, v1);
            union { _Float16 h[2]; unsigned u; } pk;
            pk.h[0] = (_Float16)v0; pk.h[1] = (_Float16)v1;
            dst[j2] = pk.u;
        }
    }
    for (int off = 32; off; off >>= 1) lmax = fmaxf(lmax, __shfl_down(lmax, off));
    if (lane == 0) sred[w] = lmax;
    __syncthreads();
    if (tid == 0) {
        float m = sred[0];
        for (int i = 1; i < 8; ++i) m = fmaxf(m, sred[i]);
        unsigned eb = __float_as_uint(m);
        eb = (eb & 0x80000000u) ? ~eb : (eb | 0x80000000u);
        atomicMax(slot, eb);
    }
}

// ---------------------------------------------------------------------------
// small-level corr (cache-resident), writes inT channel q directly.
template<int C, int H>
__global__ __launch_bounds__(256) void corr_small_kernel(
    const float* __restrict__ x, const float* __restrict__ xp,
    _Float16* __restrict__ inT, unsigned* __restrict__ slot)
{
    constexpr int PX  = H * H;
    constexpr int TOT = PX * PP;
    const int b = blockIdx.y;
    const int o = blockIdx.x * 256 + threadIdx.x;
    float v = -3.4e38f;
    if (o < TOT) {
        int p = o / PP;
        int q = o % PP;
        int y = p / H, xx = p % H;
        int sy = y + q / PD - 5, sx = xx + q % PD - 5;
        float acc = 0.f;
        if (sy >= 0 && sy < H && sx >= 0 && sx < H) {
            const float* xb  = x  + (size_t)b * C * PX + p;
            const float* xpb = xp + (size_t)b * C * PX + sy * H + sx;
#pragma unroll 8
            for (int c = 0; c < C; ++c)
                acc = fmaf(xb[c * PX], xpb[c * PX], acc);
        }
        float lv = acc > 0.f ? acc : 0.01f * acc;
        inT[((size_t)b * PX + p) * 256 + q] = (_Float16)lv;
        v = lv;
    }
    for (int off = 32; off; off >>= 1) v = fmaxf(v, __shfl_down(v, off));
    __shared__ float sred[4];
    if ((threadIdx.x & 63) == 0) sred[threadIdx.x >> 6] = v;
    __syncthreads();
    if (threadIdx.x == 0) {
        float m = fmaxf(fmaxf(sred[0], sred[1]), fmaxf(sred[2], sred[3]));
        unsigned eb = __float_as_uint(m);
        eb = (eb & 0x80000000u) ? ~eb : (eb | 0x80000000u);
        atomicMax(slot, eb);
    }
}

// ---------------------------------------------------------------------------
// build inT: scale corr ch [0,121) by 1/max, fill [121,242) from hpre, pad 0.
template<int H>
__global__ __launch_bounds__(256) void build_kernel(
    _Float16* __restrict__ inT, const float* __restrict__ hpre,
    const unsigned* __restrict__ slot)
{
    constexpr int HW = H * H;
    constexpr int NP = NB * HW;
    int idx = blockIdx.x * 256 + threadIdx.x;
    if (idx >= NP * 32) return;
    int c   = idx / NP;
    int pix = idx % NP;
    int b = pix / HW, p2 = pix % HW;
    unsigned mu = *slot;
    float maxv = (mu & 0x80000000u) ? __uint_as_float(mu ^ 0x80000000u) : __uint_as_float(~mu);
    float inv = 1.0f / maxv;
    _Float16* base = inT + (size_t)pix * 256 + c * 8;
    union { _Float16 h[8]; uint4 u; } d;
    if (c <= 14) {
        d.u = *(const uint4*)base;
#pragma unroll
        for (int j = 0; j < 8; ++j) d.h[j] = (_Float16)((float)d.h[j] * inv);
    } else if (c == 15) {
        d.u = *(const uint4*)base;
        d.h[0] = (_Float16)((float)d.h[0] * inv);
#pragma unroll
        for (int j = 1; j < 8; ++j)
            d.h[j] = (_Float16)hpre[((size_t)b * PP + (j - 1)) * HW + p2];
    } else if (c <= 29) {
#pragma unroll
        for (int j = 0; j < 8; ++j)
            d.h[j] = (_Float16)hpre[((size_t)b * PP + (c * 8 + j - 121)) * HW + p2];
    } else if (c == 30) {
        d.h[0] = (_Float16)hpre[((size_t)b * PP + 119) * HW + p2];
        d.h[1] = (_Float16)hpre[((size_t)b * PP + 120) * HW + p2];
#pragma unroll
        for (int j = 2; j < 8; ++j) d.h[j] = (_Float16)0.f;
    } else {
#pragma unroll
        for (int j = 0; j < 8; ++j) d.h[j] = (_Float16)0.f;
    }
    *(uint4*)base = d.u;
}

// ---------------------------------------------------------------------------
// weight pack (fragment-linear fp16, m = q*4+gate)
__global__ void pack_kernel(const float* __restrict__ Wsrc, _Float16* __restrict__ Apack) {
    int t = blockIdx.x * 256 + threadIdx.x;
    if (t >= 9 * 8 * 32 * 64 * 8) return;
    int e  = t & 7;
    int l  = (t >> 3) & 63;
    int mt = (t >> 9) & 31;
    int ks = (t >> 14) & 7;
    int k9 = t >> 17;
    int m    = mt * 16 + (l & 15);
    int kloc = (l >> 4) * 8 + e;
    int ic   = ks * 32 + kloc;
    float v = 0.f;
    if (m < 484 && ic < 242) {
        int q = m >> 2, g = m & 3;
        v = Wsrc[((g * PP + q) * 242 + ic) * 9 + k9];
    }
    Apack[t] = (_Float16)v;
}

// ---------------------------------------------------------------------------
// conv v2: 8x16 pixel tile (N=128), optional M-split; gload_lds staging.
// Per wave: TPW = 32/MSPLIT tiles; tile t -> mt=(w*TPW+t)>>3, nt=(w*TPW+t)&7.
template<int H, int MSPLIT>
__global__ __launch_bounds__(512, 2) void conv_mfma2_kernel(
    const _Float16* __restrict__ inT, const float* __restrict__ cpre,
    const _Float16* __restrict__ Apack, const float* __restrict__ bias,
    const _Float16* __restrict__ zg,
    float* __restrict__ outh, float* __restrict__ outc)
{
    constexpr int W = H;
    constexpr int TR = 8, TC = 16, SR = TC + 2;
    constexpr int NPOS = (TR + 2) * SR;   // 180
    constexpr int MT_BLK = 32 / MSPLIT;
    constexpr int TPW = MT_BLK;
    constexpr int AF = (TPW + 7) / 8;
    constexpr int BF = TPW < 8 ? TPW : 8;
    constexpr int TILES_X = W / TC;
    __shared__ _Float16 sIn[NPOS * 256];  // 92160 B

    const int tid  = threadIdx.x;
    const int b    = blockIdx.y;
    const int mblk = blockIdx.z;
    const int tile = blockIdx.x;
    const int ty0  = (tile / TILES_X) * TR;
    const int tx0  = (tile % TILES_X) * TC;
    const int w = tid >> 6, lane = tid & 63;
    const int lcol = lane & 15, kg = lane >> 4;

    // ---- stage tile via global_load_lds (linear dest, pre-swizzled src) ----
    char* sB = (char*)sIn;
    for (int it = w; it < NPOS / 2; it += 8) {
        int r  = it * 2 + (lane >> 5);
        int c  = lane & 31;
        int iy = r / SR, ix = r % SR;
        int gy = ty0 + iy - 1, gx = tx0 + ix - 1;
        const void* src;
        if (gy >= 0 && gy < H && gx >= 0 && gx < W)
            src = inT + ((size_t)(b * H + gy) * W + gx) * 256 + (c ^ (ix & 7)) * 8;
        else
            src = zg + lane * 8;
        GLOAD16(src, sB + it * 1024);
    }
    __syncthreads();

    const int base_mt = (w * TPW) >> 3;
    const int nt_base = (w * TPW) & 7;

    f32x4 acc[TPW];
#pragma unroll
    for (int t = 0; t < TPW; ++t) {
        int mtg = mblk * MT_BLK + base_mt + (t >> 3);
        int q = mtg * 4 + kg;
        f32x4 bv;
#pragma unroll
        for (int r = 0; r < 4; ++r) bv[r] = (q < PP) ? bias[r * PP + q] : 0.f;
        acc[t] = bv;
    }

#pragma unroll 1
    for (int k9 = 0; k9 < 9; ++k9) {
        const int ky = k9 / 3, kx = k9 % 3;
        const int ix = lcol + kx;
        const int bxsw = (ix & 7) << 4;
        int bbase[BF];
#pragma unroll
        for (int j = 0; j < BF; ++j)
            bbase[j] = ((nt_base + j + ky) * SR + ix) * 512 + kg * 16;
        const f16x8* apb = (const f16x8*)Apack +
            ((size_t)(k9 * 8) * 32 + mblk * MT_BLK + base_mt) * 64 + lane;
#pragma unroll 1
        for (int ks = 0; ks < 8; ++ks) {
            f16x8 bf[BF];
#pragma unroll
            for (int j = 0; j < BF; ++j)
                bf[j] = *(const f16x8*)(sB + ((bbase[j] + ks * 64) ^ bxsw));
            const f16x8* ap = apb + (size_t)ks * 32 * 64;
            f16x8 af[AF];
#pragma unroll
            for (int a = 0; a < AF; ++a) af[a] = ap[a * 64];
#pragma unroll
            for (int t = 0; t < TPW; ++t)
                acc[t] = __builtin_amdgcn_mfma_f32_16x16x32_f16(af[t >> 3], bf[t & 7], acc[t], 0, 0, 0);
        }
    }

    // ---- fused LSTM epilogue ----
#pragma unroll
    for (int t = 0; t < TPW; ++t) {
        int mtg = mblk * MT_BLK + base_mt + (t >> 3);
        int q = mtg * 4 + kg;
        if (q >= PP) continue;
        int nt = nt_base + (t & 7);
        int y = ty0 + nt, x = tx0 + lcol;
        float ai = acc[t][0];
        float af_ = acc[t][1];
        float ao = acc[t][2];
        float ag = acc[t][3];
        float ig = 1.f / (1.f + expf(-ai));
        float fg = 1.f / (1.f + expf(-af_));
        float og = 1.f / (1.f + expf(-ao));
        float gg = tanhf(ag);
        size_t oidx = (((size_t)b * PP + q) * H + y) * W + x;
        float cp = cpre[oidx];
        float cn = fg * cp + ig * gg;
        outh[oidx] = og * tanhf(cn);
        outc[oidx] = cn;
    }
}

// ---------------------------------------------------------------------------
// conv (old template) for tiny levels H=8/4/2
template<int H, int TR, int TC>
__global__ __launch_bounds__(512, 4) void conv_mfma_kernel(
    const _Float16* __restrict__ inT, const float* __restrict__ cpre,
    const _Float16* __restrict__ Apack, const float* __restrict__ bias,
    float* __restrict__ outh, float* __restrict__ outc)
{
    constexpr int W = H;
    constexpr int TILES_X = (W >= TC) ? (W / TC) : 1;
    constexpr int NPX   = TR * TC;
    constexpr int NT    = (NPX + 15) / 16;
    constexpr int SR    = TC + 2;
    constexpr int SROWS = TR + 2;
    constexpr int NPOS  = SROWS * SR;
    __shared__ _Float16 sIn[NPOS * 256];

    const int tid  = threadIdx.x;
    const int b    = blockIdx.y;
    const int tile = blockIdx.x;
    const int ty0  = (tile / TILES_X) * TR;
    const int tx0  = (tile % TILES_X) * TC;

    char* sB = (char*)sIn;
    constexpr int CHUNKS = NPOS * 32;
    for (int flat = tid; flat < CHUNKS; flat += 512) {
        int cg  = flat & 31;
        int pos = flat >> 5;
        int iy = pos / SR, ix = pos % SR;
        int gy = ty0 + iy - 1, gx = tx0 + ix - 1;
        f16x8 v = {0, 0, 0, 0, 0, 0, 0, 0};
        if (gy >= 0 && gy < H && gx >= 0 && gx < W)
            v = *(const f16x8*)(inT + ((size_t)(b * H + gy) * W + gx) * 256 + cg * 8);
        int dst = (pos * 512 + cg * 16) ^ ((ix & 7) << 4);
        *(f16x8*)(sB + dst) = v;
    }
    __syncthreads();

    const int w    = tid >> 6;
    const int lane = tid & 63;
    const int lcol = lane & 15;
    const int kg   = lane >> 4;

    f32x4 acc[4][NT];
#pragma unroll
    for (int i = 0; i < 4; ++i) {
        int q = (w * 4 + i) * 4 + kg;
        f32x4 bv;
#pragma unroll
        for (int r = 0; r < 4; ++r) bv[r] = (q < PP) ? bias[r * PP + q] : 0.f;
#pragma unroll
        for (int nt = 0; nt < NT; ++nt) acc[i][nt] = bv;
    }

#pragma unroll 1
    for (int k9 = 0; k9 < 9; ++k9) {
        const int ky = k9 / 3, kx = k9 % 3;
        int basev[NT], xswv[NT];
#pragma unroll
        for (int nt = 0; nt < NT; ++nt) {
            int p = nt * 16 + lcol;
            int pc = (NPX < 16 && p >= NPX) ? 0 : p;
            int py = pc / TC, px = pc % TC;
            int iy = py + ky, ix = px + kx;
            basev[nt] = (iy * SR + ix) * 512 + kg * 16;
            xswv[nt]  = (ix & 7) << 4;
        }
        const f16x8* apb = (const f16x8*)Apack + ((size_t)(k9 * 8) * 32 + w * 4) * 64 + lane;
#pragma unroll 1
        for (int ks = 0; ks < 8; ++ks) {
            f16x8 bf[NT];
#pragma unroll
            for (int nt = 0; nt < NT; ++nt) {
                int byteoff = (basev[nt] + ks * 64) ^ xswv[nt];
                bf[nt] = *(const f16x8*)(sB + byteoff);
                if (NPX < 16 && nt * 16 + lcol >= NPX) bf[nt] = (f16x8){};
            }
            const f16x8* ap = apb + (size_t)ks * 32 * 64;
            f16x8 af4[4];
#pragma unroll
            for (int i = 0; i < 4; ++i) af4[i] = ap[i * 64];
#pragma unroll
            for (int i = 0; i < 4; ++i)
#pragma unroll
                for (int nt = 0; nt < NT; ++nt)
                    acc[i][nt] = __builtin_amdgcn_mfma_f32_16x16x32_f16(af4[i], bf[nt], acc[i][nt], 0, 0, 0);
        }
    }

#pragma unroll
    for (int i = 0; i < 4; ++i) {
        int q = (w * 4 + i) * 4 + kg;
        if (q >= PP) continue;
#pragma unroll
        for (int nt = 0; nt < NT; ++nt) {
            int p = nt * 16 + lcol;
            if (NPX < 16 && p >= NPX) continue;
            int py = p / TC, px = p % TC;
            int y = ty0 + py, x = tx0 + px;
            float ai = acc[i][nt][0];
            float af_ = acc[i][nt][1];
            float ao = acc[i][nt][2];
            float ag = acc[i][nt][3];
            float ig = 1.f / (1.f + expf(-ai));
            float fg = 1.f / (1.f + expf(-af_));
            float og = 1.f / (1.f + expf(-ao));
            float gg = tanhf(ag);
            size_t oidx = (((size_t)b * PP + q) * H + y) * W + x;
            float cp = cpre[oidx];
            float cn = fg * cp + ig * gg;
            outh[oidx] = og * tanhf(cn);
            outc[oidx] = cn;
        }
    }
}

// ---------------------------------------------------------------------------
extern "C" void kernel_launch(void* const* d_in, const int* in_sizes, int n_in,
                              void* d_out, int out_size, void* d_ws, size_t ws_size,
                              hipStream_t stream) {
    (void)in_sizes; (void)n_in; (void)out_size; (void)ws_size;
    static const int HH[6] = {64, 32, 16, 8, 4, 2};

    unsigned* maxslots = (unsigned*)d_ws;
    _Float16* Apack = (_Float16*)((char*)d_ws + 256);
    _Float16* inT   = (_Float16*)((char*)d_ws + 2359808);
    _Float16* xT    = (_Float16*)((char*)d_ws + 19137024);
    _Float16* xpT   = (_Float16*)((char*)d_ws + 52691456);
    _Float16* zg    = (_Float16*)((char*)d_ws + 86245888);   // 4KB zero guard

    float* out = (float*)d_out;
    size_t obase = 0;

    init_kernel<<<1, 256, 0, stream>>>(maxslots, (float*)zg);

    for (int L = 0; L < 6; ++L) {
        const float* x    = (const float*)d_in[6 * L + 0];
        const float* xp   = (const float*)d_in[6 * L + 1];
        const float* h    = (const float*)d_in[6 * L + 2];
        const float* c    = (const float*)d_in[6 * L + 3];
        const float* Wsrc = (const float*)d_in[6 * L + 4];
        const float* bias = (const float*)d_in[6 * L + 5];
        int Hh = HH[L];
        int S = NB * PP * Hh * Hh;
        float* oh = out + obase;
        float* oc = out + obase + S;
        obase += 2 * (size_t)S;

        // ---- corr -> inT channels [0,121) + global max ----
        switch (L) {
            case 0:
                tpose_kernel<512, 64, 32><<<dim3(16, NB * 64, 2), 256, 0, stream>>>(x, xp, xT, xpT);
                corr_mfma_kernel<512, 64, 8, 8><<<dim3(64, NB), 512, 0, stream>>>(xT, xpT, zg, inT, maxslots + L);
                break;
            case 1:
                tpose_kernel<1024, 32, 32><<<dim3(16, NB * 32, 2), 256, 0, stream>>>(x, xp, xT, xpT);
                corr_mfma_kernel<1024, 32, 4, 8><<<dim3(32, NB), 512, 0, stream>>>(xT, xpT, zg, inT, maxslots + L);
                break;
            case 2:
                tpose_kernel<512, 16, 16><<<dim3(8, NB * 16, 2), 256, 0, stream>>>(x, xp, xT, xpT);
                corr_mfma_kernel<512, 16, 4, 4><<<dim3(16, NB), 512, 0, stream>>>(xT, xpT, zg, inT, maxslots + L);
                break;
            case 3: corr_small_kernel<256, 8><<<dim3((64 * PP + 255) / 256, NB), 256, 0, stream>>>(x, xp, inT, maxslots + L); break;
            case 4: corr_small_kernel<256, 4><<<dim3((16 * PP + 255) / 256, NB), 256, 0, stream>>>(x, xp, inT, maxslots + L); break;
            case 5: corr_small_kernel<256, 2><<<dim3((4 * PP + 255) / 256, NB), 256, 0, stream>>>(x, xp, inT, maxslots + L); break;
        }

        // ---- normalize + h-fill + zero-pad ----
        switch (L) {
            case 0: build_kernel<64><<<(NB * 64 * 64 * 32) / 256, 256, 0, stream>>>(inT, h, maxslots + L); break;
            case 1: build_kernel<32><<<(NB * 32 * 32 * 32) / 256, 256, 0, stream>>>(inT, h, maxslots + L); break;
            case 2: build_kernel<16><<<(NB * 16 * 16 * 32) / 256, 256, 0, stream>>>(inT, h, maxslots + L); break;
            case 3: build_kernel<8><<<(NB * 8 * 8 * 32) / 256, 256, 0, stream>>>(inT, h, maxslots + L); break;
            case 4: build_kernel<4><<<(NB * 4 * 4 * 32) / 256, 256, 0, stream>>>(inT, h, maxslots + L); break;
            case 5: build_kernel<2><<<(NB * 2 * 2 * 32) / 256, 256, 0, stream>>>(inT, h, maxslots + L); break;
        }

        pack_kernel<<<(9 * 8 * 32 * 64 * 8) / 256, 256, 0, stream>>>(Wsrc, Apack);

        switch (L) {
            case 0: conv_mfma2_kernel<64, 1><<<dim3(32, 8, 1), 512, 0, stream>>>(inT, c, Apack, bias, zg, oh, oc); break;
            case 1: conv_mfma2_kernel<32, 4><<<dim3(8, 8, 4), 512, 0, stream>>>(inT, c, Apack, bias, zg, oh, oc); break;
            case 2: conv_mfma2_kernel<16, 16><<<dim3(2, 8, 16), 512, 0, stream>>>(inT, c, Apack, bias, zg, oh, oc); break;
            case 3: conv_mfma_kernel<8, 8, 8><<<dim3(1, 8), 512, 0, stream>>>(inT, c, Apack, bias, oh, oc); break;
            case 4: conv_mfma_kernel<4, 4, 4><<<dim3(1, 8), 512, 0, stream>>>(inT, c, Apack, bias, oh, oc); break;
            case 5: conv_mfma_kernel<2, 2, 2><<<dim3(1, 8), 512, 0, stream>>>(inT, c, Apack, bias, oh, oc); break;
        }
    }
}

// Round 10
// 544.483 us; speedup vs baseline: 14.4003x; 1.0562x over previous
//
#include <hip/hip_runtime.h>
#include <hip/hip_bf16.h>
#include <cstdint>
#include <cstddef>

#define PD 11
#define PP 121
#define NB 8

typedef _Float16 f16x8 __attribute__((ext_vector_type(8)));
typedef float    f32x4 __attribute__((ext_vector_type(4)));

// async global->LDS, 16B per lane, dest = lds_base + lane*16
#define GLOAD16(SRC, DST) __builtin_amdgcn_global_load_lds( \
    (const __attribute__((address_space(1))) void*)(SRC),   \
    (__attribute__((address_space(3))) void*)(DST), 16, 0, 0)

// ---------------------------------------------------------------------------
__global__ void init_kernel(unsigned* __restrict__ slots, float* __restrict__ zg) {
    int t = threadIdx.x;
    if (t < 8) slots[t] = 0x007FFFFFu;  // enc(-inf)
    for (int i = t; i < 1024; i += 256) zg[i] = 0.f;
}

// ---------------------------------------------------------------------------
// fused fp32 NCHW -> fp16 NHWC transpose for x AND xp (blockIdx.z selects).
template<int C, int H, int TPX>
__global__ __launch_bounds__(256) void tpose_kernel(
    const float* __restrict__ xin, const float* __restrict__ xpin,
    _Float16* __restrict__ xT, _Float16* __restrict__ xpT)
{
    constexpr int W = H;
    const float* in  = blockIdx.z ? xpin : xin;
    _Float16*   out  = blockIdx.z ? xpT  : xT;
    const int by = blockIdx.y;            // b*H + y
    const int b  = by / H, y = by % H;
    constexpr int NXT = W / TPX;
    const int x0 = (blockIdx.x % NXT) * TPX;
    const int cc = (blockIdx.x / NXT) * 64;
    __shared__ float s[64][36];

    constexpr int NF4 = 64 * TPX / 4;
    for (int f = threadIdx.x; f < NF4; f += 256) {
        int r  = f / (TPX / 4);
        int xq = f % (TPX / 4);
        int col = (xq * 4) ^ (((r >> 3) & 7) * 4);
        *(float4*)&s[r][col] =
            *(const float4*)&in[((size_t)(b * C + cc + r) * H + y) * W + x0 + xq * 4];
    }
    __syncthreads();
    constexpr int NWT = TPX * 8;
    for (int t = threadIdx.x; t < NWT; t += 256) {
        int pix = t >> 3, ck = t & 7;
        union { _Float16 h[8]; f16x8 v; } d;
#pragma unroll
        for (int j = 0; j < 8; ++j)
            d.h[j] = (_Float16)s[ck * 8 + j][pix ^ (ck * 4)];
        *(f16x8*)&out[((size_t)(b * H + y) * W + x0 + pix) * C + cc + ck * 8] = d.v;
    }
}

// ---------------------------------------------------------------------------
// MFMA correlation, double-buffered gload_lds staging.
template<int C, int H, int TSY, int TSX>
__global__ __launch_bounds__(512, 2) void corr_mfma_kernel(
    const _Float16* __restrict__ xT, const _Float16* __restrict__ xpT,
    const _Float16* __restrict__ zg,
    _Float16* __restrict__ inT, unsigned* __restrict__ slot)
{
    constexpr int W  = H;
    constexpr int HY = TSY + 10, HX = TSX + 10;
    constexpr int MZ = HY * HX;
    constexpr int MT = (MZ + 15) / 16;
    constexpr int MTP = MT * 16;
    constexpr int MFRAG = (MT + 7) / 8;
    constexpr int NPX = TSY * TSX;
    constexpr int NT  = NPX / 16;
    constexpr int KC  = C / 32;
    constexpr int ABYTES = MTP * 64;
    constexpr int BUF    = ABYTES + NPX * 64;
    constexpr int NLOAD  = BUF / 1024;
    constexpr int ST2    = NPX + 8;
    constexpr int ST_B   = MTP * ST2 * 2;
    constexpr int LDS_B  = (2 * BUF > ST_B) ? 2 * BUF : ST_B;
    __shared__ char smem[LDS_B];
    __shared__ float sred[8];

    const int tid  = threadIdx.x;
    const int b    = blockIdx.y;
    constexpr int TXT = W / TSX;
    const int y0 = (blockIdx.x / TXT) * TSY;
    const int x0 = (blockIdx.x % TXT) * TSX;
    const int w = tid >> 6, lane = tid & 63;
    const int lcol = lane & 15, lkg = lane >> 4;

    auto STAGE = [&](int bufsel, int kc) {
        char* dstb = smem + bufsel * BUF;
        int c = lane & 3;
        for (int it = w; it < NLOAD; it += 8) {
            const void* src;
            if (it < MTP / 16) {
                int z = it * 16 + (lane >> 2);
                int zy = y0 + z / HX - 5, zx = x0 + z % HX - 5;
                if (z < MZ && zy >= 0 && zy < H && zx >= 0 && zx < W)
                    src = xpT + ((size_t)(b * H + zy) * W + zx) * C + kc * 32 + ((c ^ (z >> 2)) & 3) * 8;
                else
                    src = zg + lane * 8;
            } else {
                int p = (it - MTP / 16) * 16 + (lane >> 2);
                int gy = y0 + p / TSX, gx = x0 + p % TSX;
                src = xT + ((size_t)(b * H + gy) * W + gx) * C + kc * 32 + ((c ^ (p >> 2)) & 3) * 8;
            }
            GLOAD16(src, dstb + it * 1024);
        }
    };

    f32x4 acc[MFRAG][NT];
#pragma unroll
    for (int i = 0; i < MFRAG; ++i)
#pragma unroll
        for (int nt = 0; nt < NT; ++nt)
            acc[i][nt] = (f32x4){0.f, 0.f, 0.f, 0.f};

    STAGE(0, 0);
    __syncthreads();
#pragma unroll 1
    for (int kc = 0; kc < KC; ++kc) {
        if (kc + 1 < KC) STAGE((kc + 1) & 1, kc + 1);
        const char* bb = smem + (kc & 1) * BUF;
        f16x8 bF[NT];
#pragma unroll
        for (int nt = 0; nt < NT; ++nt) {
            int p = nt * 16 + lcol;
            bF[nt] = *(const f16x8*)(bb + ABYTES + p * 64 + (((lkg ^ (p >> 2)) & 3) << 4));
        }
#pragma unroll
        for (int i = 0; i < MFRAG; ++i) {
            int mt = w + i * 8;
            if (mt < MT) {
                int z = mt * 16 + lcol;
                f16x8 aF = *(const f16x8*)(bb + z * 64 + (((lkg ^ (z >> 2)) & 3) << 4));
#pragma unroll
                for (int nt = 0; nt < NT; ++nt)
                    acc[i][nt] = __builtin_amdgcn_mfma_f32_16x16x32_f16(aF, bF[nt], acc[i][nt], 0, 0, 0);
            }
        }
        __syncthreads();
    }

    // T -> LDS as fp16
    _Float16* sT = (_Float16*)smem;
#pragma unroll
    for (int i = 0; i < MFRAG; ++i) {
        int mt = w + i * 8;
        if (mt >= MT) continue;
        int z0 = mt * 16 + lkg * 4;
#pragma unroll
        for (int nt = 0; nt < NT; ++nt) {
            int p = nt * 16 + lcol;
#pragma unroll
            for (int r = 0; r < 4; ++r)
                sT[(z0 + r) * ST2 + p] = (_Float16)acc[i][nt][r];
        }
    }
    __syncthreads();

    // gather: thread (p, qg) -> 16 channels of pixel p
    float lmax = -3.4e38f;
    if (tid < NPX * 8) {
        int p  = tid >> 3;
        int qg = tid & 7;
        int py = p / TSX, px = p % TSX;
        size_t pix = (size_t)(b * H + y0 + py) * W + (x0 + px);
        unsigned* dst = (unsigned*)(inT + pix * 256) + qg * 8;
#pragma unroll
        for (int j2 = 0; j2 < 8; ++j2) {
            int q0 = qg * 16 + j2 * 2, q1 = q0 + 1;
            int qc0 = q0 < PP ? q0 : PP - 1;
            int qc1 = q1 < PP ? q1 : PP - 1;
            float v0 = (float)sT[((py + qc0 / PD) * HX + (px + qc0 % PD)) * ST2 + p];
            float v1 = (float)sT[((py + qc1 / PD) * HX + (px + qc1 % PD)) * ST2 + p];
            v0 = v0 > 0.f ? v0 : 0.01f * v0;
            v1 = v1 > 0.f ? v1 : 0.01f * v1;
            if (q0 < PP) lmax = fmaxf(lmax, v0);
            if (q1 < PP) lmax = fmaxf(lmax, v1);
            union { _Float16 h[2]; unsigned u; } pk;
            pk.h[0] = (_Float16)v0; pk.h[1] = (_Float16)v1;
            dst[j2] = pk.u;
        }
    }
    for (int off = 32; off; off >>= 1) lmax = fmaxf(lmax, __shfl_down(lmax, off));
    if (lane == 0) sred[w] = lmax;
    __syncthreads();
    if (tid == 0) {
        float m = sred[0];
        for (int i = 1; i < 8; ++i) m = fmaxf(m, sred[i]);
        unsigned eb = __float_as_uint(m);
        eb = (eb & 0x80000000u) ? ~eb : (eb | 0x80000000u);
        atomicMax(slot, eb);
    }
}

// ---------------------------------------------------------------------------
// small-level corr (cache-resident), writes inT channel q directly.
template<int C, int H>
__global__ __launch_bounds__(256) void corr_small_kernel(
    const float* __restrict__ x, const float* __restrict__ xp,
    _Float16* __restrict__ inT, unsigned* __restrict__ slot)
{
    constexpr int PX  = H * H;
    constexpr int TOT = PX * PP;
    const int b = blockIdx.y;
    const int o = blockIdx.x * 256 + threadIdx.x;
    float v = -3.4e38f;
    if (o < TOT) {
        int p = o / PP;
        int q = o % PP;
        int y = p / H, xx = p % H;
        int sy = y + q / PD - 5, sx = xx + q % PD - 5;
        float acc = 0.f;
        if (sy >= 0 && sy < H && sx >= 0 && sx < H) {
            const float* xb  = x  + (size_t)b * C * PX + p;
            const float* xpb = xp + (size_t)b * C * PX + sy * H + sx;
#pragma unroll 8
            for (int c = 0; c < C; ++c)
                acc = fmaf(xb[c * PX], xpb[c * PX], acc);
        }
        float lv = acc > 0.f ? acc : 0.01f * acc;
        inT[((size_t)b * PX + p) * 256 + q] = (_Float16)lv;
        v = lv;
    }
    for (int off = 32; off; off >>= 1) v = fmaxf(v, __shfl_down(v, off));
    __shared__ float sred[4];
    if ((threadIdx.x & 63) == 0) sred[threadIdx.x >> 6] = v;
    __syncthreads();
    if (threadIdx.x == 0) {
        float m = fmaxf(fmaxf(sred[0], sred[1]), fmaxf(sred[2], sred[3]));
        unsigned eb = __float_as_uint(m);
        eb = (eb & 0x80000000u) ? ~eb : (eb | 0x80000000u);
        atomicMax(slot, eb);
    }
}

// ---------------------------------------------------------------------------
// build inT: scale corr ch [0,121) by 1/max, fill [121,242) from hpre, pad 0.
template<int H>
__global__ __launch_bounds__(256) void build_kernel(
    _Float16* __restrict__ inT, const float* __restrict__ hpre,
    const unsigned* __restrict__ slot)
{
    constexpr int HW = H * H;
    constexpr int NP = NB * HW;
    int idx = blockIdx.x * 256 + threadIdx.x;
    if (idx >= NP * 32) return;
    int c   = idx / NP;
    int pix = idx % NP;
    int b = pix / HW, p2 = pix % HW;
    unsigned mu = *slot;
    float maxv = (mu & 0x80000000u) ? __uint_as_float(mu ^ 0x80000000u) : __uint_as_float(~mu);
    float inv = 1.0f / maxv;
    _Float16* base = inT + (size_t)pix * 256 + c * 8;
    union { _Float16 h[8]; uint4 u; } d;
    if (c <= 14) {
        d.u = *(const uint4*)base;
#pragma unroll
        for (int j = 0; j < 8; ++j) d.h[j] = (_Float16)((float)d.h[j] * inv);
    } else if (c == 15) {
        d.u = *(const uint4*)base;
        d.h[0] = (_Float16)((float)d.h[0] * inv);
#pragma unroll
        for (int j = 1; j < 8; ++j)
            d.h[j] = (_Float16)hpre[((size_t)b * PP + (j - 1)) * HW + p2];
    } else if (c <= 29) {
#pragma unroll
        for (int j = 0; j < 8; ++j)
            d.h[j] = (_Float16)hpre[((size_t)b * PP + (c * 8 + j - 121)) * HW + p2];
    } else if (c == 30) {
        d.h[0] = (_Float16)hpre[((size_t)b * PP + 119) * HW + p2];
        d.h[1] = (_Float16)hpre[((size_t)b * PP + 120) * HW + p2];
#pragma unroll
        for (int j = 2; j < 8; ++j) d.h[j] = (_Float16)0.f;
    } else {
#pragma unroll
        for (int j = 0; j < 8; ++j) d.h[j] = (_Float16)0.f;
    }
    *(uint4*)base = d.u;
}

// ---------------------------------------------------------------------------
// weight pack (fragment-linear fp16, m = q*4+gate)
__global__ void pack_kernel(const float* __restrict__ Wsrc, _Float16* __restrict__ Apack) {
    int t = blockIdx.x * 256 + threadIdx.x;
    if (t >= 9 * 8 * 32 * 64 * 8) return;
    int e  = t & 7;
    int l  = (t >> 3) & 63;
    int mt = (t >> 9) & 31;
    int ks = (t >> 14) & 7;
    int k9 = t >> 17;
    int m    = mt * 16 + (l & 15);
    int kloc = (l >> 4) * 8 + e;
    int ic   = ks * 32 + kloc;
    float v = 0.f;
    if (m < 484 && ic < 242) {
        int q = m >> 2, g = m & 3;
        v = Wsrc[((g * PP + q) * 242 + ic) * 9 + k9];
    }
    Apack[t] = (_Float16)v;
}

// ---------------------------------------------------------------------------
// conv v3: 4x16 pixel tile (55KB LDS -> 2 blocks/CU), gload_lds staging,
// explicit A-fragment register double-buffer across the 72-step (k9,ks) loop.
// MSPLIT splits the 32 m-tiles over blockIdx.z; wave w owns AF=4/MSPLIT
// m-tiles x 4 n-rows.
template<int H, int MSPLIT>
__global__ __launch_bounds__(512, 4) void conv_mfma3_kernel(
    const _Float16* __restrict__ inT, const float* __restrict__ cpre,
    const _Float16* __restrict__ Apack, const float* __restrict__ bias,
    const _Float16* __restrict__ zg,
    float* __restrict__ outh, float* __restrict__ outc)
{
    constexpr int W = H;
    constexpr int TR = 4, TC = 16, SR = TC + 2;   // SR=18
    constexpr int NPOS = (TR + 2) * SR;           // 108
    constexpr int MT_BLK = 32 / MSPLIT;
    constexpr int AF = 4 / MSPLIT;                // m-tiles per wave
    constexpr int TILES_X = W / TC;
    __shared__ _Float16 sIn[NPOS * 256];          // 55296 B

    const int tid  = threadIdx.x;
    const int b    = blockIdx.y;
    const int mblk = blockIdx.z;
    const int tile = blockIdx.x;
    const int ty0  = (tile / TILES_X) * TR;
    const int tx0  = (tile % TILES_X) * TC;
    const int w = tid >> 6, lane = tid & 63;
    const int lcol = lane & 15, kg = lane >> 4;

    // ---- stage tile via global_load_lds (linear dest, pre-swizzled src) ----
    char* sB = (char*)sIn;
    for (int it = w; it < NPOS / 2; it += 8) {
        int r  = it * 2 + (lane >> 5);
        int c  = lane & 31;
        int iy = r / SR, ix = r % SR;
        int gy = ty0 + iy - 1, gx = tx0 + ix - 1;
        const void* src;
        if (gy >= 0 && gy < H && gx >= 0 && gx < W)
            src = inT + ((size_t)(b * H + gy) * W + gx) * 256 + (c ^ (ix & 7)) * 8;
        else
            src = zg + lane * 8;
        GLOAD16(src, sB + it * 1024);
    }
    __syncthreads();

    const int mtg0 = mblk * MT_BLK + w * AF;

    f32x4 acc[AF * 4];
#pragma unroll
    for (int a = 0; a < AF; ++a) {
        int q = (mtg0 + a) * 4 + kg;
        f32x4 bv;
#pragma unroll
        for (int r = 0; r < 4; ++r) bv[r] = (q < PP) ? bias[r * PP + q] : 0.f;
#pragma unroll
        for (int j = 0; j < 4; ++j) acc[a * 4 + j] = bv;
    }

    const f16x8* apL = (const f16x8*)Apack + (size_t)mtg0 * 64 + lane;

    auto COMPUTE = [&](const f16x8* af, int s) {
        int k9 = s >> 3, ks = s & 7;
        int ky = k9 / 3, kx = k9 - ky * 3;
        int ix = lcol + kx;
        int xsw = (ix & 7) << 4;
        int cb  = kg * 16 + ks * 64;
#pragma unroll
        for (int j = 0; j < 4; ++j) {
            int addr = ((((j + ky) * SR + ix) * 512) + cb) ^ xsw;
            f16x8 bf = *(const f16x8*)(sB + addr);
#pragma unroll
            for (int a = 0; a < AF; ++a)
                acc[a * 4 + j] = __builtin_amdgcn_mfma_f32_16x16x32_f16(af[a], bf, acc[a * 4 + j], 0, 0, 0);
        }
    };

    // ---- 72-step loop, A register double-buffer (unroll-2, static names) ----
    f16x8 afA[AF], afB[AF];
#pragma unroll
    for (int a = 0; a < AF; ++a) afA[a] = apL[a * 64];
#pragma unroll 1
    for (int s2 = 0; s2 < 36; ++s2) {
        const f16x8* apB = apL + (size_t)(s2 * 2 + 1) * 2048;
#pragma unroll
        for (int a = 0; a < AF; ++a) afB[a] = apB[a * 64];
        COMPUTE(afA, s2 * 2);
        if (s2 < 35) {
            const f16x8* apA = apL + (size_t)(s2 * 2 + 2) * 2048;
#pragma unroll
            for (int a = 0; a < AF; ++a) afA[a] = apA[a * 64];
        }
        COMPUTE(afB, s2 * 2 + 1);
    }

    // ---- fused LSTM epilogue ----
#pragma unroll
    for (int a = 0; a < AF; ++a) {
        int q = (mtg0 + a) * 4 + kg;
        if (q >= PP) continue;
#pragma unroll
        for (int j = 0; j < 4; ++j) {
            int y = ty0 + j, x = tx0 + lcol;
            float ai = acc[a * 4 + j][0];
            float af_ = acc[a * 4 + j][1];
            float ao = acc[a * 4 + j][2];
            float ag = acc[a * 4 + j][3];
            float ig = 1.f / (1.f + expf(-ai));
            float fg = 1.f / (1.f + expf(-af_));
            float og = 1.f / (1.f + expf(-ao));
            float gg = tanhf(ag);
            size_t oidx = (((size_t)b * PP + q) * H + y) * W + x;
            float cp = cpre[oidx];
            float cn = fg * cp + ig * gg;
            outh[oidx] = og * tanhf(cn);
            outc[oidx] = cn;
        }
    }
}

// ---------------------------------------------------------------------------
// conv (old template) for tiny levels H=8/4/2
template<int H, int TR, int TC>
__global__ __launch_bounds__(512, 4) void conv_mfma_kernel(
    const _Float16* __restrict__ inT, const float* __restrict__ cpre,
    const _Float16* __restrict__ Apack, const float* __restrict__ bias,
    float* __restrict__ outh, float* __restrict__ outc)
{
    constexpr int W = H;
    constexpr int TILES_X = (W >= TC) ? (W / TC) : 1;
    constexpr int NPX   = TR * TC;
    constexpr int NT    = (NPX + 15) / 16;
    constexpr int SR    = TC + 2;
    constexpr int SROWS = TR + 2;
    constexpr int NPOS  = SROWS * SR;
    __shared__ _Float16 sIn[NPOS * 256];

    const int tid  = threadIdx.x;
    const int b    = blockIdx.y;
    const int tile = blockIdx.x;
    const int ty0  = (tile / TILES_X) * TR;
    const int tx0  = (tile % TILES_X) * TC;

    char* sB = (char*)sIn;
    constexpr int CHUNKS = NPOS * 32;
    for (int flat = tid; flat < CHUNKS; flat += 512) {
        int cg  = flat & 31;
        int pos = flat >> 5;
        int iy = pos / SR, ix = pos % SR;
        int gy = ty0 + iy - 1, gx = tx0 + ix - 1;
        f16x8 v = {0, 0, 0, 0, 0, 0, 0, 0};
        if (gy >= 0 && gy < H && gx >= 0 && gx < W)
            v = *(const f16x8*)(inT + ((size_t)(b * H + gy) * W + gx) * 256 + cg * 8);
        int dst = (pos * 512 + cg * 16) ^ ((ix & 7) << 4);
        *(f16x8*)(sB + dst) = v;
    }
    __syncthreads();

    const int w    = tid >> 6;
    const int lane = tid & 63;
    const int lcol = lane & 15;
    const int kg   = lane >> 4;

    f32x4 acc[4][NT];
#pragma unroll
    for (int i = 0; i < 4; ++i) {
        int q = (w * 4 + i) * 4 + kg;
        f32x4 bv;
#pragma unroll
        for (int r = 0; r < 4; ++r) bv[r] = (q < PP) ? bias[r * PP + q] : 0.f;
#pragma unroll
        for (int nt = 0; nt < NT; ++nt) acc[i][nt] = bv;
    }

#pragma unroll 1
    for (int k9 = 0; k9 < 9; ++k9) {
        const int ky = k9 / 3, kx = k9 % 3;
        int basev[NT], xswv[NT];
#pragma unroll
        for (int nt = 0; nt < NT; ++nt) {
            int p = nt * 16 + lcol;
            int pc = (NPX < 16 && p >= NPX) ? 0 : p;
            int py = pc / TC, px = pc % TC;
            int iy = py + ky, ix = px + kx;
            basev[nt] = (iy * SR + ix) * 512 + kg * 16;
            xswv[nt]  = (ix & 7) << 4;
        }
        const f16x8* apb = (const f16x8*)Apack + ((size_t)(k9 * 8) * 32 + w * 4) * 64 + lane;
#pragma unroll 1
        for (int ks = 0; ks < 8; ++ks) {
            f16x8 bf[NT];
#pragma unroll
            for (int nt = 0; nt < NT; ++nt) {
                int byteoff = (basev[nt] + ks * 64) ^ xswv[nt];
                bf[nt] = *(const f16x8*)(sB + byteoff);
                if (NPX < 16 && nt * 16 + lcol >= NPX) bf[nt] = (f16x8){};
            }
            const f16x8* ap = apb + (size_t)ks * 32 * 64;
            f16x8 af4[4];
#pragma unroll
            for (int i = 0; i < 4; ++i) af4[i] = ap[i * 64];
#pragma unroll
            for (int i = 0; i < 4; ++i)
#pragma unroll
                for (int nt = 0; nt < NT; ++nt)
                    acc[i][nt] = __builtin_amdgcn_mfma_f32_16x16x32_f16(af4[i], bf[nt], acc[i][nt], 0, 0, 0);
        }
    }

#pragma unroll
    for (int i = 0; i < 4; ++i) {
        int q = (w * 4 + i) * 4 + kg;
        if (q >= PP) continue;
#pragma unroll
        for (int nt = 0; nt < NT; ++nt) {
            int p = nt * 16 + lcol;
            if (NPX < 16 && p >= NPX) continue;
            int py = p / TC, px = p % TC;
            int y = ty0 + py, x = tx0 + px;
            float ai = acc[i][nt][0];
            float af_ = acc[i][nt][1];
            float ao = acc[i][nt][2];
            float ag = acc[i][nt][3];
            float ig = 1.f / (1.f + expf(-ai));
            float fg = 1.f / (1.f + expf(-af_));
            float og = 1.f / (1.f + expf(-ao));
            float gg = tanhf(ag);
            size_t oidx = (((size_t)b * PP + q) * H + y) * W + x;
            float cp = cpre[oidx];
            float cn = fg * cp + ig * gg;
            outh[oidx] = og * tanhf(cn);
            outc[oidx] = cn;
        }
    }
}

// ---------------------------------------------------------------------------
extern "C" void kernel_launch(void* const* d_in, const int* in_sizes, int n_in,
                              void* d_out, int out_size, void* d_ws, size_t ws_size,
                              hipStream_t stream) {
    (void)in_sizes; (void)n_in; (void)out_size; (void)ws_size;
    static const int HH[6] = {64, 32, 16, 8, 4, 2};

    unsigned* maxslots = (unsigned*)d_ws;
    _Float16* Apack = (_Float16*)((char*)d_ws + 256);
    _Float16* inT   = (_Float16*)((char*)d_ws + 2359808);
    _Float16* xT    = (_Float16*)((char*)d_ws + 19137024);
    _Float16* xpT   = (_Float16*)((char*)d_ws + 52691456);
    _Float16* zg    = (_Float16*)((char*)d_ws + 86245888);   // 4KB zero guard

    float* out = (float*)d_out;
    size_t obase = 0;

    init_kernel<<<1, 256, 0, stream>>>(maxslots, (float*)zg);

    for (int L = 0; L < 6; ++L) {
        const float* x    = (const float*)d_in[6 * L + 0];
        const float* xp   = (const float*)d_in[6 * L + 1];
        const float* h    = (const float*)d_in[6 * L + 2];
        const float* c    = (const float*)d_in[6 * L + 3];
        const float* Wsrc = (const float*)d_in[6 * L + 4];
        const float* bias = (const float*)d_in[6 * L + 5];
        int Hh = HH[L];
        int S = NB * PP * Hh * Hh;
        float* oh = out + obase;
        float* oc = out + obase + S;
        obase += 2 * (size_t)S;

        // ---- corr -> inT channels [0,121) + global max ----
        switch (L) {
            case 0:
                tpose_kernel<512, 64, 32><<<dim3(16, NB * 64, 2), 256, 0, stream>>>(x, xp, xT, xpT);
                corr_mfma_kernel<512, 64, 8, 8><<<dim3(64, NB), 512, 0, stream>>>(xT, xpT, zg, inT, maxslots + L);
                break;
            case 1:
                tpose_kernel<1024, 32, 32><<<dim3(16, NB * 32, 2), 256, 0, stream>>>(x, xp, xT, xpT);
                corr_mfma_kernel<1024, 32, 4, 8><<<dim3(32, NB), 512, 0, stream>>>(xT, xpT, zg, inT, maxslots + L);
                break;
            case 2:
                tpose_kernel<512, 16, 16><<<dim3(8, NB * 16, 2), 256, 0, stream>>>(x, xp, xT, xpT);
                corr_mfma_kernel<512, 16, 4, 4><<<dim3(16, NB), 512, 0, stream>>>(xT, xpT, zg, inT, maxslots + L);
                break;
            case 3: corr_small_kernel<256, 8><<<dim3((64 * PP + 255) / 256, NB), 256, 0, stream>>>(x, xp, inT, maxslots + L); break;
            case 4: corr_small_kernel<256, 4><<<dim3((16 * PP + 255) / 256, NB), 256, 0, stream>>>(x, xp, inT, maxslots + L); break;
            case 5: corr_small_kernel<256, 2><<<dim3((4 * PP + 255) / 256, NB), 256, 0, stream>>>(x, xp, inT, maxslots + L); break;
        }

        // ---- normalize + h-fill + zero-pad ----
        switch (L) {
            case 0: build_kernel<64><<<(NB * 64 * 64 * 32) / 256, 256, 0, stream>>>(inT, h, maxslots + L); break;
            case 1: build_kernel<32><<<(NB * 32 * 32 * 32) / 256, 256, 0, stream>>>(inT, h, maxslots + L); break;
            case 2: build_kernel<16><<<(NB * 16 * 16 * 32) / 256, 256, 0, stream>>>(inT, h, maxslots + L); break;
            case 3: build_kernel<8><<<(NB * 8 * 8 * 32) / 256, 256, 0, stream>>>(inT, h, maxslots + L); break;
            case 4: build_kernel<4><<<(NB * 4 * 4 * 32) / 256, 256, 0, stream>>>(inT, h, maxslots + L); break;
            case 5: build_kernel<2><<<(NB * 2 * 2 * 32) / 256, 256, 0, stream>>>(inT, h, maxslots + L); break;
        }

        pack_kernel<<<(9 * 8 * 32 * 64 * 8) / 256, 256, 0, stream>>>(Wsrc, Apack);

        switch (L) {
            case 0: conv_mfma3_kernel<64, 1><<<dim3(64, 8, 1), 512, 0, stream>>>(inT, c, Apack, bias, zg, oh, oc); break;
            case 1: conv_mfma3_kernel<32, 2><<<dim3(16, 8, 2), 512, 0, stream>>>(inT, c, Apack, bias, zg, oh, oc); break;
            case 2: conv_mfma3_kernel<16, 4><<<dim3(4, 8, 4),  512, 0, stream>>>(inT, c, Apack, bias, zg, oh, oc); break;
            case 3: conv_mfma_kernel<8, 8, 8><<<dim3(1, 8), 512, 0, stream>>>(inT, c, Apack, bias, oh, oc); break;
            case 4: conv_mfma_kernel<4, 4, 4><<<dim3(1, 8), 512, 0, stream>>>(inT, c, Apack, bias, oh, oc); break;
            case 5: conv_mfma_kernel<2, 2, 2><<<dim3(1, 8), 512, 0, stream>>>(inT, c, Apack, bias, oh, oc); break;
        }
    }
}

// Round 11
// 542.439 us; speedup vs baseline: 14.4546x; 1.0038x over previous
//
#include <hip/hip_runtime.h>
#include <hip/hip_bf16.h>
#include <cstdint>
#include <cstddef>

#define PD 11
#define PP 121
#define NB 8

typedef _Float16 f16x8 __attribute__((ext_vector_type(8)));
typedef float    f32x4 __attribute__((ext_vector_type(4)));

// async global->LDS, 16B per lane, dest = lds_base + lane*16
#define GLOAD16(SRC, DST) __builtin_amdgcn_global_load_lds( \
    (const __attribute__((address_space(1))) void*)(SRC),   \
    (__attribute__((address_space(3))) void*)(DST), 16, 0, 0)

// ---------------------------------------------------------------------------
__global__ void init_kernel(unsigned* __restrict__ slots, float* __restrict__ zg) {
    int t = threadIdx.x;
    if (t < 8) slots[t] = 0x007FFFFFu;  // enc(-inf)
    for (int i = t; i < 1024; i += 256) zg[i] = 0.f;
}

__device__ __forceinline__ float decode_max(const unsigned* slot) {
    unsigned mu = *slot;
    return (mu & 0x80000000u) ? __uint_as_float(mu ^ 0x80000000u) : __uint_as_float(~mu);
}

// ---------------------------------------------------------------------------
// fused fp32 NCHW -> fp16 NHWC transpose for x AND xp (blockIdx.z selects).
template<int C, int H, int TPX>
__global__ __launch_bounds__(256) void tpose_kernel(
    const float* __restrict__ xin, const float* __restrict__ xpin,
    _Float16* __restrict__ xT, _Float16* __restrict__ xpT)
{
    constexpr int W = H;
    const float* in  = blockIdx.z ? xpin : xin;
    _Float16*   out  = blockIdx.z ? xpT  : xT;
    const int by = blockIdx.y;            // b*H + y
    const int b  = by / H, y = by % H;
    constexpr int NXT = W / TPX;
    const int x0 = (blockIdx.x % NXT) * TPX;
    const int cc = (blockIdx.x / NXT) * 64;
    __shared__ float s[64][36];

    constexpr int NF4 = 64 * TPX / 4;
    for (int f = threadIdx.x; f < NF4; f += 256) {
        int r  = f / (TPX / 4);
        int xq = f % (TPX / 4);
        int col = (xq * 4) ^ (((r >> 3) & 7) * 4);
        *(float4*)&s[r][col] =
            *(const float4*)&in[((size_t)(b * C + cc + r) * H + y) * W + x0 + xq * 4];
    }
    __syncthreads();
    constexpr int NWT = TPX * 8;
    for (int t = threadIdx.x; t < NWT; t += 256) {
        int pix = t >> 3, ck = t & 7;
        union { _Float16 h[8]; f16x8 v; } d;
#pragma unroll
        for (int j = 0; j < 8; ++j)
            d.h[j] = (_Float16)s[ck * 8 + j][pix ^ (ck * 4)];
        *(f16x8*)&out[((size_t)(b * H + y) * W + x0 + pix) * C + cc + ck * 8] = d.v;
    }
}

// ---------------------------------------------------------------------------
// MFMA correlation, double-buffered gload_lds staging. Writes RAW leaky'd
// corr into inT channels [0,128) + block max -> atomicMax.
template<int C, int H, int TSY, int TSX>
__global__ __launch_bounds__(512, 2) void corr_mfma_kernel(
    const _Float16* __restrict__ xT, const _Float16* __restrict__ xpT,
    const _Float16* __restrict__ zg,
    _Float16* __restrict__ inT, unsigned* __restrict__ slot)
{
    constexpr int W  = H;
    constexpr int HY = TSY + 10, HX = TSX + 10;
    constexpr int MZ = HY * HX;
    constexpr int MT = (MZ + 15) / 16;
    constexpr int MTP = MT * 16;
    constexpr int MFRAG = (MT + 7) / 8;
    constexpr int NPX = TSY * TSX;
    constexpr int NT  = NPX / 16;
    constexpr int KC  = C / 32;
    constexpr int ABYTES = MTP * 64;
    constexpr int BUF    = ABYTES + NPX * 64;
    constexpr int NLOAD  = BUF / 1024;
    constexpr int ST2    = NPX + 8;
    constexpr int ST_B   = MTP * ST2 * 2;
    constexpr int LDS_B  = (2 * BUF > ST_B) ? 2 * BUF : ST_B;
    __shared__ char smem[LDS_B];
    __shared__ float sred[8];

    const int tid  = threadIdx.x;
    const int b    = blockIdx.y;
    constexpr int TXT = W / TSX;
    const int y0 = (blockIdx.x / TXT) * TSY;
    const int x0 = (blockIdx.x % TXT) * TSX;
    const int w = tid >> 6, lane = tid & 63;
    const int lcol = lane & 15, lkg = lane >> 4;

    auto STAGE = [&](int bufsel, int kc) {
        char* dstb = smem + bufsel * BUF;
        int c = lane & 3;
        for (int it = w; it < NLOAD; it += 8) {
            const void* src;
            if (it < MTP / 16) {
                int z = it * 16 + (lane >> 2);
                int zy = y0 + z / HX - 5, zx = x0 + z % HX - 5;
                if (z < MZ && zy >= 0 && zy < H && zx >= 0 && zx < W)
                    src = xpT + ((size_t)(b * H + zy) * W + zx) * C + kc * 32 + ((c ^ (z >> 2)) & 3) * 8;
                else
                    src = zg + lane * 8;
            } else {
                int p = (it - MTP / 16) * 16 + (lane >> 2);
                int gy = y0 + p / TSX, gx = x0 + p % TSX;
                src = xT + ((size_t)(b * H + gy) * W + gx) * C + kc * 32 + ((c ^ (p >> 2)) & 3) * 8;
            }
            GLOAD16(src, dstb + it * 1024);
        }
    };

    f32x4 acc[MFRAG][NT];
#pragma unroll
    for (int i = 0; i < MFRAG; ++i)
#pragma unroll
        for (int nt = 0; nt < NT; ++nt)
            acc[i][nt] = (f32x4){0.f, 0.f, 0.f, 0.f};

    STAGE(0, 0);
    __syncthreads();
#pragma unroll 1
    for (int kc = 0; kc < KC; ++kc) {
        if (kc + 1 < KC) STAGE((kc + 1) & 1, kc + 1);
        const char* bb = smem + (kc & 1) * BUF;
        f16x8 bF[NT];
#pragma unroll
        for (int nt = 0; nt < NT; ++nt) {
            int p = nt * 16 + lcol;
            bF[nt] = *(const f16x8*)(bb + ABYTES + p * 64 + (((lkg ^ (p >> 2)) & 3) << 4));
        }
#pragma unroll
        for (int i = 0; i < MFRAG; ++i) {
            int mt = w + i * 8;
            if (mt < MT) {
                int z = mt * 16 + lcol;
                f16x8 aF = *(const f16x8*)(bb + z * 64 + (((lkg ^ (z >> 2)) & 3) << 4));
#pragma unroll
                for (int nt = 0; nt < NT; ++nt)
                    acc[i][nt] = __builtin_amdgcn_mfma_f32_16x16x32_f16(aF, bF[nt], acc[i][nt], 0, 0, 0);
            }
        }
        __syncthreads();
    }

    // T -> LDS as fp16
    _Float16* sT = (_Float16*)smem;
#pragma unroll
    for (int i = 0; i < MFRAG; ++i) {
        int mt = w + i * 8;
        if (mt >= MT) continue;
        int z0 = mt * 16 + lkg * 4;
#pragma unroll
        for (int nt = 0; nt < NT; ++nt) {
            int p = nt * 16 + lcol;
#pragma unroll
            for (int r = 0; r < 4; ++r)
                sT[(z0 + r) * ST2 + p] = (_Float16)acc[i][nt][r];
        }
    }
    __syncthreads();

    // gather: thread (p, qg) -> 16 channels of pixel p (raw, unnormalized)
    float lmax = -3.4e38f;
    if (tid < NPX * 8) {
        int p  = tid >> 3;
        int qg = tid & 7;
        int py = p / TSX, px = p % TSX;
        size_t pix = (size_t)(b * H + y0 + py) * W + (x0 + px);
        unsigned* dst = (unsigned*)(inT + pix * 256) + qg * 8;
#pragma unroll
        for (int j2 = 0; j2 < 8; ++j2) {
            int q0 = qg * 16 + j2 * 2, q1 = q0 + 1;
            int qc0 = q0 < PP ? q0 : PP - 1;
            int qc1 = q1 < PP ? q1 : PP - 1;
            float v0 = (float)sT[((py + qc0 / PD) * HX + (px + qc0 % PD)) * ST2 + p];
            float v1 = (float)sT[((py + qc1 / PD) * HX + (px + qc1 % PD)) * ST2 + p];
            v0 = v0 > 0.f ? v0 : 0.01f * v0;
            v1 = v1 > 0.f ? v1 : 0.01f * v1;
            if (q0 < PP) lmax = fmaxf(lmax, v0);
            if (q1 < PP) lmax = fmaxf(lmax, v1);
            union { _Float16 h[2]; unsigned u; } pk;
            pk.h[0] = (_Float16)v0; pk.h[1] = (_Float16)v1;
            dst[j2] = pk.u;
        }
    }
    for (int off = 32; off; off >>= 1) lmax = fmaxf(lmax, __shfl_down(lmax, off));
    if (lane == 0) sred[w] = lmax;
    __syncthreads();
    if (tid == 0) {
        float m = sred[0];
        for (int i = 1; i < 8; ++i) m = fmaxf(m, sred[i]);
        unsigned eb = __float_as_uint(m);
        eb = (eb & 0x80000000u) ? ~eb : (eb | 0x80000000u);
        atomicMax(slot, eb);
    }
}

// ---------------------------------------------------------------------------
// small-level corr (cache-resident), writes inT channel q directly (raw).
template<int C, int H>
__global__ __launch_bounds__(256) void corr_small_kernel(
    const float* __restrict__ x, const float* __restrict__ xp,
    _Float16* __restrict__ inT, unsigned* __restrict__ slot)
{
    constexpr int PX  = H * H;
    constexpr int TOT = PX * PP;
    const int b = blockIdx.y;
    const int o = blockIdx.x * 256 + threadIdx.x;
    float v = -3.4e38f;
    if (o < TOT) {
        int p = o / PP;
        int q = o % PP;
        int y = p / H, xx = p % H;
        int sy = y + q / PD - 5, sx = xx + q % PD - 5;
        float acc = 0.f;
        if (sy >= 0 && sy < H && sx >= 0 && sx < H) {
            const float* xb  = x  + (size_t)b * C * PX + p;
            const float* xpb = xp + (size_t)b * C * PX + sy * H + sx;
#pragma unroll 8
            for (int c = 0; c < C; ++c)
                acc = fmaf(xb[c * PX], xpb[c * PX], acc);
        }
        float lv = acc > 0.f ? acc : 0.01f * acc;
        inT[((size_t)b * PX + p) * 256 + q] = (_Float16)lv;
        v = lv;
    }
    for (int off = 32; off; off >>= 1) v = fmaxf(v, __shfl_down(v, off));
    __shared__ float sred[4];
    if ((threadIdx.x & 63) == 0) sred[threadIdx.x >> 6] = v;
    __syncthreads();
    if (threadIdx.x == 0) {
        float m = fmaxf(fmaxf(sred[0], sred[1]), fmaxf(sred[2], sred[3]));
        unsigned eb = __float_as_uint(m);
        eb = (eb & 0x80000000u) ? ~eb : (eb | 0x80000000u);
        atomicMax(slot, eb);
    }
}

// ---------------------------------------------------------------------------
// build inT (h-fill only; corr channels stay RAW — weights are prescaled):
// fill [121,242) from hpre, zero [242,256). Chunks 15..31 only.
template<int H>
__global__ __launch_bounds__(256) void build_kernel(
    _Float16* __restrict__ inT, const float* __restrict__ hpre)
{
    constexpr int HW = H * H;
    constexpr int NP = NB * HW;
    int idx = blockIdx.x * 256 + threadIdx.x;
    if (idx >= NP * 17) return;
    int c   = 15 + idx / NP;
    int pix = idx % NP;
    int b = pix / HW, p2 = pix % HW;
    _Float16* base = inT + (size_t)pix * 256 + c * 8;
    union { _Float16 h[8]; uint4 u; } d;
    if (c == 15) {
        d.u = *(const uint4*)base;                             // keep ch 112..120 raw
#pragma unroll
        for (int j = 1; j < 8; ++j)                            // ch 121..127 = h 0..6
            d.h[j] = (_Float16)hpre[((size_t)b * PP + (j - 1)) * HW + p2];
    } else if (c <= 29) {
#pragma unroll
        for (int j = 0; j < 8; ++j)                            // h 7..118
            d.h[j] = (_Float16)hpre[((size_t)b * PP + (c * 8 + j - 121)) * HW + p2];
    } else if (c == 30) {
        d.h[0] = (_Float16)hpre[((size_t)b * PP + 119) * HW + p2];
        d.h[1] = (_Float16)hpre[((size_t)b * PP + 120) * HW + p2];
#pragma unroll
        for (int j = 2; j < 8; ++j) d.h[j] = (_Float16)0.f;
    } else {
#pragma unroll
        for (int j = 0; j < 8; ++j) d.h[j] = (_Float16)0.f;
    }
    *(uint4*)base = d.u;
}

// ---------------------------------------------------------------------------
// weight pack (fragment-linear fp16, m = q*4+gate), corr columns (ic<121)
// prescaled by 1/max (folds the corr normalization into A).
__global__ void pack_kernel(const float* __restrict__ Wsrc, _Float16* __restrict__ Apack,
                            const unsigned* __restrict__ slot) {
    int t = blockIdx.x * 256 + threadIdx.x;
    if (t >= 9 * 8 * 32 * 64 * 8) return;
    float inv = 1.0f / decode_max(slot);
    int e  = t & 7;
    int l  = (t >> 3) & 63;
    int mt = (t >> 9) & 31;
    int ks = (t >> 14) & 7;
    int k9 = t >> 17;
    int m    = mt * 16 + (l & 15);
    int kloc = (l >> 4) * 8 + e;
    int ic   = ks * 32 + kloc;
    float v = 0.f;
    if (m < 484 && ic < 242) {
        int q = m >> 2, g = m & 3;
        v = Wsrc[((g * PP + q) * 242 + ic) * 9 + k9];
        if (ic < PP) v *= inv;
    }
    Apack[t] = (_Float16)v;
}

// ---------------------------------------------------------------------------
// conv v3: TR x 16 pixel tile, gload_lds staging, A-frag register dbuf.
// MSPLIT splits the 32 m-tiles over blockIdx.z; wave w owns AF=4/MSPLIT
// m-tiles x TR n-rows. Ragged bottom tiles: staged rows gy>=H are zeroed,
// epilogue guards y<H.
template<int H, int TR, int MSPLIT>
__global__ __launch_bounds__(512, 4) void conv_mfma3_kernel(
    const _Float16* __restrict__ inT, const float* __restrict__ cpre,
    const _Float16* __restrict__ Apack, const float* __restrict__ bias,
    const _Float16* __restrict__ zg,
    float* __restrict__ outh, float* __restrict__ outc)
{
    constexpr int W = H;
    constexpr int TC = 16, SR = TC + 2;
    constexpr int NPOS = (TR + 2) * SR;
    constexpr int MT_BLK = 32 / MSPLIT;
    constexpr int AF = 4 / MSPLIT;
    constexpr int TILES_X = W / TC;
    __shared__ _Float16 sIn[NPOS * 256];

    const int tid  = threadIdx.x;
    const int b    = blockIdx.y;
    const int mblk = blockIdx.z;
    const int tile = blockIdx.x;
    const int ty0  = (tile / TILES_X) * TR;
    const int tx0  = (tile % TILES_X) * TC;
    const int w = tid >> 6, lane = tid & 63;
    const int lcol = lane & 15, kg = lane >> 4;

    // ---- stage tile via global_load_lds (linear dest, pre-swizzled src) ----
    char* sB = (char*)sIn;
    for (int it = w; it < NPOS / 2; it += 8) {
        int r  = it * 2 + (lane >> 5);
        int c  = lane & 31;
        int iy = r / SR, ix = r % SR;
        int gy = ty0 + iy - 1, gx = tx0 + ix - 1;
        const void* src;
        if (gy >= 0 && gy < H && gx >= 0 && gx < W)
            src = inT + ((size_t)(b * H + gy) * W + gx) * 256 + (c ^ (ix & 7)) * 8;
        else
            src = zg + lane * 8;
        GLOAD16(src, sB + it * 1024);
    }
    __syncthreads();

    const int mtg0 = mblk * MT_BLK + w * AF;

    f32x4 acc[AF * TR];
#pragma unroll
    for (int a = 0; a < AF; ++a) {
        int q = (mtg0 + a) * 4 + kg;
        f32x4 bv;
#pragma unroll
        for (int r = 0; r < 4; ++r) bv[r] = (q < PP) ? bias[r * PP + q] : 0.f;
#pragma unroll
        for (int j = 0; j < TR; ++j) acc[a * TR + j] = bv;
    }

    const f16x8* apL = (const f16x8*)Apack + (size_t)mtg0 * 64 + lane;

    auto COMPUTE = [&](const f16x8* af, int s) {
        int k9 = s >> 3, ks = s & 7;
        int ky = k9 / 3, kx = k9 - ky * 3;
        int ix = lcol + kx;
        int xsw = (ix & 7) << 4;
        int cb  = kg * 16 + ks * 64;
#pragma unroll
        for (int j = 0; j < TR; ++j) {
            int addr = ((((j + ky) * SR + ix) * 512) + cb) ^ xsw;
            f16x8 bf = *(const f16x8*)(sB + addr);
#pragma unroll
            for (int a = 0; a < AF; ++a)
                acc[a * TR + j] = __builtin_amdgcn_mfma_f32_16x16x32_f16(af[a], bf, acc[a * TR + j], 0, 0, 0);
        }
    };

    // ---- 72-step loop, A register double-buffer (unroll-2, static names) ----
    f16x8 afA[AF], afB[AF];
#pragma unroll
    for (int a = 0; a < AF; ++a) afA[a] = apL[a * 64];
#pragma unroll 1
    for (int s2 = 0; s2 < 36; ++s2) {
        const f16x8* apB = apL + (size_t)(s2 * 2 + 1) * 2048;
#pragma unroll
        for (int a = 0; a < AF; ++a) afB[a] = apB[a * 64];
        COMPUTE(afA, s2 * 2);
        if (s2 < 35) {
            const f16x8* apA = apL + (size_t)(s2 * 2 + 2) * 2048;
#pragma unroll
            for (int a = 0; a < AF; ++a) afA[a] = apA[a * 64];
        }
        COMPUTE(afB, s2 * 2 + 1);
    }

    // ---- fused LSTM epilogue ----
#pragma unroll
    for (int a = 0; a < AF; ++a) {
        int q = (mtg0 + a) * 4 + kg;
        if (q >= PP) continue;
#pragma unroll
        for (int j = 0; j < TR; ++j) {
            int y = ty0 + j, x = tx0 + lcol;
            if (y >= H) continue;
            float ai = acc[a * TR + j][0];
            float af_ = acc[a * TR + j][1];
            float ao = acc[a * TR + j][2];
            float ag = acc[a * TR + j][3];
            float ig = 1.f / (1.f + expf(-ai));
            float fg = 1.f / (1.f + expf(-af_));
            float og = 1.f / (1.f + expf(-ao));
            float gg = tanhf(ag);
            size_t oidx = (((size_t)b * PP + q) * H + y) * W + x;
            float cp = cpre[oidx];
            float cn = fg * cp + ig * gg;
            outh[oidx] = og * tanhf(cn);
            outc[oidx] = cn;
        }
    }
}

// ---------------------------------------------------------------------------
// conv (old template) for tiny levels H=8/4/2
template<int H, int TR, int TC>
__global__ __launch_bounds__(512, 4) void conv_mfma_kernel(
    const _Float16* __restrict__ inT, const float* __restrict__ cpre,
    const _Float16* __restrict__ Apack, const float* __restrict__ bias,
    float* __restrict__ outh, float* __restrict__ outc)
{
    constexpr int W = H;
    constexpr int TILES_X = (W >= TC) ? (W / TC) : 1;
    constexpr int NPX   = TR * TC;
    constexpr int NT    = (NPX + 15) / 16;
    constexpr int SR    = TC + 2;
    constexpr int SROWS = TR + 2;
    constexpr int NPOS  = SROWS * SR;
    __shared__ _Float16 sIn[NPOS * 256];

    const int tid  = threadIdx.x;
    const int b    = blockIdx.y;
    const int tile = blockIdx.x;
    const int ty0  = (tile / TILES_X) * TR;
    const int tx0  = (tile % TILES_X) * TC;

    char* sB = (char*)sIn;
    constexpr int CHUNKS = NPOS * 32;
    for (int flat = tid; flat < CHUNKS; flat += 512) {
        int cg  = flat & 31;
        int pos = flat >> 5;
        int iy = pos / SR, ix = pos % SR;
        int gy = ty0 + iy - 1, gx = tx0 + ix - 1;
        f16x8 v = {0, 0, 0, 0, 0, 0, 0, 0};
        if (gy >= 0 && gy < H && gx >= 0 && gx < W)
            v = *(const f16x8*)(inT + ((size_t)(b * H + gy) * W + gx) * 256 + cg * 8);
        int dst = (pos * 512 + cg * 16) ^ ((ix & 7) << 4);
        *(f16x8*)(sB + dst) = v;
    }
    __syncthreads();

    const int w    = tid >> 6;
    const int lane = tid & 63;
    const int lcol = lane & 15;
    const int kg   = lane >> 4;

    f32x4 acc[4][NT];
#pragma unroll
    for (int i = 0; i < 4; ++i) {
        int q = (w * 4 + i) * 4 + kg;
        f32x4 bv;
#pragma unroll
        for (int r = 0; r < 4; ++r) bv[r] = (q < PP) ? bias[r * PP + q] : 0.f;
#pragma unroll
        for (int nt = 0; nt < NT; ++nt) acc[i][nt] = bv;
    }

#pragma unroll 1
    for (int k9 = 0; k9 < 9; ++k9) {
        const int ky = k9 / 3, kx = k9 % 3;
        int basev[NT], xswv[NT];
#pragma unroll
        for (int nt = 0; nt < NT; ++nt) {
            int p = nt * 16 + lcol;
            int pc = (NPX < 16 && p >= NPX) ? 0 : p;
            int py = pc / TC, px = pc % TC;
            int iy = py + ky, ix = px + kx;
            basev[nt] = (iy * SR + ix) * 512 + kg * 16;
            xswv[nt]  = (ix & 7) << 4;
        }
        const f16x8* apb = (const f16x8*)Apack + ((size_t)(k9 * 8) * 32 + w * 4) * 64 + lane;
#pragma unroll 1
        for (int ks = 0; ks < 8; ++ks) {
            f16x8 bf[NT];
#pragma unroll
            for (int nt = 0; nt < NT; ++nt) {
                int byteoff = (basev[nt] + ks * 64) ^ xswv[nt];
                bf[nt] = *(const f16x8*)(sB + byteoff);
                if (NPX < 16 && nt * 16 + lcol >= NPX) bf[nt] = (f16x8){};
            }
            const f16x8* ap = apb + (size_t)ks * 32 * 64;
            f16x8 af4[4];
#pragma unroll
            for (int i = 0; i < 4; ++i) af4[i] = ap[i * 64];
#pragma unroll
            for (int i = 0; i < 4; ++i)
#pragma unroll
                for (int nt = 0; nt < NT; ++nt)
                    acc[i][nt] = __builtin_amdgcn_mfma_f32_16x16x32_f16(af4[i], bf[nt], acc[i][nt], 0, 0, 0);
        }
    }

#pragma unroll
    for (int i = 0; i < 4; ++i) {
        int q = (w * 4 + i) * 4 + kg;
        if (q >= PP) continue;
#pragma unroll
        for (int nt = 0; nt < NT; ++nt) {
            int p = nt * 16 + lcol;
            if (NPX < 16 && p >= NPX) continue;
            int py = p / TC, px = p % TC;
            int y = ty0 + py, x = tx0 + px;
            float ai = acc[i][nt][0];
            float af_ = acc[i][nt][1];
            float ao = acc[i][nt][2];
            float ag = acc[i][nt][3];
            float ig = 1.f / (1.f + expf(-ai));
            float fg = 1.f / (1.f + expf(-af_));
            float og = 1.f / (1.f + expf(-ao));
            float gg = tanhf(ag);
            size_t oidx = (((size_t)b * PP + q) * H + y) * W + x;
            float cp = cpre[oidx];
            float cn = fg * cp + ig * gg;
            outh[oidx] = og * tanhf(cn);
            outc[oidx] = cn;
        }
    }
}

// ---------------------------------------------------------------------------
extern "C" void kernel_launch(void* const* d_in, const int* in_sizes, int n_in,
                              void* d_out, int out_size, void* d_ws, size_t ws_size,
                              hipStream_t stream) {
    (void)in_sizes; (void)n_in; (void)out_size; (void)ws_size;
    static const int HH[6] = {64, 32, 16, 8, 4, 2};

    unsigned* maxslots = (unsigned*)d_ws;
    _Float16* Apack = (_Float16*)((char*)d_ws + 256);
    _Float16* inT   = (_Float16*)((char*)d_ws + 2359808);
    _Float16* xT    = (_Float16*)((char*)d_ws + 19137024);
    _Float16* xpT   = (_Float16*)((char*)d_ws + 52691456);
    _Float16* zg    = (_Float16*)((char*)d_ws + 86245888);   // 4KB zero guard

    float* out = (float*)d_out;
    size_t obase = 0;

    init_kernel<<<1, 256, 0, stream>>>(maxslots, (float*)zg);

    for (int L = 0; L < 6; ++L) {
        const float* x    = (const float*)d_in[6 * L + 0];
        const float* xp   = (const float*)d_in[6 * L + 1];
        const float* h    = (const float*)d_in[6 * L + 2];
        const float* c    = (const float*)d_in[6 * L + 3];
        const float* Wsrc = (const float*)d_in[6 * L + 4];
        const float* bias = (const float*)d_in[6 * L + 5];
        int Hh = HH[L];
        int S = NB * PP * Hh * Hh;
        float* oh = out + obase;
        float* oc = out + obase + S;
        obase += 2 * (size_t)S;

        // ---- corr -> inT channels [0,121) (raw) + global max ----
        switch (L) {
            case 0:
                tpose_kernel<512, 64, 32><<<dim3(16, NB * 64, 2), 256, 0, stream>>>(x, xp, xT, xpT);
                corr_mfma_kernel<512, 64, 8, 8><<<dim3(64, NB), 512, 0, stream>>>(xT, xpT, zg, inT, maxslots + L);
                break;
            case 1:
                tpose_kernel<1024, 32, 32><<<dim3(16, NB * 32, 2), 256, 0, stream>>>(x, xp, xT, xpT);
                corr_mfma_kernel<1024, 32, 4, 8><<<dim3(32, NB), 512, 0, stream>>>(xT, xpT, zg, inT, maxslots + L);
                break;
            case 2:
                tpose_kernel<512, 16, 16><<<dim3(8, NB * 16, 2), 256, 0, stream>>>(x, xp, xT, xpT);
                corr_mfma_kernel<512, 16, 4, 4><<<dim3(16, NB), 512, 0, stream>>>(xT, xpT, zg, inT, maxslots + L);
                break;
            case 3: corr_small_kernel<256, 8><<<dim3((64 * PP + 255) / 256, NB), 256, 0, stream>>>(x, xp, inT, maxslots + L); break;
            case 4: corr_small_kernel<256, 4><<<dim3((16 * PP + 255) / 256, NB), 256, 0, stream>>>(x, xp, inT, maxslots + L); break;
            case 5: corr_small_kernel<256, 2><<<dim3((4 * PP + 255) / 256, NB), 256, 0, stream>>>(x, xp, inT, maxslots + L); break;
        }

        // ---- h-fill + zero-pad (chunks 15..31 only; corr stays raw) ----
        switch (L) {
            case 0: build_kernel<64><<<(NB * 64 * 64 * 17 + 255) / 256, 256, 0, stream>>>(inT, h); break;
            case 1: build_kernel<32><<<(NB * 32 * 32 * 17 + 255) / 256, 256, 0, stream>>>(inT, h); break;
            case 2: build_kernel<16><<<(NB * 16 * 16 * 17 + 255) / 256, 256, 0, stream>>>(inT, h); break;
            case 3: build_kernel<8><<<(NB * 8 * 8 * 17 + 255) / 256, 256, 0, stream>>>(inT, h); break;
            case 4: build_kernel<4><<<(NB * 4 * 4 * 17 + 255) / 256, 256, 0, stream>>>(inT, h); break;
            case 5: build_kernel<2><<<(NB * 2 * 2 * 17 + 255) / 256, 256, 0, stream>>>(inT, h); break;
        }

        // ---- pack (after corr: scales corr-columns by 1/max) ----
        pack_kernel<<<(9 * 8 * 32 * 64 * 8) / 256, 256, 0, stream>>>(Wsrc, Apack, maxslots + L);

        switch (L) {
            case 0: conv_mfma3_kernel<64, 6, 2><<<dim3(44, 8, 2), 512, 0, stream>>>(inT, c, Apack, bias, zg, oh, oc); break;
            case 1: conv_mfma3_kernel<32, 4, 2><<<dim3(16, 8, 2), 512, 0, stream>>>(inT, c, Apack, bias, zg, oh, oc); break;
            case 2: conv_mfma3_kernel<16, 4, 4><<<dim3(4, 8, 4),  512, 0, stream>>>(inT, c, Apack, bias, zg, oh, oc); break;
            case 3: conv_mfma_kernel<8, 8, 8><<<dim3(1, 8), 512, 0, stream>>>(inT, c, Apack, bias, oh, oc); break;
            case 4: conv_mfma_kernel<4, 4, 4><<<dim3(1, 8), 512, 0, stream>>>(inT, c, Apack, bias, oh, oc); break;
            case 5: conv_mfma_kernel<2, 2, 2><<<dim3(1, 8), 512, 0, stream>>>(inT, c, Apack, bias, oh, oc); break;
        }
    }
}